// Round 7
// baseline (247.778 us; speedup 1.0000x reference)
//
#include <hip/hip_runtime.h>

#define NN 100000
#define NE 1600000
#define F  128
#define NSPL 50000              // agg16 split: nodes < NSPL in out1, rest in ws

// radix partition params
#define SH   10                 // bucket = dst >> 10
#define NPB  1024               // nodes per bucket
#define NBKT 98                 // ceil(NN/1024)
#define B1   256                // pass-1 blocks
#define CH1  6250               // NE / B1 exactly

constexpr float EPS   = 1e-5f;
constexpr float SLOPE = 0.01f;

typedef __attribute__((ext_vector_type(8))) short short8;
typedef __attribute__((ext_vector_type(4))) float f32x4;

__device__ inline unsigned int bf16rne(float f) {
    unsigned int u = __float_as_uint(f);
    return (u + 0x7fffu + ((u >> 16) & 1u)) >> 16;
}
__device__ inline float blo(unsigned int u) { return __uint_as_float(u << 16); }
__device__ inline float bhi(unsigned int u) { return __uint_as_float(u & 0xffff0000u); }
__device__ inline unsigned int pack2(float a, float b) {
    return bf16rne(a) | (bf16rne(b) << 16);
}

// ---------------- W prep (fragment-ordered bf16 tiles) + zero stats ----------------
__global__ void k_wprep(const float* __restrict__ Wm, unsigned int* __restrict__ Wt,
                        float* __restrict__ stats) {
    int idx = blockIdx.x * 256 + threadIdx.x;   // 8192 total
    if (blockIdx.x == 0 && threadIdx.x < 2 * F) stats[threadIdx.x] = 0.0f;
    int p = idx & 3, lane = (idx >> 2) & 63, n = (idx >> 8) & 7, kk = idx >> 11;
    int k0 = kk * 32 + (lane >> 4) * 8 + 2 * p;
    int c  = n * 16 + (lane & 15);
    unsigned int lo = bf16rne(Wm[k0 * F + c]);
    unsigned int hi = bf16rne(Wm[(k0 + 1) * F + c]);
    Wt[idx] = lo | (hi << 16);
}

// ---------------- pass 1a: per-block bucket histogram ----------------
__global__ __launch_bounds__(1024) void k_hist1(const int* __restrict__ dst,
                                                unsigned int* __restrict__ mat) {
    __shared__ unsigned int h[NBKT];
    if (threadIdx.x < NBKT) h[threadIdx.x] = 0u;
    __syncthreads();
    const int e0 = blockIdx.x * CH1;
    for (int i = threadIdx.x; i < CH1; i += 1024)
        atomicAdd(&h[dst[e0 + i] >> SH], 1u);
    __syncthreads();
    if (threadIdx.x < NBKT) mat[threadIdx.x * B1 + blockIdx.x] = h[threadIdx.x];
}

// ---------------- pass 1b: exclusive scan of (bucket,block) matrix ----------------
__global__ __launch_bounds__(1024) void k_scan1(unsigned int* __restrict__ mat) {
    __shared__ unsigned int ps[1024];
    const int t = threadIdx.x;
    const int total = NBKT * B1;          // 25088
    const int SER = 25;
    int lo = t * SER, hi = min(lo + SER, total);
    unsigned int loc[SER];
    unsigned int s = 0u;
    for (int i = lo; i < hi; ++i) { loc[i - lo] = mat[i]; s += loc[i - lo]; }
    ps[t] = s;
    __syncthreads();
    for (int off = 1; off < 1024; off <<= 1) {
        unsigned int a = (t >= off) ? ps[t - off] : 0u;
        __syncthreads();
        ps[t] += a;
        __syncthreads();
    }
    unsigned int run = (t == 0) ? 0u : ps[t - 1];
    for (int i = lo; i < hi; ++i) { unsigned int v = loc[i - lo]; mat[i] = run; run += v; }
}

// ---------------- pass 1c: scatter edges into bucket segments ----------------
__global__ __launch_bounds__(1024) void k_scat1(const int* __restrict__ ei,
                                                const unsigned int* __restrict__ mat,
                                                unsigned int* __restrict__ ebuf) {
    __shared__ unsigned int cur[NBKT];
    if (threadIdx.x < NBKT) cur[threadIdx.x] = mat[threadIdx.x * B1 + blockIdx.x];
    __syncthreads();
    const int e0 = blockIdx.x * CH1;
    for (int i = threadIdx.x; i < CH1; i += 1024) {
        int s = ei[e0 + i];
        int d = ei[NE + e0 + i];
        unsigned int pos = atomicAdd(&cur[d >> SH], 1u);
        ebuf[pos] = ((unsigned int)(d & (NPB - 1)) << 17) | (unsigned int)s;
    }
}

// ---------------- pass 2: per-bucket degree/scan/row_start/dis + csr fill ----------------
__global__ __launch_bounds__(1024) void k_fill2(const unsigned int* __restrict__ mat,
                                                const unsigned int* __restrict__ ebuf,
                                                int* __restrict__ row_start,
                                                float* __restrict__ dis,
                                                int* __restrict__ csr) {
    __shared__ unsigned int hist[NPB];
    __shared__ unsigned int cur[NPB];
    __shared__ unsigned int ps[1024];
    const int t = threadIdx.x;
    const int bkt = blockIdx.x;
    const int nb0 = bkt << SH;
    hist[t] = 0u;
    __syncthreads();
    const unsigned int ebase = mat[bkt * B1];
    const unsigned int eend  = (bkt == NBKT - 1) ? (unsigned int)NE : mat[(bkt + 1) * B1];
    for (unsigned int i = ebase + t; i < eend; i += 1024)
        atomicAdd(&hist[ebuf[i] >> 17], 1u);
    __syncthreads();
    const unsigned int deg = hist[t];
    ps[t] = deg;
    __syncthreads();
    for (int off = 1; off < 1024; off <<= 1) {
        unsigned int a = (t >= off) ? ps[t - off] : 0u;
        __syncthreads();
        ps[t] += a;
        __syncthreads();
    }
    const unsigned int ex = (t == 0) ? 0u : ps[t - 1];
    cur[t] = ebase + ex;
    const int node = nb0 + t;
    if (node < NN) {
        row_start[node] = (int)(ebase + ex);
        dis[node] = rsqrtf((float)(deg + 1u));
    }
    if (bkt == NBKT - 1 && t == 0) row_start[NN] = NE;
    __syncthreads();
    for (unsigned int i = ebase + t; i < eend; i += 1024) {
        unsigned int v = ebuf[i];
        unsigned int pos = atomicAdd(&cur[v >> 17], 1u);
        csr[pos] = (int)(v & 0x1FFFFu);
    }
}

// ---------------- MFMA GEMM: g = bf16(x @ W) * dis ----------------
__global__ __launch_bounds__(256) void k_gemm(const float* __restrict__ x,
                                              const unsigned int* __restrict__ Wt,
                                              const float* __restrict__ dis,
                                              unsigned short* __restrict__ g16) {
    __shared__ unsigned int xl[128 * 64];   // 32 KB bf16-pair tile
    const int tid = threadIdx.x;
    const int lane = tid & 63, wave = tid >> 6;
    const int row0 = blockIdx.x * 128;

#pragma unroll
    for (int i = 0; i < 16; ++i) {
        int fi = i * 256 + tid;            // 0..4095
        int lr = fi >> 5;                  // local row (32 thr/row)
        int cf = (fi & 31) * 4;            // f32 col
        int gr = row0 + lr; if (gr >= NN) gr = NN - 1;
        float4 v = *(const float4*)(x + (size_t)gr * F + cf);
        unsigned int u0 = pack2(v.x, v.y);
        unsigned int u1 = pack2(v.z, v.w);
        int cu = (cf >> 1) ^ ((lr & 7) << 2);
        uint2 w2; w2.x = u0; w2.y = u1;
        *(uint2*)&xl[lr * 64 + cu] = w2;
    }
    __syncthreads();

    const int rbase = row0 + wave * 32;
    short8 afr[2][4];
#pragma unroll
    for (int m = 0; m < 2; ++m) {
        int lr = wave * 32 + m * 16 + (lane & 15);
#pragma unroll
        for (int kk = 0; kk < 4; ++kk) {
            int cu = (kk * 16 + (lane >> 4) * 4) ^ ((lr & 7) << 2);
            afr[m][kk] = *(const short8*)&xl[lr * 64 + cu];
        }
    }

    f32x4 acc[2][8];
#pragma unroll
    for (int m = 0; m < 2; ++m)
#pragma unroll
        for (int n = 0; n < 8; ++n) { f32x4 z = {0.f, 0.f, 0.f, 0.f}; acc[m][n] = z; }

    const uint4* Wt4 = (const uint4*)Wt;
#pragma unroll
    for (int kk = 0; kk < 4; ++kk) {
        union { uint4 u; short8 s; } bfr[8];
#pragma unroll
        for (int n = 0; n < 8; ++n) bfr[n].u = Wt4[(kk * 8 + n) * 64 + lane];
#pragma unroll
        for (int m = 0; m < 2; ++m)
#pragma unroll
            for (int n = 0; n < 8; ++n)
                acc[m][n] = __builtin_amdgcn_mfma_f32_16x16x32_bf16(afr[m][kk], bfr[n].s, acc[m][n], 0, 0, 0);
    }

    float dv[2][4];
#pragma unroll
    for (int m = 0; m < 2; ++m)
#pragma unroll
        for (int r = 0; r < 4; ++r) {
            int row = rbase + m * 16 + (lane >> 4) * 4 + r;
            dv[m][r] = (row < NN) ? dis[row] : 0.0f;
        }
#pragma unroll
    for (int m = 0; m < 2; ++m)
#pragma unroll
        for (int n = 0; n < 8; ++n)
#pragma unroll
            for (int r = 0; r < 4; ++r) {
                int row = rbase + m * 16 + (lane >> 4) * 4 + r;
                if (row < NN) {
                    int col = n * 16 + (lane & 15);
                    g16[(size_t)row * F + col] = (unsigned short)bf16rne(acc[m][n][r] * dv[m][r]);
                }
            }
}

// ---------------- gather: agg16 = bf16(b + dis[n]*sum(g[src] over src ∪ {n})) ----------------
// wave per node; csr ids preloaded once (coalesced), distributed via shfl;
// 8 rows/iter, 8 lanes × 32 B per row; 3-stage shfl_xor reduce; bf16-pair output
// split across agg_lo (nodes < NSPL, in out1) and agg_hi (rest, in ws).
__global__ __launch_bounds__(256) void k_gather(const unsigned int* __restrict__ g,
                                                const int* __restrict__ csr,
                                                const int* __restrict__ row_start,
                                                const float* __restrict__ dis,
                                                const float* __restrict__ b,
                                                unsigned int* __restrict__ agg_lo,
                                                unsigned int* __restrict__ agg_hi) {
    const int lane = threadIdx.x & 63;
    const int node = blockIdx.x * 4 + (threadIdx.x >> 6);
    if (node >= NN) return;
    const int q = lane >> 3;           // row slot within iteration (0..7)
    const int c = lane & 7;            // 32B chunk: features 16c..16c+15
    const int j = row_start[node];
    const int e = row_start[node + 1];
    const int L = e - j + 1;           // + self
    int sv = (j + lane < e) ? csr[j + lane] : node;
    float a0 = 0.f, a1 = 0.f, a2 = 0.f, a3 = 0.f;
    float a4 = 0.f, a5 = 0.f, a6 = 0.f, a7 = 0.f;
    float a8 = 0.f, a9 = 0.f, aA = 0.f, aB = 0.f;
    float aC = 0.f, aD = 0.f, aE = 0.f, aF = 0.f;
    int k = 0;
    const int L1 = (L < 64) ? L : 64;
    for (; k < L1; k += 8) {
        int kk = k + q;                 // <= 63
        int row = __shfl(sv, kk);
        if (kk < L) {
            const uint4* p = (const uint4*)&g[(size_t)row * 64 + c * 8];
            uint4 v0 = p[0];
            uint4 v1 = p[1];
            a0 += blo(v0.x); a1 += bhi(v0.x);
            a2 += blo(v0.y); a3 += bhi(v0.y);
            a4 += blo(v0.z); a5 += bhi(v0.z);
            a6 += blo(v0.w); a7 += bhi(v0.w);
            a8 += blo(v1.x); a9 += bhi(v1.x);
            aA += blo(v1.y); aB += bhi(v1.y);
            aC += blo(v1.z); aD += bhi(v1.z);
            aE += blo(v1.w); aF += bhi(v1.w);
        }
    }
    for (; k < L; k += 8) {            // rare: deg+1 > 64
        int kk = k + q;
        int row = (j + kk < e) ? csr[j + kk] : node;
        if (kk < L) {
            const uint4* p = (const uint4*)&g[(size_t)row * 64 + c * 8];
            uint4 v0 = p[0];
            uint4 v1 = p[1];
            a0 += blo(v0.x); a1 += bhi(v0.x);
            a2 += blo(v0.y); a3 += bhi(v0.y);
            a4 += blo(v0.z); a5 += bhi(v0.z);
            a6 += blo(v0.w); a7 += bhi(v0.w);
            a8 += blo(v1.x); a9 += bhi(v1.x);
            aA += blo(v1.y); aB += bhi(v1.y);
            aC += blo(v1.z); aD += bhi(v1.z);
            aE += blo(v1.w); aF += bhi(v1.w);
        }
    }
#define RED(a) a += __shfl_xor(a, 8); a += __shfl_xor(a, 16); a += __shfl_xor(a, 32);
    RED(a0) RED(a1) RED(a2) RED(a3) RED(a4) RED(a5) RED(a6) RED(a7)
    RED(a8) RED(a9) RED(aA) RED(aB) RED(aC) RED(aD) RED(aE) RED(aF)
#undef RED
    if (q == 0) {                      // lanes 0..7 write the row
        float d = dis[node];
        const float4* bp = (const float4*)&b[c * 16];
        float4 b0 = bp[0], b1 = bp[1], b2 = bp[2], b3 = bp[3];
        uint4 w0, w1;
        w0.x = pack2(b0.x + d * a0, b0.y + d * a1);
        w0.y = pack2(b0.z + d * a2, b0.w + d * a3);
        w0.z = pack2(b1.x + d * a4, b1.y + d * a5);
        w0.w = pack2(b1.z + d * a6, b1.w + d * a7);
        w1.x = pack2(b2.x + d * a8, b2.y + d * a9);
        w1.y = pack2(b2.z + d * aA, b2.w + d * aB);
        w1.z = pack2(b3.x + d * aC, b3.y + d * aD);
        w1.w = pack2(b3.z + d * aE, b3.w + d * aF);
        unsigned int* base = (node < NSPL) ? (agg_lo + (size_t)node * 64)
                                           : (agg_hi + (size_t)(node - NSPL) * 64);
        uint4* op = (uint4*)(base + c * 8);
        op[0] = w0;
        op[1] = w1;
    }
}

// ---------------- per-feature sums / sumsq from split bf16 agg ----------------
__global__ __launch_bounds__(256) void k_stats(const unsigned int* __restrict__ agg_lo,
                                               const unsigned int* __restrict__ agg_hi,
                                               float* __restrict__ sums,
                                               float* __restrict__ sumsq) {
    __shared__ float red[256];
    const int c = threadIdx.x & 63;    // u32 col: features 2c,2c+1
    const int ty = threadIdx.x >> 6;   // 0..3
    float se = 0.f, so = 0.f, qe = 0.f, qo = 0.f;
    for (int row = blockIdx.x * 4 + ty; row < NN; row += gridDim.x * 4) {
        unsigned int u = (row < NSPL) ? agg_lo[(size_t)row * 64 + c]
                                      : agg_hi[(size_t)(row - NSPL) * 64 + c];
        float v0 = blo(u), v1 = bhi(u);
        se += v0; so += v1;
        qe += v0 * v0; qo += v1 * v1;
    }
    red[threadIdx.x] = se; __syncthreads();
    if (ty == 0) atomicAdd(&sums[2 * c], red[c] + red[c + 64] + red[c + 128] + red[c + 192]);
    __syncthreads();
    red[threadIdx.x] = so; __syncthreads();
    if (ty == 0) atomicAdd(&sums[2 * c + 1], red[c] + red[c + 64] + red[c + 128] + red[c + 192]);
    __syncthreads();
    red[threadIdx.x] = qe; __syncthreads();
    if (ty == 0) atomicAdd(&sumsq[2 * c], red[c] + red[c + 64] + red[c + 128] + red[c + 192]);
    __syncthreads();
    red[threadIdx.x] = qo; __syncthreads();
    if (ty == 0) atomicAdd(&sumsq[2 * c + 1], red[c] + red[c + 64] + red[c + 128] + red[c + 192]);
}

// ---------------- norm: out0 = LeakyReLU(agg*A + Bc); A,Bc from stats (per-block) ----------------
__global__ __launch_bounds__(256) void k_norm(const unsigned int* __restrict__ agg_lo,
                                              const unsigned int* __restrict__ agg_hi,
                                              const float* __restrict__ sums,
                                              const float* __restrict__ sumsq,
                                              const float* __restrict__ gw,
                                              const float* __restrict__ gb,
                                              const float* __restrict__ gms,
                                              float* __restrict__ out0) {
    __shared__ float A[F], Bc[F];
    if (threadIdx.x < F) {
        int f = threadIdx.x;
        const float invn = 1.0f / (float)NN;
        float mean = sums[f] * invn;
        float ms = mean * gms[f];
        float var = sumsq[f] * invn - 2.0f * ms * mean + ms * ms;
        float inv = rsqrtf(var + EPS);
        float a = inv * gw[f];
        A[f] = a;
        Bc[f] = gb[f] - ms * a;
    }
    __syncthreads();
    const long half = (long)NSPL * 64;
    const long total = (long)NN * 64;
    for (long i = (long)blockIdx.x * blockDim.x + threadIdx.x; i < total;
         i += (long)gridDim.x * blockDim.x) {
        unsigned int u = (i < half) ? agg_lo[i] : agg_hi[i - half];
        int c = (int)(i & 63);
        float v0 = blo(u) * A[2 * c] + Bc[2 * c];
        float v1 = bhi(u) * A[2 * c + 1] + Bc[2 * c + 1];
        v0 = v0 > 0.f ? v0 : SLOPE * v0;
        v1 = v1 > 0.f ? v1 : SLOPE * v1;
        float2 r; r.x = v0; r.y = v1;
        *(float2*)&out0[2 * i] = r;
    }
}

// ---------------- edge_index passthrough as float (runs last: overwrites agg_lo) ----------------
__global__ void k_eicopy(const int* __restrict__ ei, float* __restrict__ out1) {
    const long total = 2L * NE / 4;
    const int4* i4 = (const int4*)ei;
    float4* o4 = (float4*)out1;
    for (long i = (long)blockIdx.x * blockDim.x + threadIdx.x; i < total;
         i += (long)gridDim.x * blockDim.x) {
        int4 v = i4[i];
        float4 r;
        r.x = (float)v.x; r.y = (float)v.y; r.z = (float)v.z; r.w = (float)v.w;
        o4[i] = r;
    }
}

extern "C" void kernel_launch(void* const* d_in, const int* in_sizes, int n_in,
                              void* d_out, int out_size, void* d_ws, size_t ws_size,
                              hipStream_t stream) {
    const float* x   = (const float*)d_in[0];
    const int*   ei  = (const int*)d_in[1];
    const float* Wm  = (const float*)d_in[2];
    const float* b   = (const float*)d_in[3];
    const float* gw  = (const float*)d_in[4];
    const float* gb  = (const float*)d_in[5];
    const float* gms = (const float*)d_in[6];

    float* out  = (float*)d_out;                 // region0: NN*F, region1: 2*NE
    float* out1 = out + (size_t)NN * F;
    unsigned int* agg_lo = (unsigned int*)out1;  // NSPL*64 u32 = 2*NE u32, exact fit

    // ws layout (u32 units). ebuf aliases g: ebuf consumed by k_fill2 before k_gemm writes g.
    unsigned int* wsu   = (unsigned int*)d_ws;
    unsigned int* g     = wsu;                          // NN*64 u32 (25.6 MB)
    unsigned int* ebuf  = wsu;                          // NE u32 (6.4 MB) — alias of g
    unsigned int* mat   = g + (size_t)NN * 64;          // NBKT*B1 = 25088
    int* row_start      = (int*)(mat + NBKT * B1 + 64); // NN+1
    int* csr            = row_start + NN + 2;           // NE (+8 pad)
    float* dis          = (float*)(csr + NE + 8);       // NN
    float* stats        = dis + NN;                     // 512
    unsigned int* Wt    = (unsigned int*)(stats + 512); // 8192
    unsigned int* agg_hi = Wt + 8192;                   // (NN-NSPL)*64 u32 (12.8 MB)
    float* sums  = stats;
    float* sumsq = stats + F;

    k_wprep<<<32, 256, 0, stream>>>(Wm, Wt, stats);
    k_hist1<<<B1, 1024, 0, stream>>>(ei + NE, mat);
    k_scan1<<<1, 1024, 0, stream>>>(mat);
    k_scat1<<<B1, 1024, 0, stream>>>(ei, mat, ebuf);
    k_fill2<<<NBKT, 1024, 0, stream>>>(mat, ebuf, row_start, dis, csr);
    k_gemm<<<(NN + 127) / 128, 256, 0, stream>>>(x, Wt, dis, (unsigned short*)g);
    k_gather<<<NN / 4, 256, 0, stream>>>(g, csr, row_start, dis, b, agg_lo, agg_hi);
    k_stats<<<1024, 256, 0, stream>>>(agg_lo, agg_hi, sums, sumsq);
    k_norm<<<2048, 256, 0, stream>>>(agg_lo, agg_hi, sums, sumsq, gw, gb, gms, out);
    k_eicopy<<<2048, 256, 0, stream>>>(ei, out1);
}

// Round 8
// 194.448 us; speedup vs baseline: 1.2743x; 1.2743x over previous
//
#include <hip/hip_runtime.h>

#define NN 100000
#define NE 1600000
#define F  128
#define NSPL 50000              // agg16 split: nodes < NSPL in out1, rest in ws

// radix partition params
#define SH   10                 // bucket = dst >> 10
#define NPB  1024               // nodes per bucket
#define NBKT 98                 // ceil(NN/1024)
#define B1   256                // pass-1 blocks
#define CH1  6250               // NE / B1 exactly

#define SB   512                // stats blocks (partials, no atomics)

constexpr float EPS   = 1e-5f;
constexpr float SLOPE = 0.01f;

typedef __attribute__((ext_vector_type(8))) short short8;
typedef __attribute__((ext_vector_type(4))) float f32x4;

__device__ inline unsigned int bf16rne(float f) {
    unsigned int u = __float_as_uint(f);
    return (u + 0x7fffu + ((u >> 16) & 1u)) >> 16;
}
__device__ inline float blo(unsigned int u) { return __uint_as_float(u << 16); }
__device__ inline float bhi(unsigned int u) { return __uint_as_float(u & 0xffff0000u); }
__device__ inline unsigned int pack2(float a, float b) {
    return bf16rne(a) | (bf16rne(b) << 16);
}

// ---------------- W prep (fragment-ordered bf16 tiles) ----------------
__global__ void k_wprep(const float* __restrict__ Wm, unsigned int* __restrict__ Wt) {
    int idx = blockIdx.x * 256 + threadIdx.x;   // 8192 total
    int p = idx & 3, lane = (idx >> 2) & 63, n = (idx >> 8) & 7, kk = idx >> 11;
    int k0 = kk * 32 + (lane >> 4) * 8 + 2 * p;
    int c  = n * 16 + (lane & 15);
    unsigned int lo = bf16rne(Wm[k0 * F + c]);
    unsigned int hi = bf16rne(Wm[(k0 + 1) * F + c]);
    Wt[idx] = lo | (hi << 16);
}

// ---------------- pass 1a: per-block bucket histogram ----------------
__global__ __launch_bounds__(1024) void k_hist1(const int* __restrict__ dst,
                                                unsigned int* __restrict__ mat) {
    __shared__ unsigned int h[NBKT];
    if (threadIdx.x < NBKT) h[threadIdx.x] = 0u;
    __syncthreads();
    const int e0 = blockIdx.x * CH1;
    for (int i = threadIdx.x; i < CH1; i += 1024)
        atomicAdd(&h[dst[e0 + i] >> SH], 1u);
    __syncthreads();
    if (threadIdx.x < NBKT) mat[threadIdx.x * B1 + blockIdx.x] = h[threadIdx.x];
}

// ---------------- pass 1b: exclusive scan of (bucket,block) matrix ----------------
__global__ __launch_bounds__(1024) void k_scan1(unsigned int* __restrict__ mat) {
    __shared__ unsigned int ps[1024];
    const int t = threadIdx.x;
    const int total = NBKT * B1;          // 25088
    const int SER = 25;
    int lo = t * SER, hi = min(lo + SER, total);
    unsigned int loc[SER];
    unsigned int s = 0u;
    for (int i = lo; i < hi; ++i) { loc[i - lo] = mat[i]; s += loc[i - lo]; }
    ps[t] = s;
    __syncthreads();
    for (int off = 1; off < 1024; off <<= 1) {
        unsigned int a = (t >= off) ? ps[t - off] : 0u;
        __syncthreads();
        ps[t] += a;
        __syncthreads();
    }
    unsigned int run = (t == 0) ? 0u : ps[t - 1];
    for (int i = lo; i < hi; ++i) { unsigned int v = loc[i - lo]; mat[i] = run; run += v; }
}

// ---------------- pass 1c: scatter edges into bucket segments ----------------
__global__ __launch_bounds__(1024) void k_scat1(const int* __restrict__ ei,
                                                const unsigned int* __restrict__ mat,
                                                unsigned int* __restrict__ ebuf) {
    __shared__ unsigned int cur[NBKT];
    if (threadIdx.x < NBKT) cur[threadIdx.x] = mat[threadIdx.x * B1 + blockIdx.x];
    __syncthreads();
    const int e0 = blockIdx.x * CH1;
    for (int i = threadIdx.x; i < CH1; i += 1024) {
        int s = ei[e0 + i];
        int d = ei[NE + e0 + i];
        unsigned int pos = atomicAdd(&cur[d >> SH], 1u);
        ebuf[pos] = ((unsigned int)(d & (NPB - 1)) << 17) | (unsigned int)s;
    }
}

// ---------------- pass 2: per-bucket degree/scan/row_start/dis + csr fill ----------------
__global__ __launch_bounds__(1024) void k_fill2(const unsigned int* __restrict__ mat,
                                                const unsigned int* __restrict__ ebuf,
                                                int* __restrict__ row_start,
                                                float* __restrict__ dis,
                                                int* __restrict__ csr) {
    __shared__ unsigned int hist[NPB];
    __shared__ unsigned int cur[NPB];
    __shared__ unsigned int ps[1024];
    const int t = threadIdx.x;
    const int bkt = blockIdx.x;
    const int nb0 = bkt << SH;
    hist[t] = 0u;
    __syncthreads();
    const unsigned int ebase = mat[bkt * B1];
    const unsigned int eend  = (bkt == NBKT - 1) ? (unsigned int)NE : mat[(bkt + 1) * B1];
    for (unsigned int i = ebase + t; i < eend; i += 1024)
        atomicAdd(&hist[ebuf[i] >> 17], 1u);
    __syncthreads();
    const unsigned int deg = hist[t];
    ps[t] = deg;
    __syncthreads();
    for (int off = 1; off < 1024; off <<= 1) {
        unsigned int a = (t >= off) ? ps[t - off] : 0u;
        __syncthreads();
        ps[t] += a;
        __syncthreads();
    }
    const unsigned int ex = (t == 0) ? 0u : ps[t - 1];
    cur[t] = ebase + ex;
    const int node = nb0 + t;
    if (node < NN) {
        row_start[node] = (int)(ebase + ex);
        dis[node] = rsqrtf((float)(deg + 1u));
    }
    if (bkt == NBKT - 1 && t == 0) row_start[NN] = NE;
    __syncthreads();
    for (unsigned int i = ebase + t; i < eend; i += 1024) {
        unsigned int v = ebuf[i];
        unsigned int pos = atomicAdd(&cur[v >> 17], 1u);
        csr[pos] = (int)(v & 0x1FFFFu);
    }
}

// ---------------- MFMA GEMM: g = bf16(x @ W) * dis ----------------
__global__ __launch_bounds__(256) void k_gemm(const float* __restrict__ x,
                                              const unsigned int* __restrict__ Wt,
                                              const float* __restrict__ dis,
                                              unsigned short* __restrict__ g16) {
    __shared__ unsigned int xl[128 * 64];   // 32 KB bf16-pair tile
    const int tid = threadIdx.x;
    const int lane = tid & 63, wave = tid >> 6;
    const int row0 = blockIdx.x * 128;

#pragma unroll
    for (int i = 0; i < 16; ++i) {
        int fi = i * 256 + tid;            // 0..4095
        int lr = fi >> 5;                  // local row (32 thr/row)
        int cf = (fi & 31) * 4;            // f32 col
        int gr = row0 + lr; if (gr >= NN) gr = NN - 1;
        float4 v = *(const float4*)(x + (size_t)gr * F + cf);
        unsigned int u0 = pack2(v.x, v.y);
        unsigned int u1 = pack2(v.z, v.w);
        int cu = (cf >> 1) ^ ((lr & 7) << 2);
        uint2 w2; w2.x = u0; w2.y = u1;
        *(uint2*)&xl[lr * 64 + cu] = w2;
    }
    __syncthreads();

    const int rbase = row0 + wave * 32;
    short8 afr[2][4];
#pragma unroll
    for (int m = 0; m < 2; ++m) {
        int lr = wave * 32 + m * 16 + (lane & 15);
#pragma unroll
        for (int kk = 0; kk < 4; ++kk) {
            int cu = (kk * 16 + (lane >> 4) * 4) ^ ((lr & 7) << 2);
            afr[m][kk] = *(const short8*)&xl[lr * 64 + cu];
        }
    }

    f32x4 acc[2][8];
#pragma unroll
    for (int m = 0; m < 2; ++m)
#pragma unroll
        for (int n = 0; n < 8; ++n) { f32x4 z = {0.f, 0.f, 0.f, 0.f}; acc[m][n] = z; }

    const uint4* Wt4 = (const uint4*)Wt;
#pragma unroll
    for (int kk = 0; kk < 4; ++kk) {
        union { uint4 u; short8 s; } bfr[8];
#pragma unroll
        for (int n = 0; n < 8; ++n) bfr[n].u = Wt4[(kk * 8 + n) * 64 + lane];
#pragma unroll
        for (int m = 0; m < 2; ++m)
#pragma unroll
            for (int n = 0; n < 8; ++n)
                acc[m][n] = __builtin_amdgcn_mfma_f32_16x16x32_bf16(afr[m][kk], bfr[n].s, acc[m][n], 0, 0, 0);
    }

    float dv[2][4];
#pragma unroll
    for (int m = 0; m < 2; ++m)
#pragma unroll
        for (int r = 0; r < 4; ++r) {
            int row = rbase + m * 16 + (lane >> 4) * 4 + r;
            dv[m][r] = (row < NN) ? dis[row] : 0.0f;
        }
#pragma unroll
    for (int m = 0; m < 2; ++m)
#pragma unroll
        for (int n = 0; n < 8; ++n)
#pragma unroll
            for (int r = 0; r < 4; ++r) {
                int row = rbase + m * 16 + (lane >> 4) * 4 + r;
                if (row < NN) {
                    int col = n * 16 + (lane & 15);
                    g16[(size_t)row * F + col] = (unsigned short)bf16rne(acc[m][n][r] * dv[m][r]);
                }
            }
}

// ---------------- gather: agg16 = bf16(b + dis[n]*sum(g[src] over src ∪ {n})) ----------------
__global__ __launch_bounds__(256) void k_gather(const unsigned int* __restrict__ g,
                                                const int* __restrict__ csr,
                                                const int* __restrict__ row_start,
                                                const float* __restrict__ dis,
                                                const float* __restrict__ b,
                                                unsigned int* __restrict__ agg_lo,
                                                unsigned int* __restrict__ agg_hi) {
    const int lane = threadIdx.x & 63;
    const int node = blockIdx.x * 4 + (threadIdx.x >> 6);
    if (node >= NN) return;
    const int q = lane >> 3;           // row slot within iteration (0..7)
    const int c = lane & 7;            // 32B chunk: features 16c..16c+15
    const int j = row_start[node];
    const int e = row_start[node + 1];
    const int L = e - j + 1;           // + self
    int sv = (j + lane < e) ? csr[j + lane] : node;
    float a0 = 0.f, a1 = 0.f, a2 = 0.f, a3 = 0.f;
    float a4 = 0.f, a5 = 0.f, a6 = 0.f, a7 = 0.f;
    float a8 = 0.f, a9 = 0.f, aA = 0.f, aB = 0.f;
    float aC = 0.f, aD = 0.f, aE = 0.f, aF = 0.f;
    int k = 0;
    const int L1 = (L < 64) ? L : 64;
    for (; k < L1; k += 8) {
        int kk = k + q;                 // <= 63
        int row = __shfl(sv, kk);
        if (kk < L) {
            const uint4* p = (const uint4*)&g[(size_t)row * 64 + c * 8];
            uint4 v0 = p[0];
            uint4 v1 = p[1];
            a0 += blo(v0.x); a1 += bhi(v0.x);
            a2 += blo(v0.y); a3 += bhi(v0.y);
            a4 += blo(v0.z); a5 += bhi(v0.z);
            a6 += blo(v0.w); a7 += bhi(v0.w);
            a8 += blo(v1.x); a9 += bhi(v1.x);
            aA += blo(v1.y); aB += bhi(v1.y);
            aC += blo(v1.z); aD += bhi(v1.z);
            aE += blo(v1.w); aF += bhi(v1.w);
        }
    }
    for (; k < L; k += 8) {            // rare: deg+1 > 64
        int kk = k + q;
        int row = (j + kk < e) ? csr[j + kk] : node;
        if (kk < L) {
            const uint4* p = (const uint4*)&g[(size_t)row * 64 + c * 8];
            uint4 v0 = p[0];
            uint4 v1 = p[1];
            a0 += blo(v0.x); a1 += bhi(v0.x);
            a2 += blo(v0.y); a3 += bhi(v0.y);
            a4 += blo(v0.z); a5 += bhi(v0.z);
            a6 += blo(v0.w); a7 += bhi(v0.w);
            a8 += blo(v1.x); a9 += bhi(v1.x);
            aA += blo(v1.y); aB += bhi(v1.y);
            aC += blo(v1.z); aD += bhi(v1.z);
            aE += blo(v1.w); aF += bhi(v1.w);
        }
    }
#define RED(a) a += __shfl_xor(a, 8); a += __shfl_xor(a, 16); a += __shfl_xor(a, 32);
    RED(a0) RED(a1) RED(a2) RED(a3) RED(a4) RED(a5) RED(a6) RED(a7)
    RED(a8) RED(a9) RED(aA) RED(aB) RED(aC) RED(aD) RED(aE) RED(aF)
#undef RED
    if (q == 0) {                      // lanes 0..7 write the row
        float d = dis[node];
        const float4* bp = (const float4*)&b[c * 16];
        float4 b0 = bp[0], b1 = bp[1], b2 = bp[2], b3 = bp[3];
        uint4 w0, w1;
        w0.x = pack2(b0.x + d * a0, b0.y + d * a1);
        w0.y = pack2(b0.z + d * a2, b0.w + d * a3);
        w0.z = pack2(b1.x + d * a4, b1.y + d * a5);
        w0.w = pack2(b1.z + d * a6, b1.w + d * a7);
        w1.x = pack2(b2.x + d * a8, b2.y + d * a9);
        w1.y = pack2(b2.z + d * aA, b2.w + d * aB);
        w1.z = pack2(b3.x + d * aC, b3.y + d * aD);
        w1.w = pack2(b3.z + d * aE, b3.w + d * aF);
        unsigned int* base = (node < NSPL) ? (agg_lo + (size_t)node * 64)
                                           : (agg_hi + (size_t)(node - NSPL) * 64);
        uint4* op = (uint4*)(base + c * 8);
        op[0] = w0;
        op[1] = w1;
    }
}

// ---------------- stats: uint4 streaming, shfl+LDS reduce, dense partials ----------------
// stride % 16 == 0 -> each thread owns a fixed uint4-column (features 8c..8c+7).
__global__ __launch_bounds__(256) void k_stats(const unsigned int* __restrict__ agg_lo,
                                               const unsigned int* __restrict__ agg_hi,
                                               float* __restrict__ partials) {
    __shared__ float lds[4][16][16];
    const int tid = threadIdx.x;
    const int lane = tid & 63, wave = tid >> 6;
    const int c4 = tid & 15;
    const uint4* lo4 = (const uint4*)agg_lo;
    const uint4* hi4 = (const uint4*)agg_hi;
    const long totalLo = (long)NSPL * 16;
    const long total   = (long)NN * 16;
    const long stride  = (long)SB * 256;
    float s[8], qq[8];
#pragma unroll
    for (int i = 0; i < 8; ++i) { s[i] = 0.f; qq[i] = 0.f; }
    for (long i = (long)blockIdx.x * 256 + tid; i < total; i += stride) {
        uint4 v = (i < totalLo) ? lo4[i] : hi4[i - totalLo];
        float f0 = blo(v.x), f1 = bhi(v.x), f2 = blo(v.y), f3 = bhi(v.y);
        float f4 = blo(v.z), f5 = bhi(v.z), f6 = blo(v.w), f7 = bhi(v.w);
        s[0] += f0; qq[0] += f0 * f0;  s[1] += f1; qq[1] += f1 * f1;
        s[2] += f2; qq[2] += f2 * f2;  s[3] += f3; qq[3] += f3 * f3;
        s[4] += f4; qq[4] += f4 * f4;  s[5] += f5; qq[5] += f5 * f5;
        s[6] += f6; qq[6] += f6 * f6;  s[7] += f7; qq[7] += f7 * f7;
    }
    // wave reduce: combine lanes sharing c4 (lane, +16, +32, +48)
#pragma unroll
    for (int i = 0; i < 8; ++i) {
        s[i]  += __shfl_xor(s[i], 16);  s[i]  += __shfl_xor(s[i], 32);
        qq[i] += __shfl_xor(qq[i], 16); qq[i] += __shfl_xor(qq[i], 32);
    }
    if (lane < 16) {
#pragma unroll
        for (int i = 0; i < 8; ++i) {
            lds[wave][lane][i]     = s[i];
            lds[wave][lane][i + 8] = qq[i];
        }
    }
    __syncthreads();
    // 256 threads: c4n = tid>>4, slot = tid&15
    const int c4n = tid >> 4, slot = tid & 15;
    float v = lds[0][c4n][slot] + lds[1][c4n][slot] + lds[2][c4n][slot] + lds[3][c4n][slot];
    int f = c4n * 8 + (slot & 7);
    int idx = (slot < 8) ? f : (F + f);
    partials[(size_t)blockIdx.x * 256 + idx] = v;
}

// ---------------- reduce partials -> stats[256] (sums | sumsq) ----------------
__global__ __launch_bounds__(256) void k_red(const float* __restrict__ partials,
                                             float* __restrict__ stats) {
    float acc = 0.f;
    for (int bq = 0; bq < SB; ++bq) acc += partials[bq * 256 + threadIdx.x];
    stats[threadIdx.x] = acc;
}

// ---------------- norm: out0 = LeakyReLU(agg*A + Bc); uint4 in, 2x float4 out ----------------
__global__ __launch_bounds__(256) void k_norm(const unsigned int* __restrict__ agg_lo,
                                              const unsigned int* __restrict__ agg_hi,
                                              const float* __restrict__ stats,
                                              const float* __restrict__ gw,
                                              const float* __restrict__ gb,
                                              const float* __restrict__ gms,
                                              float* __restrict__ out0) {
    __shared__ float A[F], Bc[F];
    if (threadIdx.x < F) {
        int f = threadIdx.x;
        const float invn = 1.0f / (float)NN;
        float mean = stats[f] * invn;
        float ms = mean * gms[f];
        float var = stats[F + f] * invn - 2.0f * ms * mean + ms * ms;
        float inv = rsqrtf(var + EPS);
        float a = inv * gw[f];
        A[f] = a;
        Bc[f] = gb[f] - ms * a;
    }
    __syncthreads();
    const int c4 = threadIdx.x & 15;       // fixed uint4-column per thread
    float ra[8], rb[8];
#pragma unroll
    for (int i = 0; i < 8; ++i) { ra[i] = A[c4 * 8 + i]; rb[i] = Bc[c4 * 8 + i]; }
    const uint4* lo4 = (const uint4*)agg_lo;
    const uint4* hi4 = (const uint4*)agg_hi;
    const long totalLo = (long)NSPL * 16;
    const long total   = (long)NN * 16;
    const long stride  = (long)gridDim.x * 256;
    for (long i = (long)blockIdx.x * 256 + threadIdx.x; i < total; i += stride) {
        uint4 v = (i < totalLo) ? lo4[i] : hi4[i - totalLo];
        float f0 = blo(v.x) * ra[0] + rb[0], f1 = bhi(v.x) * ra[1] + rb[1];
        float f2 = blo(v.y) * ra[2] + rb[2], f3 = bhi(v.y) * ra[3] + rb[3];
        float f4 = blo(v.z) * ra[4] + rb[4], f5 = bhi(v.z) * ra[5] + rb[5];
        float f6 = blo(v.w) * ra[6] + rb[6], f7 = bhi(v.w) * ra[7] + rb[7];
        f0 = f0 > 0.f ? f0 : SLOPE * f0;  f1 = f1 > 0.f ? f1 : SLOPE * f1;
        f2 = f2 > 0.f ? f2 : SLOPE * f2;  f3 = f3 > 0.f ? f3 : SLOPE * f3;
        f4 = f4 > 0.f ? f4 : SLOPE * f4;  f5 = f5 > 0.f ? f5 : SLOPE * f5;
        f6 = f6 > 0.f ? f6 : SLOPE * f6;  f7 = f7 > 0.f ? f7 : SLOPE * f7;
        float4 r0, r1;
        r0.x = f0; r0.y = f1; r0.z = f2; r0.w = f3;
        r1.x = f4; r1.y = f5; r1.z = f6; r1.w = f7;
        float* op = out0 + i * 8;
        *(float4*)op = r0;
        *(float4*)(op + 4) = r1;
    }
}

// ---------------- edge_index passthrough as float (runs last: overwrites agg_lo) ----------------
__global__ void k_eicopy(const int* __restrict__ ei, float* __restrict__ out1) {
    const long total = 2L * NE / 4;
    const int4* i4 = (const int4*)ei;
    float4* o4 = (float4*)out1;
    for (long i = (long)blockIdx.x * blockDim.x + threadIdx.x; i < total;
         i += (long)gridDim.x * blockDim.x) {
        int4 v = i4[i];
        float4 r;
        r.x = (float)v.x; r.y = (float)v.y; r.z = (float)v.z; r.w = (float)v.w;
        o4[i] = r;
    }
}

extern "C" void kernel_launch(void* const* d_in, const int* in_sizes, int n_in,
                              void* d_out, int out_size, void* d_ws, size_t ws_size,
                              hipStream_t stream) {
    const float* x   = (const float*)d_in[0];
    const int*   ei  = (const int*)d_in[1];
    const float* Wm  = (const float*)d_in[2];
    const float* b   = (const float*)d_in[3];
    const float* gw  = (const float*)d_in[4];
    const float* gb  = (const float*)d_in[5];
    const float* gms = (const float*)d_in[6];

    float* out  = (float*)d_out;                 // region0: NN*F, region1: 2*NE
    float* out1 = out + (size_t)NN * F;
    unsigned int* agg_lo = (unsigned int*)out1;  // NSPL*64 u32 = 2*NE u32, exact fit

    // ws layout (u32 units). ebuf aliases g: ebuf consumed by k_fill2 before k_gemm writes g.
    unsigned int* wsu   = (unsigned int*)d_ws;
    unsigned int* g     = wsu;                          // NN*64 u32 (25.6 MB)
    unsigned int* ebuf  = wsu;                          // NE u32 (6.4 MB) — alias of g
    unsigned int* mat   = g + (size_t)NN * 64;          // NBKT*B1 = 25088
    int* row_start      = (int*)(mat + NBKT * B1 + 64); // NN+1
    int* csr            = row_start + NN + 2;           // NE (+8 pad)
    float* dis          = (float*)(csr + NE + 8);       // NN
    float* stats        = dis + NN;                     // 256
    unsigned int* Wt    = (unsigned int*)(stats + 256); // 8192
    unsigned int* agg_hi = Wt + 8192;                   // (NN-NSPL)*64 u32 (12.8 MB)
    float* partials     = (float*)(agg_hi + (size_t)(NN - NSPL) * 64); // SB*256 (512 KB)

    k_wprep<<<32, 256, 0, stream>>>(Wm, Wt);
    k_hist1<<<B1, 1024, 0, stream>>>(ei + NE, mat);
    k_scan1<<<1, 1024, 0, stream>>>(mat);
    k_scat1<<<B1, 1024, 0, stream>>>(ei, mat, ebuf);
    k_fill2<<<NBKT, 1024, 0, stream>>>(mat, ebuf, row_start, dis, csr);
    k_gemm<<<(NN + 127) / 128, 256, 0, stream>>>(x, Wt, dis, (unsigned short*)g);
    k_gather<<<NN / 4, 256, 0, stream>>>(g, csr, row_start, dis, b, agg_lo, agg_hi);
    k_stats<<<SB, 256, 0, stream>>>(agg_lo, agg_hi, partials);
    k_red<<<1, 256, 0, stream>>>(partials, stats);
    k_norm<<<1024, 256, 0, stream>>>(agg_lo, agg_hi, stats, gw, gb, gms, out);
    k_eicopy<<<2048, 256, 0, stream>>>(ei, out1);
}

// Round 9
// 184.494 us; speedup vs baseline: 1.3430x; 1.0540x over previous
//
#include <hip/hip_runtime.h>

#define NN 100000
#define NE 1600000
#define F  128
#define NSPL 50000              // agg16 split: nodes < NSPL in out1, rest in ws

// radix partition params
#define SH   10                 // bucket = dst >> 10
#define NPB  1024               // nodes per bucket
#define NBKT 98                 // ceil(NN/1024)
#define B1   256                // pass-1 blocks
#define CH1  6250               // NE / B1 exactly

#define SB   256                // stats blocks (partials, no atomics)

constexpr float EPS   = 1e-5f;
constexpr float SLOPE = 0.01f;

typedef __attribute__((ext_vector_type(8))) short short8;
typedef __attribute__((ext_vector_type(4))) float f32x4;
typedef __attribute__((ext_vector_type(2))) float f32x2;

__device__ inline unsigned int bf16rne(float f) {
    unsigned int u = __float_as_uint(f);
    return (u + 0x7fffu + ((u >> 16) & 1u)) >> 16;
}
__device__ inline float blo(unsigned int u) { return __uint_as_float(u << 16); }
__device__ inline float bhi(unsigned int u) { return __uint_as_float(u & 0xffff0000u); }
__device__ inline unsigned int pack2(float a, float b) {
    return bf16rne(a) | (bf16rne(b) << 16);
}
__device__ inline f32x2 pkadd(f32x2 a, f32x2 b) {
    f32x2 d;
    asm("v_pk_add_f32 %0, %1, %2" : "=v"(d) : "v"(a), "v"(b));
    return d;
}
__device__ inline f32x2 up2(unsigned int u) {
    f32x2 r;
    r.x = __uint_as_float(u << 16);
    r.y = __uint_as_float(u & 0xffff0000u);
    return r;
}

// ---------------- W prep (fragment-ordered bf16 tiles) ----------------
__global__ void k_wprep(const float* __restrict__ Wm, unsigned int* __restrict__ Wt) {
    int idx = blockIdx.x * 256 + threadIdx.x;   // 8192 total
    int p = idx & 3, lane = (idx >> 2) & 63, n = (idx >> 8) & 7, kk = idx >> 11;
    int k0 = kk * 32 + (lane >> 4) * 8 + 2 * p;
    int c  = n * 16 + (lane & 15);
    unsigned int lo = bf16rne(Wm[k0 * F + c]);
    unsigned int hi = bf16rne(Wm[(k0 + 1) * F + c]);
    Wt[idx] = lo | (hi << 16);
}

// ---------------- pass 1a: per-block bucket histogram ----------------
__global__ __launch_bounds__(1024) void k_hist1(const int* __restrict__ dst,
                                                unsigned int* __restrict__ mat) {
    __shared__ unsigned int h[NBKT];
    if (threadIdx.x < NBKT) h[threadIdx.x] = 0u;
    __syncthreads();
    const int e0 = blockIdx.x * CH1;
    for (int i = threadIdx.x; i < CH1; i += 1024)
        atomicAdd(&h[dst[e0 + i] >> SH], 1u);
    __syncthreads();
    if (threadIdx.x < NBKT) mat[threadIdx.x * B1 + blockIdx.x] = h[threadIdx.x];
}

// ---------------- pass 1b: exclusive scan of (bucket,block) matrix ----------------
__global__ __launch_bounds__(1024) void k_scan1(unsigned int* __restrict__ mat) {
    __shared__ unsigned int ps[1024];
    const int t = threadIdx.x;
    const int total = NBKT * B1;          // 25088
    const int SER = 25;
    int lo = t * SER, hi = min(lo + SER, total);
    unsigned int loc[SER];
    unsigned int s = 0u;
    for (int i = lo; i < hi; ++i) { loc[i - lo] = mat[i]; s += loc[i - lo]; }
    ps[t] = s;
    __syncthreads();
    for (int off = 1; off < 1024; off <<= 1) {
        unsigned int a = (t >= off) ? ps[t - off] : 0u;
        __syncthreads();
        ps[t] += a;
        __syncthreads();
    }
    unsigned int run = (t == 0) ? 0u : ps[t - 1];
    for (int i = lo; i < hi; ++i) { unsigned int v = loc[i - lo]; mat[i] = run; run += v; }
}

// ---------------- pass 1c: scatter edges into bucket segments ----------------
__global__ __launch_bounds__(1024) void k_scat1(const int* __restrict__ ei,
                                                const unsigned int* __restrict__ mat,
                                                unsigned int* __restrict__ ebuf) {
    __shared__ unsigned int cur[NBKT];
    if (threadIdx.x < NBKT) cur[threadIdx.x] = mat[threadIdx.x * B1 + blockIdx.x];
    __syncthreads();
    const int e0 = blockIdx.x * CH1;
    for (int i = threadIdx.x; i < CH1; i += 1024) {
        int s = ei[e0 + i];
        int d = ei[NE + e0 + i];
        unsigned int pos = atomicAdd(&cur[d >> SH], 1u);
        ebuf[pos] = ((unsigned int)(d & (NPB - 1)) << 17) | (unsigned int)s;
    }
}

// ---------------- pass 2: per-bucket degree/scan/row_start/dis + csr fill ----------------
__global__ __launch_bounds__(1024) void k_fill2(const unsigned int* __restrict__ mat,
                                                const unsigned int* __restrict__ ebuf,
                                                int* __restrict__ row_start,
                                                float* __restrict__ dis,
                                                int* __restrict__ csr) {
    __shared__ unsigned int hist[NPB];
    __shared__ unsigned int cur[NPB];
    __shared__ unsigned int ps[1024];
    const int t = threadIdx.x;
    const int bkt = blockIdx.x;
    const int nb0 = bkt << SH;
    hist[t] = 0u;
    __syncthreads();
    const unsigned int ebase = mat[bkt * B1];
    const unsigned int eend  = (bkt == NBKT - 1) ? (unsigned int)NE : mat[(bkt + 1) * B1];
    for (unsigned int i = ebase + t; i < eend; i += 1024)
        atomicAdd(&hist[ebuf[i] >> 17], 1u);
    __syncthreads();
    const unsigned int deg = hist[t];
    ps[t] = deg;
    __syncthreads();
    for (int off = 1; off < 1024; off <<= 1) {
        unsigned int a = (t >= off) ? ps[t - off] : 0u;
        __syncthreads();
        ps[t] += a;
        __syncthreads();
    }
    const unsigned int ex = (t == 0) ? 0u : ps[t - 1];
    cur[t] = ebase + ex;
    const int node = nb0 + t;
    if (node < NN) {
        row_start[node] = (int)(ebase + ex);
        dis[node] = rsqrtf((float)(deg + 1u));
    }
    if (bkt == NBKT - 1 && t == 0) row_start[NN] = NE;
    __syncthreads();
    for (unsigned int i = ebase + t; i < eend; i += 1024) {
        unsigned int v = ebuf[i];
        unsigned int pos = atomicAdd(&cur[v >> 17], 1u);
        csr[pos] = (int)(v & 0x1FFFFu);
    }
}

// ---------------- MFMA GEMM: g = bf16(x @ W) * dis ----------------
__global__ __launch_bounds__(256) void k_gemm(const float* __restrict__ x,
                                              const unsigned int* __restrict__ Wt,
                                              const float* __restrict__ dis,
                                              unsigned short* __restrict__ g16) {
    __shared__ unsigned int xl[128 * 64];   // 32 KB bf16-pair tile
    const int tid = threadIdx.x;
    const int lane = tid & 63, wave = tid >> 6;
    const int row0 = blockIdx.x * 128;

#pragma unroll
    for (int i = 0; i < 16; ++i) {
        int fi = i * 256 + tid;            // 0..4095
        int lr = fi >> 5;                  // local row (32 thr/row)
        int cf = (fi & 31) * 4;            // f32 col
        int gr = row0 + lr; if (gr >= NN) gr = NN - 1;
        float4 v = *(const float4*)(x + (size_t)gr * F + cf);
        unsigned int u0 = pack2(v.x, v.y);
        unsigned int u1 = pack2(v.z, v.w);
        int cu = (cf >> 1) ^ ((lr & 7) << 2);
        uint2 w2; w2.x = u0; w2.y = u1;
        *(uint2*)&xl[lr * 64 + cu] = w2;
    }
    __syncthreads();

    const int rbase = row0 + wave * 32;
    short8 afr[2][4];
#pragma unroll
    for (int m = 0; m < 2; ++m) {
        int lr = wave * 32 + m * 16 + (lane & 15);
#pragma unroll
        for (int kk = 0; kk < 4; ++kk) {
            int cu = (kk * 16 + (lane >> 4) * 4) ^ ((lr & 7) << 2);
            afr[m][kk] = *(const short8*)&xl[lr * 64 + cu];
        }
    }

    f32x4 acc[2][8];
#pragma unroll
    for (int m = 0; m < 2; ++m)
#pragma unroll
        for (int n = 0; n < 8; ++n) { f32x4 z = {0.f, 0.f, 0.f, 0.f}; acc[m][n] = z; }

    const uint4* Wt4 = (const uint4*)Wt;
#pragma unroll
    for (int kk = 0; kk < 4; ++kk) {
        union { uint4 u; short8 s; } bfr[8];
#pragma unroll
        for (int n = 0; n < 8; ++n) bfr[n].u = Wt4[(kk * 8 + n) * 64 + lane];
#pragma unroll
        for (int m = 0; m < 2; ++m)
#pragma unroll
            for (int n = 0; n < 8; ++n)
                acc[m][n] = __builtin_amdgcn_mfma_f32_16x16x32_bf16(afr[m][kk], bfr[n].s, acc[m][n], 0, 0, 0);
    }

    float dv[2][4];
#pragma unroll
    for (int m = 0; m < 2; ++m)
#pragma unroll
        for (int r = 0; r < 4; ++r) {
            int row = rbase + m * 16 + (lane >> 4) * 4 + r;
            dv[m][r] = (row < NN) ? dis[row] : 0.0f;
        }
#pragma unroll
    for (int m = 0; m < 2; ++m)
#pragma unroll
        for (int n = 0; n < 8; ++n)
#pragma unroll
            for (int r = 0; r < 4; ++r) {
                int row = rbase + m * 16 + (lane >> 4) * 4 + r;
                if (row < NN) {
                    int col = n * 16 + (lane & 15);
                    g16[(size_t)row * F + col] = (unsigned short)bf16rne(acc[m][n][r] * dv[m][r]);
                }
            }
}

// ---------------- gather: agg16 = bf16(b + dis[n]*sum(g[src] over src ∪ {n})) ----------------
// wave per node; 16 lanes/row (uint4), 4 row-slots, 2 rows unrolled per iter;
// f32x2 accumulators + v_pk_add_f32; 2-stage shfl reduce; bf16-pair output.
__global__ __launch_bounds__(256) void k_gather(const unsigned int* __restrict__ g,
                                                const int* __restrict__ csr,
                                                const int* __restrict__ row_start,
                                                const float* __restrict__ dis,
                                                const float* __restrict__ b,
                                                unsigned int* __restrict__ agg_lo,
                                                unsigned int* __restrict__ agg_hi) {
    const int lane = threadIdx.x & 63;
    const int node = blockIdx.x * 4 + (threadIdx.x >> 6);
    if (node >= NN) return;
    const int q = lane >> 4;           // row slot (0..3)
    const int c = lane & 15;           // uint4 col: features 8c..8c+7
    const int j = row_start[node];
    const int e = row_start[node + 1];
    const int L = e - j + 1;           // + self
    int sv = (j + lane < e) ? csr[j + lane] : node;   // preload ids; self past end
    f32x2 A0 = {0.f, 0.f}, A1 = A0, A2 = A0, A3 = A0;
    int k = 0;
    const int L1 = (L < 64) ? L : 64;
    for (; k < L1; k += 8) {
        int k0 = k + q, k1 = k0 + 4;
        int r0 = __shfl(sv, k0);
        int r1 = __shfl(sv, k1);
        bool p0 = k0 < L, p1 = k1 < L;
        uint4 v0, v1;
        if (p0) v0 = *(const uint4*)&g[(size_t)r0 * 64 + c * 4];
        if (p1) v1 = *(const uint4*)&g[(size_t)r1 * 64 + c * 4];
        if (p0) {
            A0 = pkadd(A0, up2(v0.x)); A1 = pkadd(A1, up2(v0.y));
            A2 = pkadd(A2, up2(v0.z)); A3 = pkadd(A3, up2(v0.w));
        }
        if (p1) {
            A0 = pkadd(A0, up2(v1.x)); A1 = pkadd(A1, up2(v1.y));
            A2 = pkadd(A2, up2(v1.z)); A3 = pkadd(A3, up2(v1.w));
        }
    }
    for (; k < L; k += 8) {            // rare: deg+1 > 64
        int k0 = k + q, k1 = k0 + 4;
        if (k0 < L) {
            int r0 = (j + k0 < e) ? csr[j + k0] : node;
            uint4 v = *(const uint4*)&g[(size_t)r0 * 64 + c * 4];
            A0 = pkadd(A0, up2(v.x)); A1 = pkadd(A1, up2(v.y));
            A2 = pkadd(A2, up2(v.z)); A3 = pkadd(A3, up2(v.w));
        }
        if (k1 < L) {
            int r1 = (j + k1 < e) ? csr[j + k1] : node;
            uint4 v = *(const uint4*)&g[(size_t)r1 * 64 + c * 4];
            A0 = pkadd(A0, up2(v.x)); A1 = pkadd(A1, up2(v.y));
            A2 = pkadd(A2, up2(v.z)); A3 = pkadd(A3, up2(v.w));
        }
    }
    // reduce across q (bits 4,5): 2 stages, 8 floats
#define RED2(A) A.x += __shfl_xor(A.x, 16); A.x += __shfl_xor(A.x, 32); \
                A.y += __shfl_xor(A.y, 16); A.y += __shfl_xor(A.y, 32);
    RED2(A0) RED2(A1) RED2(A2) RED2(A3)
#undef RED2
    if (q == 0) {                      // lanes 0..15 write the row (256B contiguous)
        float d = dis[node];
        const float4* bp = (const float4*)&b[c * 8];
        float4 b0 = bp[0], b1 = bp[1];
        uint4 w;
        w.x = pack2(b0.x + d * A0.x, b0.y + d * A0.y);
        w.y = pack2(b0.z + d * A1.x, b0.w + d * A1.y);
        w.z = pack2(b1.x + d * A2.x, b1.y + d * A2.y);
        w.w = pack2(b1.z + d * A3.x, b1.w + d * A3.y);
        unsigned int* base = (node < NSPL) ? (agg_lo + (size_t)node * 64)
                                           : (agg_hi + (size_t)(node - NSPL) * 64);
        *(uint4*)(base + c * 4) = w;
    }
}

// ---------------- stats: uint4 streaming, shfl+LDS reduce, dense partials ----------------
__global__ __launch_bounds__(256) void k_stats(const unsigned int* __restrict__ agg_lo,
                                               const unsigned int* __restrict__ agg_hi,
                                               float* __restrict__ partials) {
    __shared__ float lds[4][16][16];
    const int tid = threadIdx.x;
    const int lane = tid & 63, wave = tid >> 6;
    const uint4* lo4 = (const uint4*)agg_lo;
    const uint4* hi4 = (const uint4*)agg_hi;
    const long totalLo = (long)NSPL * 16;
    const long total   = (long)NN * 16;
    const long stride  = (long)SB * 256;
    float s[8], qq[8];
#pragma unroll
    for (int i = 0; i < 8; ++i) { s[i] = 0.f; qq[i] = 0.f; }
    for (long i = (long)blockIdx.x * 256 + tid; i < total; i += stride) {
        uint4 v = (i < totalLo) ? lo4[i] : hi4[i - totalLo];
        float f0 = blo(v.x), f1 = bhi(v.x), f2 = blo(v.y), f3 = bhi(v.y);
        float f4 = blo(v.z), f5 = bhi(v.z), f6 = blo(v.w), f7 = bhi(v.w);
        s[0] += f0; qq[0] += f0 * f0;  s[1] += f1; qq[1] += f1 * f1;
        s[2] += f2; qq[2] += f2 * f2;  s[3] += f3; qq[3] += f3 * f3;
        s[4] += f4; qq[4] += f4 * f4;  s[5] += f5; qq[5] += f5 * f5;
        s[6] += f6; qq[6] += f6 * f6;  s[7] += f7; qq[7] += f7 * f7;
    }
#pragma unroll
    for (int i = 0; i < 8; ++i) {
        s[i]  += __shfl_xor(s[i], 16);  s[i]  += __shfl_xor(s[i], 32);
        qq[i] += __shfl_xor(qq[i], 16); qq[i] += __shfl_xor(qq[i], 32);
    }
    if (lane < 16) {
#pragma unroll
        for (int i = 0; i < 8; ++i) {
            lds[wave][lane][i]     = s[i];
            lds[wave][lane][i + 8] = qq[i];
        }
    }
    __syncthreads();
    const int c4n = tid >> 4, slot = tid & 15;
    float v = lds[0][c4n][slot] + lds[1][c4n][slot] + lds[2][c4n][slot] + lds[3][c4n][slot];
    int f = c4n * 8 + (slot & 7);
    int idx = (slot < 8) ? f : (F + f);
    partials[(size_t)blockIdx.x * 256 + idx] = v;
}

// ---------------- reduce partials -> stats[256] (sums | sumsq) ----------------
__global__ __launch_bounds__(256) void k_red(const float* __restrict__ partials,
                                             float* __restrict__ stats) {
    float acc = 0.f;
    for (int bq = 0; bq < SB; ++bq) acc += partials[bq * 256 + threadIdx.x];
    stats[threadIdx.x] = acc;
}

// ---------------- fused norm + eicopy ----------------
// out0 = LeakyReLU(agg*A + Bc); for i < totalLo also out1[i] = float(ei[i])
// (same 16B range as the agg_lo[i] just read; opaque-asm dep forces load-before-store).
__global__ __launch_bounds__(256) void k_normei(const unsigned int* __restrict__ agg_lo,
                                               const unsigned int* __restrict__ agg_hi,
                                               const float* __restrict__ stats,
                                               const float* __restrict__ gw,
                                               const float* __restrict__ gb,
                                               const float* __restrict__ gms,
                                               float* __restrict__ out0,
                                               const int* __restrict__ ei,
                                               float* __restrict__ out1) {
    __shared__ float A[F], Bc[F];
    if (threadIdx.x < F) {
        int f = threadIdx.x;
        const float invn = 1.0f / (float)NN;
        float mean = stats[f] * invn;
        float ms = mean * gms[f];
        float var = stats[F + f] * invn - 2.0f * ms * mean + ms * ms;
        float inv = rsqrtf(var + EPS);
        float a = inv * gw[f];
        A[f] = a;
        Bc[f] = gb[f] - ms * a;
    }
    __syncthreads();
    const int c4 = threadIdx.x & 15;       // fixed uint4-column per thread
    float ra[8], rb[8];
#pragma unroll
    for (int i = 0; i < 8; ++i) { ra[i] = A[c4 * 8 + i]; rb[i] = Bc[c4 * 8 + i]; }
    const uint4* lo4 = (const uint4*)agg_lo;
    const uint4* hi4 = (const uint4*)agg_hi;
    const int4* ei4 = (const int4*)ei;
    float4* o14 = (float4*)out1;
    const long totalLo = (long)NSPL * 16;
    const long total   = (long)NN * 16;
    const long stride  = (long)gridDim.x * 256;
    for (long i = (long)blockIdx.x * 256 + threadIdx.x; i < total; i += stride) {
        bool isLo = i < totalLo;
        uint4 v = isLo ? lo4[i] : hi4[i - totalLo];
        float f0 = blo(v.x) * ra[0] + rb[0], f1 = bhi(v.x) * ra[1] + rb[1];
        float f2 = blo(v.y) * ra[2] + rb[2], f3 = bhi(v.y) * ra[3] + rb[3];
        float f4 = blo(v.z) * ra[4] + rb[4], f5 = bhi(v.z) * ra[5] + rb[5];
        float f6 = blo(v.w) * ra[6] + rb[6], f7 = bhi(v.w) * ra[7] + rb[7];
        f0 = f0 > 0.f ? f0 : SLOPE * f0;  f1 = f1 > 0.f ? f1 : SLOPE * f1;
        f2 = f2 > 0.f ? f2 : SLOPE * f2;  f3 = f3 > 0.f ? f3 : SLOPE * f3;
        f4 = f4 > 0.f ? f4 : SLOPE * f4;  f5 = f5 > 0.f ? f5 : SLOPE * f5;
        f6 = f6 > 0.f ? f6 : SLOPE * f6;  f7 = f7 > 0.f ? f7 : SLOPE * f7;
        float4 r0, r1;
        r0.x = f0; r0.y = f1; r0.z = f2; r0.w = f3;
        r1.x = f4; r1.y = f5; r1.z = f6; r1.w = f7;
        float* op = out0 + i * 8;
        *(float4*)op = r0;
        *(float4*)(op + 4) = r1;
        if (isLo) {
            int4 ev = ei4[i];
            unsigned int z;                       // opaque zero derived from v.x:
            asm("v_and_b32 %0, 0, %1" : "=v"(z) : "v"(v.x));
            float4 r;
            r.x = (float)(ev.x | (int)z);         // store depends on agg load
            r.y = (float)ev.y;
            r.z = (float)ev.z;
            r.w = (float)ev.w;
            o14[i] = r;
        }
    }
}

extern "C" void kernel_launch(void* const* d_in, const int* in_sizes, int n_in,
                              void* d_out, int out_size, void* d_ws, size_t ws_size,
                              hipStream_t stream) {
    const float* x   = (const float*)d_in[0];
    const int*   ei  = (const int*)d_in[1];
    const float* Wm  = (const float*)d_in[2];
    const float* b   = (const float*)d_in[3];
    const float* gw  = (const float*)d_in[4];
    const float* gb  = (const float*)d_in[5];
    const float* gms = (const float*)d_in[6];

    float* out  = (float*)d_out;                 // region0: NN*F, region1: 2*NE
    float* out1 = out + (size_t)NN * F;
    unsigned int* agg_lo = (unsigned int*)out1;  // NSPL*64 u32 = 2*NE u32, exact fit

    // ws layout (u32 units). ebuf aliases g: ebuf consumed by k_fill2 before k_gemm writes g.
    unsigned int* wsu   = (unsigned int*)d_ws;
    unsigned int* g     = wsu;                          // NN*64 u32 (25.6 MB)
    unsigned int* ebuf  = wsu;                          // NE u32 (6.4 MB) — alias of g
    unsigned int* mat   = g + (size_t)NN * 64;          // NBKT*B1 = 25088
    int* row_start      = (int*)(mat + NBKT * B1 + 64); // NN+1
    int* csr            = row_start + NN + 2;           // NE (+8 pad)
    float* dis          = (float*)(csr + NE + 8);       // NN
    float* stats        = dis + NN;                     // 256
    unsigned int* Wt    = (unsigned int*)(stats + 256); // 8192
    unsigned int* agg_hi = Wt + 8192;                   // (NN-NSPL)*64 u32 (12.8 MB)
    float* partials     = (float*)(agg_hi + (size_t)(NN - NSPL) * 64); // SB*256 (256 KB)

    k_wprep<<<32, 256, 0, stream>>>(Wm, Wt);
    k_hist1<<<B1, 1024, 0, stream>>>(ei + NE, mat);
    k_scan1<<<1, 1024, 0, stream>>>(mat);
    k_scat1<<<B1, 1024, 0, stream>>>(ei, mat, ebuf);
    k_fill2<<<NBKT, 1024, 0, stream>>>(mat, ebuf, row_start, dis, csr);
    k_gemm<<<(NN + 127) / 128, 256, 0, stream>>>(x, Wt, dis, (unsigned short*)g);
    k_gather<<<NN / 4, 256, 0, stream>>>(g, csr, row_start, dis, b, agg_lo, agg_hi);
    k_stats<<<SB, 256, 0, stream>>>(agg_lo, agg_hi, partials);
    k_red<<<1, 256, 0, stream>>>(partials, stats);
    k_normei<<<1024, 256, 0, stream>>>(agg_lo, agg_hi, stats, gw, gb, gms, out, ei, out1);
}

// Round 10
// 166.580 us; speedup vs baseline: 1.4874x; 1.1075x over previous
//
#include <hip/hip_runtime.h>

#define NN 100000
#define NE 1600000
#define F  128
#define NSPL 50000              // agg16 split: nodes < NSPL in out1, rest in ws

// radix partition params
#define SH   8                  // bucket = dst >> 8
#define NPB  256                // nodes per bucket
#define NBKT 391                // ceil(NN/256)
#define B1   256                // pass-1 blocks
#define CH1  6250               // NE / B1 exactly
#define MATN (NBKT * B1)        // 100096
#define MATP (98 * 1024)        // padded to scan grid (100352)
#define BCAP2 6144              // fill2 LDS stage cap (mean 4096, +32 sigma)

#define SB   256                // stats blocks (partials, no atomics)

constexpr float EPS   = 1e-5f;
constexpr float SLOPE = 0.01f;

typedef __attribute__((ext_vector_type(8))) short short8;
typedef __attribute__((ext_vector_type(4))) float f32x4;
typedef __attribute__((ext_vector_type(2))) float f32x2;

__device__ inline unsigned int bf16rne(float f) {
    unsigned int u = __float_as_uint(f);
    return (u + 0x7fffu + ((u >> 16) & 1u)) >> 16;
}
__device__ inline float blo(unsigned int u) { return __uint_as_float(u << 16); }
__device__ inline float bhi(unsigned int u) { return __uint_as_float(u & 0xffff0000u); }
__device__ inline unsigned int pack2(float a, float b) {
    return bf16rne(a) | (bf16rne(b) << 16);
}
__device__ inline f32x2 pkadd(f32x2 a, f32x2 b) {
    f32x2 d;
    asm("v_pk_add_f32 %0, %1, %2" : "=v"(d) : "v"(a), "v"(b));
    return d;
}
// lo exact; hi carries low-16-bit mantissa noise (<= 2^-8 relative) — fine vs threshold
__device__ inline f32x2 up2n(unsigned int u) {
    f32x2 r;
    r.x = __uint_as_float(u << 16);
    r.y = __uint_as_float(u);
    return r;
}

// ---------------- W prep (fragment-ordered bf16 tiles) ----------------
__global__ void k_wprep(const float* __restrict__ Wm, unsigned int* __restrict__ Wt) {
    int idx = blockIdx.x * 256 + threadIdx.x;   // 8192 total
    int p = idx & 3, lane = (idx >> 2) & 63, n = (idx >> 8) & 7, kk = idx >> 11;
    int k0 = kk * 32 + (lane >> 4) * 8 + 2 * p;
    int c  = n * 16 + (lane & 15);
    unsigned int lo = bf16rne(Wm[k0 * F + c]);
    unsigned int hi = bf16rne(Wm[(k0 + 1) * F + c]);
    Wt[idx] = lo | (hi << 16);
}

// ---------------- pass 1a: per-block bucket histogram (391 counters) ----------------
__global__ __launch_bounds__(1024) void k_hist1(const int* __restrict__ dst,
                                                unsigned int* __restrict__ mat) {
    __shared__ unsigned int h[NBKT];
    if (threadIdx.x < NBKT) h[threadIdx.x] = 0u;
    __syncthreads();
    const int e0 = blockIdx.x * CH1;
    for (int i = threadIdx.x; i < CH1; i += 1024)
        atomicAdd(&h[dst[e0 + i] >> SH], 1u);
    __syncthreads();
    if (threadIdx.x < NBKT) mat[threadIdx.x * B1 + blockIdx.x] = h[threadIdx.x];
}

// ---------------- hierarchical exclusive scan of mat (100096 entries) ----------------
__global__ __launch_bounds__(1024) void k_scanA(const unsigned int* __restrict__ mat,
                                                unsigned int* __restrict__ scn,
                                                unsigned int* __restrict__ bsums) {
    __shared__ unsigned int ps[1024];
    const int t = threadIdx.x;
    const int i = blockIdx.x * 1024 + t;        // grid 98*1024 == MATP
    unsigned int v = mat[i];                     // pad region: garbage, harmless
    ps[t] = v;
    __syncthreads();
    for (int off = 1; off < 1024; off <<= 1) {
        unsigned int a = (t >= off) ? ps[t - off] : 0u;
        __syncthreads();
        ps[t] += a;
        __syncthreads();
    }
    scn[i] = ps[t];                              // inclusive within block
    if (t == 1023) bsums[blockIdx.x] = ps[1023];
}

__global__ __launch_bounds__(128) void k_scanB(const unsigned int* __restrict__ bsums,
                                               unsigned int* __restrict__ boff) {
    __shared__ unsigned int ps[128];
    const int t = threadIdx.x;
    unsigned int v = (t < 98) ? bsums[t] : 0u;
    ps[t] = v;
    __syncthreads();
    for (int off = 1; off < 128; off <<= 1) {
        unsigned int a = (t >= off) ? ps[t - off] : 0u;
        __syncthreads();
        ps[t] += a;
        __syncthreads();
    }
    if (t < 98) boff[t] = ps[t] - v;             // exclusive block offsets
}

__global__ __launch_bounds__(1024) void k_scanC(const unsigned int* __restrict__ scn,
                                                const unsigned int* __restrict__ boff,
                                                unsigned int* __restrict__ mat) {
    const int i = blockIdx.x * 1024 + threadIdx.x;
    if (i < MATN) mat[i] = scn[i] + boff[i >> 10] - mat[i];   // exclusive, in place
}

// ---------------- pass 1c: scatter edges into bucket segments ----------------
__global__ __launch_bounds__(1024) void k_scat1(const int* __restrict__ ei,
                                                const unsigned int* __restrict__ mat,
                                                unsigned int* __restrict__ ebuf) {
    __shared__ unsigned int cur[NBKT];
    if (threadIdx.x < NBKT) cur[threadIdx.x] = mat[threadIdx.x * B1 + blockIdx.x];
    __syncthreads();
    const int e0 = blockIdx.x * CH1;
    for (int i = threadIdx.x; i < CH1; i += 1024) {
        int s = ei[e0 + i];
        int d = ei[NE + e0 + i];
        unsigned int pos = atomicAdd(&cur[d >> SH], 1u);
        ebuf[pos] = ((unsigned int)(d & (NPB - 1)) << 17) | (unsigned int)s;
    }
}

// ---------------- pass 2: LDS-staged per-bucket degree/scan/row_start/dis + csr ----------------
__global__ __launch_bounds__(256) void k_fill2(const unsigned int* __restrict__ mat,
                                               const unsigned int* __restrict__ ebuf,
                                               int* __restrict__ row_start,
                                               float* __restrict__ dis,
                                               int* __restrict__ csr) {
    __shared__ unsigned int stage[BCAP2];
    __shared__ unsigned int hist[NPB];
    __shared__ unsigned int cur[NPB];
    __shared__ unsigned int ps[NPB];
    const int t = threadIdx.x;
    const int bkt = blockIdx.x;
    hist[t] = 0u;
    __syncthreads();
    const unsigned int ebase = mat[bkt * B1];
    const unsigned int eend  = (bkt == NBKT - 1) ? (unsigned int)NE : mat[(bkt + 1) * B1];
    const unsigned int n = eend - ebase;
    const unsigned int m = (n < BCAP2) ? n : BCAP2;
    for (unsigned int i = t; i < m; i += 256) {
        unsigned int v = ebuf[ebase + i];
        stage[i] = v;
        atomicAdd(&hist[v >> 17], 1u);
    }
    for (unsigned int i = BCAP2 + t; i < n; i += 256)   // overflow path (≈never)
        atomicAdd(&hist[ebuf[ebase + i] >> 17], 1u);
    __syncthreads();
    const unsigned int deg = hist[t];
    ps[t] = deg;
    __syncthreads();
    for (int off = 1; off < 256; off <<= 1) {
        unsigned int a = (t >= off) ? ps[t - off] : 0u;
        __syncthreads();
        ps[t] += a;
        __syncthreads();
    }
    const unsigned int ex = (t == 0) ? 0u : ps[t - 1];
    cur[t] = ebase + ex;
    const int node = bkt * NPB + t;
    if (node <= NN) row_start[node] = (int)(ebase + ex);   // node==NN lands on NE
    if (node < NN)  dis[node] = rsqrtf((float)(deg + 1u));
    __syncthreads();
    for (unsigned int i = t; i < m; i += 256) {
        unsigned int v = stage[i];
        unsigned int pos = atomicAdd(&cur[v >> 17], 1u);
        csr[pos] = (int)(v & 0x1FFFFu);
    }
    for (unsigned int i = BCAP2 + t; i < n; i += 256) {   // overflow path
        unsigned int v = ebuf[ebase + i];
        unsigned int pos = atomicAdd(&cur[v >> 17], 1u);
        csr[pos] = (int)(v & 0x1FFFFu);
    }
}

// ---------------- MFMA GEMM: g = bf16(x @ W) * dis ----------------
__global__ __launch_bounds__(256) void k_gemm(const float* __restrict__ x,
                                              const unsigned int* __restrict__ Wt,
                                              const float* __restrict__ dis,
                                              unsigned short* __restrict__ g16) {
    __shared__ unsigned int xl[128 * 64];   // 32 KB bf16-pair tile
    const int tid = threadIdx.x;
    const int lane = tid & 63, wave = tid >> 6;
    const int row0 = blockIdx.x * 128;

#pragma unroll
    for (int i = 0; i < 16; ++i) {
        int fi = i * 256 + tid;            // 0..4095
        int lr = fi >> 5;                  // local row (32 thr/row)
        int cf = (fi & 31) * 4;            // f32 col
        int gr = row0 + lr; if (gr >= NN) gr = NN - 1;
        float4 v = *(const float4*)(x + (size_t)gr * F + cf);
        unsigned int u0 = pack2(v.x, v.y);
        unsigned int u1 = pack2(v.z, v.w);
        int cu = (cf >> 1) ^ ((lr & 7) << 2);
        uint2 w2; w2.x = u0; w2.y = u1;
        *(uint2*)&xl[lr * 64 + cu] = w2;
    }
    __syncthreads();

    const int rbase = row0 + wave * 32;
    short8 afr[2][4];
#pragma unroll
    for (int m = 0; m < 2; ++m) {
        int lr = wave * 32 + m * 16 + (lane & 15);
#pragma unroll
        for (int kk = 0; kk < 4; ++kk) {
            int cu = (kk * 16 + (lane >> 4) * 4) ^ ((lr & 7) << 2);
            afr[m][kk] = *(const short8*)&xl[lr * 64 + cu];
        }
    }

    f32x4 acc[2][8];
#pragma unroll
    for (int m = 0; m < 2; ++m)
#pragma unroll
        for (int n = 0; n < 8; ++n) { f32x4 z = {0.f, 0.f, 0.f, 0.f}; acc[m][n] = z; }

    const uint4* Wt4 = (const uint4*)Wt;
#pragma unroll
    for (int kk = 0; kk < 4; ++kk) {
        union { uint4 u; short8 s; } bfr[8];
#pragma unroll
        for (int n = 0; n < 8; ++n) bfr[n].u = Wt4[(kk * 8 + n) * 64 + lane];
#pragma unroll
        for (int m = 0; m < 2; ++m)
#pragma unroll
            for (int n = 0; n < 8; ++n)
                acc[m][n] = __builtin_amdgcn_mfma_f32_16x16x32_bf16(afr[m][kk], bfr[n].s, acc[m][n], 0, 0, 0);
    }

    float dv[2][4];
#pragma unroll
    for (int m = 0; m < 2; ++m)
#pragma unroll
        for (int r = 0; r < 4; ++r) {
            int row = rbase + m * 16 + (lane >> 4) * 4 + r;
            dv[m][r] = (row < NN) ? dis[row] : 0.0f;
        }
#pragma unroll
    for (int m = 0; m < 2; ++m)
#pragma unroll
        for (int n = 0; n < 8; ++n)
#pragma unroll
            for (int r = 0; r < 4; ++r) {
                int row = rbase + m * 16 + (lane >> 4) * 4 + r;
                if (row < NN) {
                    int col = n * 16 + (lane & 15);
                    g16[(size_t)row * F + col] = (unsigned short)bf16rne(acc[m][n][r] * dv[m][r]);
                }
            }
}

// ---------------- gather: agg16 = bf16(b + dis[n]*sum(g[src] over src ∪ {n})) ----------------
__global__ __launch_bounds__(256) void k_gather(const unsigned int* __restrict__ g,
                                                const int* __restrict__ csr,
                                                const int* __restrict__ row_start,
                                                const float* __restrict__ dis,
                                                const float* __restrict__ b,
                                                unsigned int* __restrict__ agg_lo,
                                                unsigned int* __restrict__ agg_hi) {
    const int lane = threadIdx.x & 63;
    const int node = blockIdx.x * 4 + (threadIdx.x >> 6);
    if (node >= NN) return;
    const int q = lane >> 4;           // row slot (0..3)
    const int c = lane & 15;           // uint4 col: features 8c..8c+7
    const int j = row_start[node];
    const int e = row_start[node + 1];
    const int L = e - j + 1;           // + self
    int sv = (j + lane < e) ? csr[j + lane] : node;   // preload ids; self past end
    f32x2 A0 = {0.f, 0.f}, A1 = A0, A2 = A0, A3 = A0;
    int k = 0;
    const int L1 = (L < 64) ? L : 64;
    for (; k < L1; k += 8) {
        int k0 = k + q, k1 = k0 + 4;
        int r0 = __shfl(sv, k0);
        int r1 = __shfl(sv, k1);
        bool p0 = k0 < L, p1 = k1 < L;
        uint4 v0, v1;
        if (p0) v0 = *(const uint4*)&g[(size_t)r0 * 64 + c * 4];
        if (p1) v1 = *(const uint4*)&g[(size_t)r1 * 64 + c * 4];
        if (p0) {
            A0 = pkadd(A0, up2n(v0.x)); A1 = pkadd(A1, up2n(v0.y));
            A2 = pkadd(A2, up2n(v0.z)); A3 = pkadd(A3, up2n(v0.w));
        }
        if (p1) {
            A0 = pkadd(A0, up2n(v1.x)); A1 = pkadd(A1, up2n(v1.y));
            A2 = pkadd(A2, up2n(v1.z)); A3 = pkadd(A3, up2n(v1.w));
        }
    }
    for (; k < L; k += 8) {            // rare: deg+1 > 64
        int k0 = k + q, k1 = k0 + 4;
        if (k0 < L) {
            int r0 = (j + k0 < e) ? csr[j + k0] : node;
            uint4 v = *(const uint4*)&g[(size_t)r0 * 64 + c * 4];
            A0 = pkadd(A0, up2n(v.x)); A1 = pkadd(A1, up2n(v.y));
            A2 = pkadd(A2, up2n(v.z)); A3 = pkadd(A3, up2n(v.w));
        }
        if (k1 < L) {
            int r1 = (j + k1 < e) ? csr[j + k1] : node;
            uint4 v = *(const uint4*)&g[(size_t)r1 * 64 + c * 4];
            A0 = pkadd(A0, up2n(v.x)); A1 = pkadd(A1, up2n(v.y));
            A2 = pkadd(A2, up2n(v.z)); A3 = pkadd(A3, up2n(v.w));
        }
    }
#define RED2(A) A.x += __shfl_xor(A.x, 16); A.x += __shfl_xor(A.x, 32); \
                A.y += __shfl_xor(A.y, 16); A.y += __shfl_xor(A.y, 32);
    RED2(A0) RED2(A1) RED2(A2) RED2(A3)
#undef RED2
    if (q == 0) {                      // lanes 0..15 write the row (256B contiguous)
        float d = dis[node];
        const float4* bp = (const float4*)&b[c * 8];
        float4 b0 = bp[0], b1 = bp[1];
        uint4 w;
        w.x = pack2(b0.x + d * A0.x, b0.y + d * A0.y);
        w.y = pack2(b0.z + d * A1.x, b0.w + d * A1.y);
        w.z = pack2(b1.x + d * A2.x, b1.y + d * A2.y);
        w.w = pack2(b1.z + d * A3.x, b1.w + d * A3.y);
        unsigned int* base = (node < NSPL) ? (agg_lo + (size_t)node * 64)
                                           : (agg_hi + (size_t)(node - NSPL) * 64);
        *(uint4*)(base + c * 4) = w;
    }
}

// ---------------- stats: uint4 streaming, shfl+LDS reduce, dense partials ----------------
__global__ __launch_bounds__(256) void k_stats(const unsigned int* __restrict__ agg_lo,
                                               const unsigned int* __restrict__ agg_hi,
                                               float* __restrict__ partials) {
    __shared__ float lds[4][16][16];
    const int tid = threadIdx.x;
    const int lane = tid & 63, wave = tid >> 6;
    const uint4* lo4 = (const uint4*)agg_lo;
    const uint4* hi4 = (const uint4*)agg_hi;
    const long totalLo = (long)NSPL * 16;
    const long total   = (long)NN * 16;
    const long stride  = (long)SB * 256;
    float s[8], qq[8];
#pragma unroll
    for (int i = 0; i < 8; ++i) { s[i] = 0.f; qq[i] = 0.f; }
    for (long i = (long)blockIdx.x * 256 + tid; i < total; i += stride) {
        uint4 v = (i < totalLo) ? lo4[i] : hi4[i - totalLo];
        float f0 = blo(v.x), f1 = bhi(v.x), f2 = blo(v.y), f3 = bhi(v.y);
        float f4 = blo(v.z), f5 = bhi(v.z), f6 = blo(v.w), f7 = bhi(v.w);
        s[0] += f0; qq[0] += f0 * f0;  s[1] += f1; qq[1] += f1 * f1;
        s[2] += f2; qq[2] += f2 * f2;  s[3] += f3; qq[3] += f3 * f3;
        s[4] += f4; qq[4] += f4 * f4;  s[5] += f5; qq[5] += f5 * f5;
        s[6] += f6; qq[6] += f6 * f6;  s[7] += f7; qq[7] += f7 * f7;
    }
#pragma unroll
    for (int i = 0; i < 8; ++i) {
        s[i]  += __shfl_xor(s[i], 16);  s[i]  += __shfl_xor(s[i], 32);
        qq[i] += __shfl_xor(qq[i], 16); qq[i] += __shfl_xor(qq[i], 32);
    }
    if (lane < 16) {
#pragma unroll
        for (int i = 0; i < 8; ++i) {
            lds[wave][lane][i]     = s[i];
            lds[wave][lane][i + 8] = qq[i];
        }
    }
    __syncthreads();
    const int c4n = tid >> 4, slot = tid & 15;
    float v = lds[0][c4n][slot] + lds[1][c4n][slot] + lds[2][c4n][slot] + lds[3][c4n][slot];
    int f = c4n * 8 + (slot & 7);
    int idx = (slot < 8) ? f : (F + f);
    partials[(size_t)blockIdx.x * 256 + idx] = v;
}

// ---------------- reduce partials -> stats[256] (sums | sumsq) ----------------
__global__ __launch_bounds__(256) void k_red(const float* __restrict__ partials,
                                             float* __restrict__ stats) {
    float a0 = 0.f, a1 = 0.f, a2 = 0.f, a3 = 0.f;
    for (int bq = 0; bq < SB; bq += 4) {
        a0 += partials[(bq + 0) * 256 + threadIdx.x];
        a1 += partials[(bq + 1) * 256 + threadIdx.x];
        a2 += partials[(bq + 2) * 256 + threadIdx.x];
        a3 += partials[(bq + 3) * 256 + threadIdx.x];
    }
    stats[threadIdx.x] = (a0 + a1) + (a2 + a3);
}

// ---------------- fused norm + eicopy ----------------
__global__ __launch_bounds__(256) void k_normei(const unsigned int* __restrict__ agg_lo,
                                               const unsigned int* __restrict__ agg_hi,
                                               const float* __restrict__ stats,
                                               const float* __restrict__ gw,
                                               const float* __restrict__ gb,
                                               const float* __restrict__ gms,
                                               float* __restrict__ out0,
                                               const int* __restrict__ ei,
                                               float* __restrict__ out1) {
    __shared__ float A[F], Bc[F];
    if (threadIdx.x < F) {
        int f = threadIdx.x;
        const float invn = 1.0f / (float)NN;
        float mean = stats[f] * invn;
        float ms = mean * gms[f];
        float var = stats[F + f] * invn - 2.0f * ms * mean + ms * ms;
        float inv = rsqrtf(var + EPS);
        float a = inv * gw[f];
        A[f] = a;
        Bc[f] = gb[f] - ms * a;
    }
    __syncthreads();
    const int c4 = threadIdx.x & 15;       // fixed uint4-column per thread
    float ra[8], rb[8];
#pragma unroll
    for (int i = 0; i < 8; ++i) { ra[i] = A[c4 * 8 + i]; rb[i] = Bc[c4 * 8 + i]; }
    const uint4* lo4 = (const uint4*)agg_lo;
    const uint4* hi4 = (const uint4*)agg_hi;
    const int4* ei4 = (const int4*)ei;
    float4* o14 = (float4*)out1;
    const long totalLo = (long)NSPL * 16;
    const long total   = (long)NN * 16;
    const long stride  = (long)gridDim.x * 256;
    for (long i = (long)blockIdx.x * 256 + threadIdx.x; i < total; i += stride) {
        bool isLo = i < totalLo;
        uint4 v = isLo ? lo4[i] : hi4[i - totalLo];
        float f0 = blo(v.x) * ra[0] + rb[0], f1 = bhi(v.x) * ra[1] + rb[1];
        float f2 = blo(v.y) * ra[2] + rb[2], f3 = bhi(v.y) * ra[3] + rb[3];
        float f4 = blo(v.z) * ra[4] + rb[4], f5 = bhi(v.z) * ra[5] + rb[5];
        float f6 = blo(v.w) * ra[6] + rb[6], f7 = bhi(v.w) * ra[7] + rb[7];
        f0 = f0 > 0.f ? f0 : SLOPE * f0;  f1 = f1 > 0.f ? f1 : SLOPE * f1;
        f2 = f2 > 0.f ? f2 : SLOPE * f2;  f3 = f3 > 0.f ? f3 : SLOPE * f3;
        f4 = f4 > 0.f ? f4 : SLOPE * f4;  f5 = f5 > 0.f ? f5 : SLOPE * f5;
        f6 = f6 > 0.f ? f6 : SLOPE * f6;  f7 = f7 > 0.f ? f7 : SLOPE * f7;
        float4 r0, r1;
        r0.x = f0; r0.y = f1; r0.z = f2; r0.w = f3;
        r1.x = f4; r1.y = f5; r1.z = f6; r1.w = f7;
        float* op = out0 + i * 8;
        *(float4*)op = r0;
        *(float4*)(op + 4) = r1;
        if (isLo) {
            int4 ev = ei4[i];
            unsigned int z;                       // opaque zero derived from v.x:
            asm("v_and_b32 %0, 0, %1" : "=v"(z) : "v"(v.x));
            float4 r;
            r.x = (float)(ev.x | (int)z);         // store depends on agg load
            r.y = (float)ev.y;
            r.z = (float)ev.z;
            r.w = (float)ev.w;
            o14[i] = r;
        }
    }
}

extern "C" void kernel_launch(void* const* d_in, const int* in_sizes, int n_in,
                              void* d_out, int out_size, void* d_ws, size_t ws_size,
                              hipStream_t stream) {
    const float* x   = (const float*)d_in[0];
    const int*   ei  = (const int*)d_in[1];
    const float* Wm  = (const float*)d_in[2];
    const float* b   = (const float*)d_in[3];
    const float* gw  = (const float*)d_in[4];
    const float* gb  = (const float*)d_in[5];
    const float* gms = (const float*)d_in[6];

    float* out  = (float*)d_out;                 // region0: NN*F, region1: 2*NE
    float* out1 = out + (size_t)NN * F;
    unsigned int* agg_lo = (unsigned int*)out1;  // NSPL*64 u32 = 2*NE u32, exact fit

    // ws layout (u32 units). ebuf aliases g: ebuf consumed by k_fill2 before k_gemm writes g.
    unsigned int* wsu   = (unsigned int*)d_ws;
    unsigned int* g     = wsu;                          // NN*64 u32 (25.6 MB)
    unsigned int* ebuf  = wsu;                          // NE u32 (6.4 MB) — alias of g
    unsigned int* mat   = g + (size_t)NN * 64;          // MATP (padded)
    unsigned int* scn   = mat + MATP;                   // MATP
    unsigned int* bsums = scn + MATP;                   // 128
    unsigned int* boff  = bsums + 128;                  // 128
    int* row_start      = (int*)(boff + 128);           // NN+1
    int* csr            = row_start + NN + 2;           // NE (+8 pad)
    float* dis          = (float*)(csr + NE + 8);       // NN
    float* stats        = dis + NN;                     // 256
    unsigned int* Wt    = (unsigned int*)(stats + 256); // 8192
    unsigned int* agg_hi = Wt + 8192;                   // (NN-NSPL)*64 u32 (12.8 MB)
    float* partials     = (float*)(agg_hi + (size_t)(NN - NSPL) * 64); // SB*256 (256 KB)

    k_wprep<<<32, 256, 0, stream>>>(Wm, Wt);
    k_hist1<<<B1, 1024, 0, stream>>>(ei + NE, mat);
    k_scanA<<<98, 1024, 0, stream>>>(mat, scn, bsums);
    k_scanB<<<1, 128, 0, stream>>>(bsums, boff);
    k_scanC<<<98, 1024, 0, stream>>>(scn, boff, mat);
    k_scat1<<<B1, 1024, 0, stream>>>(ei, mat, ebuf);
    k_fill2<<<NBKT, 256, 0, stream>>>(mat, ebuf, row_start, dis, csr);
    k_gemm<<<(NN + 127) / 128, 256, 0, stream>>>(x, Wt, dis, (unsigned short*)g);
    k_gather<<<NN / 4, 256, 0, stream>>>(g, csr, row_start, dis, b, agg_lo, agg_hi);
    k_stats<<<SB, 256, 0, stream>>>(agg_lo, agg_hi, partials);
    k_red<<<1, 256, 0, stream>>>(partials, stats);
    k_normei<<<1024, 256, 0, stream>>>(agg_lo, agg_hi, stats, gw, gb, gms, out, ei, out1);
}

// Round 11
// 164.629 us; speedup vs baseline: 1.5051x; 1.0118x over previous
//
#include <hip/hip_runtime.h>

#define NN 100000
#define NE 1600000
#define F  128
#define NSPL 50000              // agg16 split: nodes < NSPL in out1, rest in ws

// radix partition params
#define SH   8                  // bucket = dst >> 8
#define NPB  256                // nodes per bucket
#define NBKT 391                // ceil(NN/256)
#define B1   256                // pass-1 blocks
#define CH1  6250               // NE / B1 exactly
#define MATN (NBKT * B1)        // 100096
#define MATP (98 * 1024)        // padded to scan grid (100352)
#define BCAP2 6144              // fill2 LDS stage cap (mean 4096, +32 sigma)

#define SB   256                // stats blocks (partials, no atomics)

constexpr float EPS   = 1e-5f;
constexpr float SLOPE = 0.01f;

typedef __attribute__((ext_vector_type(8))) short short8;
typedef __attribute__((ext_vector_type(4))) float f32x4;
typedef __attribute__((ext_vector_type(2))) float f32x2;

__device__ inline unsigned int bf16rne(float f) {
    unsigned int u = __float_as_uint(f);
    return (u + 0x7fffu + ((u >> 16) & 1u)) >> 16;
}
__device__ inline float blo(unsigned int u) { return __uint_as_float(u << 16); }
__device__ inline float bhi(unsigned int u) { return __uint_as_float(u & 0xffff0000u); }
__device__ inline unsigned int pack2(float a, float b) {
    return bf16rne(a) | (bf16rne(b) << 16);
}
__device__ inline f32x2 pkadd(f32x2 a, f32x2 b) {
    f32x2 d;
    asm("v_pk_add_f32 %0, %1, %2" : "=v"(d) : "v"(a), "v"(b));
    return d;
}
// lo exact; hi carries low-16-bit mantissa noise (<= 2^-8 relative) — fine vs threshold
__device__ inline f32x2 up2n(unsigned int u) {
    f32x2 r;
    r.x = __uint_as_float(u << 16);
    r.y = __uint_as_float(u);
    return r;
}

// ---------------- W prep (fragment-ordered bf16 tiles) ----------------
__global__ void k_wprep(const float* __restrict__ Wm, unsigned int* __restrict__ Wt) {
    int idx = blockIdx.x * 256 + threadIdx.x;   // 8192 total
    int p = idx & 3, lane = (idx >> 2) & 63, n = (idx >> 8) & 7, kk = idx >> 11;
    int k0 = kk * 32 + (lane >> 4) * 8 + 2 * p;
    int c  = n * 16 + (lane & 15);
    unsigned int lo = bf16rne(Wm[k0 * F + c]);
    unsigned int hi = bf16rne(Wm[(k0 + 1) * F + c]);
    Wt[idx] = lo | (hi << 16);
}

// ---------------- pass 1a: per-block bucket histogram (391 counters) ----------------
__global__ __launch_bounds__(1024) void k_hist1(const int* __restrict__ dst,
                                                unsigned int* __restrict__ mat) {
    __shared__ unsigned int h[NBKT];
    if (threadIdx.x < NBKT) h[threadIdx.x] = 0u;
    __syncthreads();
    const int e0 = blockIdx.x * CH1;
    for (int i = threadIdx.x; i < CH1; i += 1024)
        atomicAdd(&h[dst[e0 + i] >> SH], 1u);
    __syncthreads();
    if (threadIdx.x < NBKT) mat[threadIdx.x * B1 + blockIdx.x] = h[threadIdx.x];
}

// ---------------- hierarchical scan of mat (inclusive per block + block offsets) ----------------
__global__ __launch_bounds__(1024) void k_scanA(const unsigned int* __restrict__ mat,
                                                unsigned int* __restrict__ scn,
                                                unsigned int* __restrict__ bsums) {
    __shared__ unsigned int ps[1024];
    const int t = threadIdx.x;
    const int i = blockIdx.x * 1024 + t;        // grid 98*1024 == MATP
    unsigned int v = mat[i];                     // pad region: garbage, harmless
    ps[t] = v;
    __syncthreads();
    for (int off = 1; off < 1024; off <<= 1) {
        unsigned int a = (t >= off) ? ps[t - off] : 0u;
        __syncthreads();
        ps[t] += a;
        __syncthreads();
    }
    scn[i] = ps[t];                              // inclusive within block
    if (t == 1023) bsums[blockIdx.x] = ps[1023];
}

__global__ __launch_bounds__(128) void k_scanB(const unsigned int* __restrict__ bsums,
                                               unsigned int* __restrict__ boff) {
    __shared__ unsigned int ps[128];
    const int t = threadIdx.x;
    unsigned int v = (t < 98) ? bsums[t] : 0u;
    ps[t] = v;
    __syncthreads();
    for (int off = 1; off < 128; off <<= 1) {
        unsigned int a = (t >= off) ? ps[t - off] : 0u;
        __syncthreads();
        ps[t] += a;
        __syncthreads();
    }
    if (t < 98) boff[t] = ps[t] - v;             // exclusive block offsets
}

// exclusive(i) = scn[i] + boff[i>>10] - mat[i]   (computed inline by consumers)

// ---------------- pass 1c: scatter edges into bucket segments ----------------
__global__ __launch_bounds__(1024) void k_scat1(const int* __restrict__ ei,
                                                const unsigned int* __restrict__ mat,
                                                const unsigned int* __restrict__ scn,
                                                const unsigned int* __restrict__ boff,
                                                unsigned int* __restrict__ ebuf) {
    __shared__ unsigned int cur[NBKT];
    if (threadIdx.x < NBKT) {
        int idx = threadIdx.x * B1 + blockIdx.x;
        cur[threadIdx.x] = scn[idx] + boff[idx >> 10] - mat[idx];
    }
    __syncthreads();
    const int e0 = blockIdx.x * CH1;
    for (int i = threadIdx.x; i < CH1; i += 1024) {
        int s = ei[e0 + i];
        int d = ei[NE + e0 + i];
        unsigned int pos = atomicAdd(&cur[d >> SH], 1u);
        ebuf[pos] = ((unsigned int)(d & (NPB - 1)) << 17) | (unsigned int)s;
    }
}

// ---------------- pass 2: LDS-staged per-bucket degree/scan/row_start/dis + csr ----------------
__global__ __launch_bounds__(256) void k_fill2(const unsigned int* __restrict__ mat,
                                               const unsigned int* __restrict__ scn,
                                               const unsigned int* __restrict__ boff,
                                               const unsigned int* __restrict__ ebuf,
                                               int* __restrict__ row_start,
                                               float* __restrict__ dis,
                                               int* __restrict__ csr) {
    __shared__ unsigned int stage[BCAP2];
    __shared__ unsigned int hist[NPB];
    __shared__ unsigned int cur[NPB];
    __shared__ unsigned int ps[NPB];
    const int t = threadIdx.x;
    const int bkt = blockIdx.x;
    hist[t] = 0u;
    __syncthreads();
    const int i0 = bkt * B1;
    const unsigned int ebase = scn[i0] + boff[i0 >> 10] - mat[i0];
    unsigned int eend;
    if (bkt == NBKT - 1) eend = (unsigned int)NE;
    else {
        const int i1 = (bkt + 1) * B1;
        eend = scn[i1] + boff[i1 >> 10] - mat[i1];
    }
    const unsigned int n = eend - ebase;
    const unsigned int m = (n < BCAP2) ? n : BCAP2;
    for (unsigned int i = t; i < m; i += 256) {
        unsigned int v = ebuf[ebase + i];
        stage[i] = v;
        atomicAdd(&hist[v >> 17], 1u);
    }
    for (unsigned int i = BCAP2 + t; i < n; i += 256)   // overflow path (≈never)
        atomicAdd(&hist[ebuf[ebase + i] >> 17], 1u);
    __syncthreads();
    const unsigned int deg = hist[t];
    ps[t] = deg;
    __syncthreads();
    for (int off = 1; off < 256; off <<= 1) {
        unsigned int a = (t >= off) ? ps[t - off] : 0u;
        __syncthreads();
        ps[t] += a;
        __syncthreads();
    }
    const unsigned int ex = (t == 0) ? 0u : ps[t - 1];
    cur[t] = ebase + ex;
    const int node = bkt * NPB + t;
    if (node <= NN) row_start[node] = (int)(ebase + ex);   // node==NN lands on NE
    if (node < NN)  dis[node] = rsqrtf((float)(deg + 1u));
    __syncthreads();
    for (unsigned int i = t; i < m; i += 256) {
        unsigned int v = stage[i];
        unsigned int pos = atomicAdd(&cur[v >> 17], 1u);
        csr[pos] = (int)(v & 0x1FFFFu);
    }
    for (unsigned int i = BCAP2 + t; i < n; i += 256) {   // overflow path
        unsigned int v = ebuf[ebase + i];
        unsigned int pos = atomicAdd(&cur[v >> 17], 1u);
        csr[pos] = (int)(v & 0x1FFFFu);
    }
}

// ---------------- MFMA GEMM: g = bf16(x @ W) * dis ----------------
__global__ __launch_bounds__(256) void k_gemm(const float* __restrict__ x,
                                              const unsigned int* __restrict__ Wt,
                                              const float* __restrict__ dis,
                                              unsigned short* __restrict__ g16) {
    __shared__ unsigned int xl[128 * 64];   // 32 KB bf16-pair tile
    const int tid = threadIdx.x;
    const int lane = tid & 63, wave = tid >> 6;
    const int row0 = blockIdx.x * 128;

#pragma unroll
    for (int i = 0; i < 16; ++i) {
        int fi = i * 256 + tid;            // 0..4095
        int lr = fi >> 5;                  // local row (32 thr/row)
        int cf = (fi & 31) * 4;            // f32 col
        int gr = row0 + lr; if (gr >= NN) gr = NN - 1;
        float4 v = *(const float4*)(x + (size_t)gr * F + cf);
        unsigned int u0 = pack2(v.x, v.y);
        unsigned int u1 = pack2(v.z, v.w);
        int cu = (cf >> 1) ^ ((lr & 7) << 2);
        uint2 w2; w2.x = u0; w2.y = u1;
        *(uint2*)&xl[lr * 64 + cu] = w2;
    }
    __syncthreads();

    const int rbase = row0 + wave * 32;
    short8 afr[2][4];
#pragma unroll
    for (int m = 0; m < 2; ++m) {
        int lr = wave * 32 + m * 16 + (lane & 15);
#pragma unroll
        for (int kk = 0; kk < 4; ++kk) {
            int cu = (kk * 16 + (lane >> 4) * 4) ^ ((lr & 7) << 2);
            afr[m][kk] = *(const short8*)&xl[lr * 64 + cu];
        }
    }

    f32x4 acc[2][8];
#pragma unroll
    for (int m = 0; m < 2; ++m)
#pragma unroll
        for (int n = 0; n < 8; ++n) { f32x4 z = {0.f, 0.f, 0.f, 0.f}; acc[m][n] = z; }

    const uint4* Wt4 = (const uint4*)Wt;
#pragma unroll
    for (int kk = 0; kk < 4; ++kk) {
        union { uint4 u; short8 s; } bfr[8];
#pragma unroll
        for (int n = 0; n < 8; ++n) bfr[n].u = Wt4[(kk * 8 + n) * 64 + lane];
#pragma unroll
        for (int m = 0; m < 2; ++m)
#pragma unroll
            for (int n = 0; n < 8; ++n)
                acc[m][n] = __builtin_amdgcn_mfma_f32_16x16x32_bf16(afr[m][kk], bfr[n].s, acc[m][n], 0, 0, 0);
    }

    float dv[2][4];
#pragma unroll
    for (int m = 0; m < 2; ++m)
#pragma unroll
        for (int r = 0; r < 4; ++r) {
            int row = rbase + m * 16 + (lane >> 4) * 4 + r;
            dv[m][r] = (row < NN) ? dis[row] : 0.0f;
        }
#pragma unroll
    for (int m = 0; m < 2; ++m)
#pragma unroll
        for (int n = 0; n < 8; ++n)
#pragma unroll
            for (int r = 0; r < 4; ++r) {
                int row = rbase + m * 16 + (lane >> 4) * 4 + r;
                if (row < NN) {
                    int col = n * 16 + (lane & 15);
                    g16[(size_t)row * F + col] = (unsigned short)bf16rne(acc[m][n][r] * dv[m][r]);
                }
            }
}

// ---------------- gather: agg16 = bf16(b + dis[n]*sum(g[src] over src ∪ {n})) ----------------
// wave per node; 16 lanes/row (uint4), 4 row-slots, 4 rows unrolled per iter
// (4 loads in flight); f32x2 + v_pk_add_f32; 2-stage shfl reduce; bf16-pair out.
__global__ __launch_bounds__(256) void k_gather(const unsigned int* __restrict__ g,
                                                const int* __restrict__ csr,
                                                const int* __restrict__ row_start,
                                                const float* __restrict__ dis,
                                                const float* __restrict__ b,
                                                unsigned int* __restrict__ agg_lo,
                                                unsigned int* __restrict__ agg_hi) {
    const int lane = threadIdx.x & 63;
    const int node = blockIdx.x * 4 + (threadIdx.x >> 6);
    if (node >= NN) return;
    const int q = lane >> 4;           // row slot (0..3)
    const int c = lane & 15;           // uint4 col: features 8c..8c+7
    const int j = row_start[node];
    const int e = row_start[node + 1];
    const int L = e - j + 1;           // + self
    int sv = (j + lane < e) ? csr[j + lane] : node;   // preload ids; self past end
    f32x2 A0 = {0.f, 0.f}, A1 = A0, A2 = A0, A3 = A0;
    int k = 0;
    const int L1 = (L < 64) ? L : 64;
    for (; k < L1; k += 16) {
        int k0 = k + q, k1 = k0 + 4, k2 = k0 + 8, k3 = k0 + 12;
        int r0 = __shfl(sv, k0);
        int r1 = __shfl(sv, k1);
        int r2 = __shfl(sv, k2);
        int r3 = __shfl(sv, k3);
        bool p0 = k0 < L, p1 = k1 < L, p2 = k2 < L, p3 = k3 < L;
        uint4 v0, v1, v2, v3;
        if (p0) v0 = *(const uint4*)&g[(size_t)r0 * 64 + c * 4];
        if (p1) v1 = *(const uint4*)&g[(size_t)r1 * 64 + c * 4];
        if (p2) v2 = *(const uint4*)&g[(size_t)r2 * 64 + c * 4];
        if (p3) v3 = *(const uint4*)&g[(size_t)r3 * 64 + c * 4];
        if (p0) {
            A0 = pkadd(A0, up2n(v0.x)); A1 = pkadd(A1, up2n(v0.y));
            A2 = pkadd(A2, up2n(v0.z)); A3 = pkadd(A3, up2n(v0.w));
        }
        if (p1) {
            A0 = pkadd(A0, up2n(v1.x)); A1 = pkadd(A1, up2n(v1.y));
            A2 = pkadd(A2, up2n(v1.z)); A3 = pkadd(A3, up2n(v1.w));
        }
        if (p2) {
            A0 = pkadd(A0, up2n(v2.x)); A1 = pkadd(A1, up2n(v2.y));
            A2 = pkadd(A2, up2n(v2.z)); A3 = pkadd(A3, up2n(v2.w));
        }
        if (p3) {
            A0 = pkadd(A0, up2n(v3.x)); A1 = pkadd(A1, up2n(v3.y));
            A2 = pkadd(A2, up2n(v3.z)); A3 = pkadd(A3, up2n(v3.w));
        }
    }
    for (; k < L; k += 16) {           // rare: deg+1 > 64
#pragma unroll
        for (int s = 0; s < 4; ++s) {
            int ks = k + q + s * 4;
            if (ks < L) {
                int rs = (j + ks < e) ? csr[j + ks] : node;
                uint4 v = *(const uint4*)&g[(size_t)rs * 64 + c * 4];
                A0 = pkadd(A0, up2n(v.x)); A1 = pkadd(A1, up2n(v.y));
                A2 = pkadd(A2, up2n(v.z)); A3 = pkadd(A3, up2n(v.w));
            }
        }
    }
#define RED2(A) A.x += __shfl_xor(A.x, 16); A.x += __shfl_xor(A.x, 32); \
                A.y += __shfl_xor(A.y, 16); A.y += __shfl_xor(A.y, 32);
    RED2(A0) RED2(A1) RED2(A2) RED2(A3)
#undef RED2
    if (q == 0) {                      // lanes 0..15 write the row (256B contiguous)
        float d = dis[node];
        const float4* bp = (const float4*)&b[c * 8];
        float4 b0 = bp[0], b1 = bp[1];
        uint4 w;
        w.x = pack2(b0.x + d * A0.x, b0.y + d * A0.y);
        w.y = pack2(b0.z + d * A1.x, b0.w + d * A1.y);
        w.z = pack2(b1.x + d * A2.x, b1.y + d * A2.y);
        w.w = pack2(b1.z + d * A3.x, b1.w + d * A3.y);
        unsigned int* base = (node < NSPL) ? (agg_lo + (size_t)node * 64)
                                           : (agg_hi + (size_t)(node - NSPL) * 64);
        *(uint4*)(base + c * 4) = w;
    }
}

// ---------------- stats: uint4 streaming, shfl+LDS reduce, dense partials ----------------
__global__ __launch_bounds__(256) void k_stats(const unsigned int* __restrict__ agg_lo,
                                               const unsigned int* __restrict__ agg_hi,
                                               float* __restrict__ partials) {
    __shared__ float lds[4][16][16];
    const int tid = threadIdx.x;
    const int lane = tid & 63, wave = tid >> 6;
    const uint4* lo4 = (const uint4*)agg_lo;
    const uint4* hi4 = (const uint4*)agg_hi;
    const long totalLo = (long)NSPL * 16;
    const long total   = (long)NN * 16;
    const long stride  = (long)SB * 256;
    float s[8], qq[8];
#pragma unroll
    for (int i = 0; i < 8; ++i) { s[i] = 0.f; qq[i] = 0.f; }
    for (long i = (long)blockIdx.x * 256 + tid; i < total; i += stride) {
        uint4 v = (i < totalLo) ? lo4[i] : hi4[i - totalLo];
        float f0 = blo(v.x), f1 = bhi(v.x), f2 = blo(v.y), f3 = bhi(v.y);
        float f4 = blo(v.z), f5 = bhi(v.z), f6 = blo(v.w), f7 = bhi(v.w);
        s[0] += f0; qq[0] += f0 * f0;  s[1] += f1; qq[1] += f1 * f1;
        s[2] += f2; qq[2] += f2 * f2;  s[3] += f3; qq[3] += f3 * f3;
        s[4] += f4; qq[4] += f4 * f4;  s[5] += f5; qq[5] += f5 * f5;
        s[6] += f6; qq[6] += f6 * f6;  s[7] += f7; qq[7] += f7 * f7;
    }
#pragma unroll
    for (int i = 0; i < 8; ++i) {
        s[i]  += __shfl_xor(s[i], 16);  s[i]  += __shfl_xor(s[i], 32);
        qq[i] += __shfl_xor(qq[i], 16); qq[i] += __shfl_xor(qq[i], 32);
    }
    if (lane < 16) {
#pragma unroll
        for (int i = 0; i < 8; ++i) {
            lds[wave][lane][i]     = s[i];
            lds[wave][lane][i + 8] = qq[i];
        }
    }
    __syncthreads();
    const int c4n = tid >> 4, slot = tid & 15;
    float v = lds[0][c4n][slot] + lds[1][c4n][slot] + lds[2][c4n][slot] + lds[3][c4n][slot];
    int f = c4n * 8 + (slot & 7);
    int idx = (slot < 8) ? f : (F + f);
    partials[(size_t)blockIdx.x * 256 + idx] = v;
}

// ---------------- reduce partials -> stats[256] (sums | sumsq) ----------------
__global__ __launch_bounds__(256) void k_red(const float* __restrict__ partials,
                                             float* __restrict__ stats) {
    float a0 = 0.f, a1 = 0.f, a2 = 0.f, a3 = 0.f;
    for (int bq = 0; bq < SB; bq += 4) {
        a0 += partials[(bq + 0) * 256 + threadIdx.x];
        a1 += partials[(bq + 1) * 256 + threadIdx.x];
        a2 += partials[(bq + 2) * 256 + threadIdx.x];
        a3 += partials[(bq + 3) * 256 + threadIdx.x];
    }
    stats[threadIdx.x] = (a0 + a1) + (a2 + a3);
}

// ---------------- fused norm + eicopy ----------------
__global__ __launch_bounds__(256) void k_normei(const unsigned int* __restrict__ agg_lo,
                                               const unsigned int* __restrict__ agg_hi,
                                               const float* __restrict__ stats,
                                               const float* __restrict__ gw,
                                               const float* __restrict__ gb,
                                               const float* __restrict__ gms,
                                               float* __restrict__ out0,
                                               const int* __restrict__ ei,
                                               float* __restrict__ out1) {
    __shared__ float A[F], Bc[F];
    if (threadIdx.x < F) {
        int f = threadIdx.x;
        const float invn = 1.0f / (float)NN;
        float mean = stats[f] * invn;
        float ms = mean * gms[f];
        float var = stats[F + f] * invn - 2.0f * ms * mean + ms * ms;
        float inv = rsqrtf(var + EPS);
        float a = inv * gw[f];
        A[f] = a;
        Bc[f] = gb[f] - ms * a;
    }
    __syncthreads();
    const int c4 = threadIdx.x & 15;       // fixed uint4-column per thread
    float ra[8], rb[8];
#pragma unroll
    for (int i = 0; i < 8; ++i) { ra[i] = A[c4 * 8 + i]; rb[i] = Bc[c4 * 8 + i]; }
    const uint4* lo4 = (const uint4*)agg_lo;
    const uint4* hi4 = (const uint4*)agg_hi;
    const int4* ei4 = (const int4*)ei;
    float4* o14 = (float4*)out1;
    const long totalLo = (long)NSPL * 16;
    const long total   = (long)NN * 16;
    const long stride  = (long)gridDim.x * 256;
    for (long i = (long)blockIdx.x * 256 + threadIdx.x; i < total; i += stride) {
        bool isLo = i < totalLo;
        uint4 v = isLo ? lo4[i] : hi4[i - totalLo];
        float f0 = blo(v.x) * ra[0] + rb[0], f1 = bhi(v.x) * ra[1] + rb[1];
        float f2 = blo(v.y) * ra[2] + rb[2], f3 = bhi(v.y) * ra[3] + rb[3];
        float f4 = blo(v.z) * ra[4] + rb[4], f5 = bhi(v.z) * ra[5] + rb[5];
        float f6 = blo(v.w) * ra[6] + rb[6], f7 = bhi(v.w) * ra[7] + rb[7];
        f0 = f0 > 0.f ? f0 : SLOPE * f0;  f1 = f1 > 0.f ? f1 : SLOPE * f1;
        f2 = f2 > 0.f ? f2 : SLOPE * f2;  f3 = f3 > 0.f ? f3 : SLOPE * f3;
        f4 = f4 > 0.f ? f4 : SLOPE * f4;  f5 = f5 > 0.f ? f5 : SLOPE * f5;
        f6 = f6 > 0.f ? f6 : SLOPE * f6;  f7 = f7 > 0.f ? f7 : SLOPE * f7;
        float4 r0, r1;
        r0.x = f0; r0.y = f1; r0.z = f2; r0.w = f3;
        r1.x = f4; r1.y = f5; r1.z = f6; r1.w = f7;
        float* op = out0 + i * 8;
        *(float4*)op = r0;
        *(float4*)(op + 4) = r1;
        if (isLo) {
            int4 ev = ei4[i];
            unsigned int z;                       // opaque zero derived from v.x:
            asm("v_and_b32 %0, 0, %1" : "=v"(z) : "v"(v.x));
            float4 r;
            r.x = (float)(ev.x | (int)z);         // store depends on agg load
            r.y = (float)ev.y;
            r.z = (float)ev.z;
            r.w = (float)ev.w;
            o14[i] = r;
        }
    }
}

extern "C" void kernel_launch(void* const* d_in, const int* in_sizes, int n_in,
                              void* d_out, int out_size, void* d_ws, size_t ws_size,
                              hipStream_t stream) {
    const float* x   = (const float*)d_in[0];
    const int*   ei  = (const int*)d_in[1];
    const float* Wm  = (const float*)d_in[2];
    const float* b   = (const float*)d_in[3];
    const float* gw  = (const float*)d_in[4];
    const float* gb  = (const float*)d_in[5];
    const float* gms = (const float*)d_in[6];

    float* out  = (float*)d_out;                 // region0: NN*F, region1: 2*NE
    float* out1 = out + (size_t)NN * F;
    unsigned int* agg_lo = (unsigned int*)out1;  // NSPL*64 u32 = 2*NE u32, exact fit

    // ws layout (u32 units). ebuf aliases g: ebuf consumed by k_fill2 before k_gemm writes g.
    unsigned int* wsu   = (unsigned int*)d_ws;
    unsigned int* g     = wsu;                          // NN*64 u32 (25.6 MB)
    unsigned int* ebuf  = wsu;                          // NE u32 (6.4 MB) — alias of g
    unsigned int* mat   = g + (size_t)NN * 64;          // MATP (padded)
    unsigned int* scn   = mat + MATP;                   // MATP
    unsigned int* bsums = scn + MATP;                   // 128
    unsigned int* boff  = bsums + 128;                  // 128
    int* row_start      = (int*)(boff + 128);           // NN+1
    int* csr            = row_start + NN + 2;           // NE (+8 pad)
    float* dis          = (float*)(csr + NE + 8);       // NN
    float* stats        = dis + NN;                     // 256
    unsigned int* Wt    = (unsigned int*)(stats + 256); // 8192
    unsigned int* agg_hi = Wt + 8192;                   // (NN-NSPL)*64 u32 (12.8 MB)
    float* partials     = (float*)(agg_hi + (size_t)(NN - NSPL) * 64); // SB*256 (256 KB)

    k_wprep<<<32, 256, 0, stream>>>(Wm, Wt);
    k_hist1<<<B1, 1024, 0, stream>>>(ei + NE, mat);
    k_scanA<<<98, 1024, 0, stream>>>(mat, scn, bsums);
    k_scanB<<<1, 128, 0, stream>>>(bsums, boff);
    k_scat1<<<B1, 1024, 0, stream>>>(ei, mat, scn, boff, ebuf);
    k_fill2<<<NBKT, 256, 0, stream>>>(mat, scn, boff, ebuf, row_start, dis, csr);
    k_gemm<<<(NN + 127) / 128, 256, 0, stream>>>(x, Wt, dis, (unsigned short*)g);
    k_gather<<<NN / 4, 256, 0, stream>>>(g, csr, row_start, dis, b, agg_lo, agg_hi);
    k_stats<<<SB, 256, 0, stream>>>(agg_lo, agg_hi, partials);
    k_red<<<1, 256, 0, stream>>>(partials, stats);
    k_normei<<<1024, 256, 0, stream>>>(agg_lo, agg_hi, stats, gw, gb, gms, out, ei, out1);
}

// Round 12
// 155.781 us; speedup vs baseline: 1.5906x; 1.0568x over previous
//
#include <hip/hip_runtime.h>

#define NN 100000
#define NE 1600000
#define F  128
#define NSPL 50000              // agg16 split: nodes < NSPL in out1, rest in ws

// radix partition params
#define SH   8                  // bucket = dst >> 8
#define NPB  256                // nodes per bucket
#define NBKT 391                // ceil(NN/256)
#define B1   256                // pass-1 blocks
#define CH1  6250               // NE / B1 exactly
#define MATN (NBKT * B1)        // 100096
#define MATP (98 * 1024)        // padded to scan grid (100352)
#define BCAP2 6144              // fill2 LDS stage cap (mean 4096, +32 sigma)

#define SB   256                // stats blocks (partials, no atomics)

constexpr float EPS   = 1e-5f;
constexpr float SLOPE = 0.01f;

typedef __attribute__((ext_vector_type(8))) short short8;
typedef __attribute__((ext_vector_type(4))) float f32x4;
typedef __attribute__((ext_vector_type(2))) float f32x2;

__device__ inline unsigned int bf16rne(float f) {
    unsigned int u = __float_as_uint(f);
    return (u + 0x7fffu + ((u >> 16) & 1u)) >> 16;
}
__device__ inline float blo(unsigned int u) { return __uint_as_float(u << 16); }
__device__ inline float bhi(unsigned int u) { return __uint_as_float(u & 0xffff0000u); }
__device__ inline unsigned int pack2(float a, float b) {
    return bf16rne(a) | (bf16rne(b) << 16);
}
__device__ inline f32x2 pkadd(f32x2 a, f32x2 b) {
    f32x2 d;
    asm("v_pk_add_f32 %0, %1, %2" : "=v"(d) : "v"(a), "v"(b));
    return d;
}
// lo exact; hi carries low-16-bit mantissa noise (<= 2^-8 relative) — fine vs threshold
__device__ inline f32x2 up2n(unsigned int u) {
    f32x2 r;
    r.x = __uint_as_float(u << 16);
    r.y = __uint_as_float(u);
    return r;
}

// ---------------- pass 1a: per-block bucket histogram + (blocks 0-7) W prep ----------------
__global__ __launch_bounds__(1024) void k_hist1(const int* __restrict__ dst,
                                                unsigned int* __restrict__ mat,
                                                const float* __restrict__ Wm,
                                                unsigned int* __restrict__ Wt) {
    __shared__ unsigned int h[NBKT];
    if (threadIdx.x < NBKT) h[threadIdx.x] = 0u;
    __syncthreads();
    if (blockIdx.x < 8) {                        // fused W prep (8192 entries)
        int idx = blockIdx.x * 1024 + threadIdx.x;
        int p = idx & 3, lane = (idx >> 2) & 63, n = (idx >> 8) & 7, kk = idx >> 11;
        int k0 = kk * 32 + (lane >> 4) * 8 + 2 * p;
        int c  = n * 16 + (lane & 15);
        unsigned int lo = bf16rne(Wm[k0 * F + c]);
        unsigned int hi = bf16rne(Wm[(k0 + 1) * F + c]);
        Wt[idx] = lo | (hi << 16);
    }
    const int e0 = blockIdx.x * CH1;
    for (int i = threadIdx.x; i < CH1; i += 1024)
        atomicAdd(&h[dst[e0 + i] >> SH], 1u);
    __syncthreads();
    if (threadIdx.x < NBKT) mat[threadIdx.x * B1 + blockIdx.x] = h[threadIdx.x];
}

// ---------------- scanA: inclusive per 1024-block + block sums ----------------
__global__ __launch_bounds__(1024) void k_scanA(const unsigned int* __restrict__ mat,
                                                unsigned int* __restrict__ scn,
                                                unsigned int* __restrict__ bsums) {
    __shared__ unsigned int ps[1024];
    const int t = threadIdx.x;
    const int i = blockIdx.x * 1024 + t;        // grid 98*1024 == MATP
    unsigned int v = mat[i];                     // pad region: garbage, harmless
    ps[t] = v;
    __syncthreads();
    for (int off = 1; off < 1024; off <<= 1) {
        unsigned int a = (t >= off) ? ps[t - off] : 0u;
        __syncthreads();
        ps[t] += a;
        __syncthreads();
    }
    scn[i] = ps[t];                              // inclusive within block
    if (t == 1023) bsums[blockIdx.x] = ps[1023];
}

// exclusive(i) = scn[i] + boff[i>>10] - mat[i]; boff computed in-block from bsums

// ---------------- pass 1c: scatter edges into bucket segments ----------------
__global__ __launch_bounds__(1024) void k_scat1(const int* __restrict__ ei,
                                                const unsigned int* __restrict__ mat,
                                                const unsigned int* __restrict__ scn,
                                                const unsigned int* __restrict__ bsums,
                                                unsigned int* __restrict__ ebuf) {
    __shared__ unsigned int cur[NBKT];
    __shared__ unsigned int bo[128];
    const int t = threadIdx.x;
    if (t < 128) {                               // 98-entry exclusive scan of bsums
        unsigned int v = (t < 98) ? bsums[t] : 0u;
        bo[t] = v;
        for (int off = 1; off < 128; off <<= 1) {
            __syncthreads();
            unsigned int a = (t >= off) ? bo[t - off] : 0u;
            __syncthreads();
            bo[t] += a;
        }
        bo[t] -= v;                              // exclusive
    } else {
        for (int off = 1; off < 128; off <<= 1) { __syncthreads(); __syncthreads(); }
    }
    __syncthreads();
    if (t < NBKT) {
        int idx = t * B1 + blockIdx.x;
        cur[t] = scn[idx] + bo[idx >> 10] - mat[idx];
    }
    __syncthreads();
    const int e0 = blockIdx.x * CH1;
    for (int i = t; i < CH1; i += 1024) {
        int s = ei[e0 + i];
        int d = ei[NE + e0 + i];
        unsigned int pos = atomicAdd(&cur[d >> SH], 1u);
        ebuf[pos] = ((unsigned int)(d & (NPB - 1)) << 17) | (unsigned int)s;
    }
}

// ---------------- pass 2: LDS-staged per-bucket degree/scan/row_start/dis + csr ----------------
__global__ __launch_bounds__(256) void k_fill2(const unsigned int* __restrict__ mat,
                                               const unsigned int* __restrict__ scn,
                                               const unsigned int* __restrict__ bsums,
                                               const unsigned int* __restrict__ ebuf,
                                               int* __restrict__ row_start,
                                               float* __restrict__ dis,
                                               int* __restrict__ csr) {
    __shared__ unsigned int stage[BCAP2];
    __shared__ unsigned int hist[NPB];
    __shared__ unsigned int cur[NPB];
    __shared__ unsigned int ps[NPB];
    __shared__ unsigned int bo[128];
    const int t = threadIdx.x;
    const int bkt = blockIdx.x;
    hist[t] = 0u;
    if (t < 128) {                               // 98-entry exclusive scan of bsums
        unsigned int v = (t < 98) ? bsums[t] : 0u;
        bo[t] = v;
        for (int off = 1; off < 128; off <<= 1) {
            __syncthreads();
            unsigned int a = (t >= off) ? bo[t - off] : 0u;
            __syncthreads();
            bo[t] += a;
        }
        bo[t] -= v;
    } else {
        for (int off = 1; off < 128; off <<= 1) { __syncthreads(); __syncthreads(); }
    }
    __syncthreads();
    const int i0 = bkt * B1;
    const unsigned int ebase = scn[i0] + bo[i0 >> 10] - mat[i0];
    unsigned int eend;
    if (bkt == NBKT - 1) eend = (unsigned int)NE;
    else {
        const int i1 = (bkt + 1) * B1;
        eend = scn[i1] + bo[i1 >> 10] - mat[i1];
    }
    const unsigned int n = eend - ebase;
    const unsigned int m = (n < BCAP2) ? n : BCAP2;
    for (unsigned int i = t; i < m; i += 256) {
        unsigned int v = ebuf[ebase + i];
        stage[i] = v;
        atomicAdd(&hist[v >> 17], 1u);
    }
    for (unsigned int i = BCAP2 + t; i < n; i += 256)   // overflow path (≈never)
        atomicAdd(&hist[ebuf[ebase + i] >> 17], 1u);
    __syncthreads();
    const unsigned int deg = hist[t];
    ps[t] = deg;
    __syncthreads();
    for (int off = 1; off < 256; off <<= 1) {
        unsigned int a = (t >= off) ? ps[t - off] : 0u;
        __syncthreads();
        ps[t] += a;
        __syncthreads();
    }
    const unsigned int ex = (t == 0) ? 0u : ps[t - 1];
    cur[t] = ebase + ex;
    const int node = bkt * NPB + t;
    if (node <= NN) row_start[node] = (int)(ebase + ex);   // node==NN lands on NE
    if (node < NN)  dis[node] = rsqrtf((float)(deg + 1u));
    __syncthreads();
    for (unsigned int i = t; i < m; i += 256) {
        unsigned int v = stage[i];
        unsigned int pos = atomicAdd(&cur[v >> 17], 1u);
        csr[pos] = (int)(v & 0x1FFFFu);
    }
    for (unsigned int i = BCAP2 + t; i < n; i += 256) {   // overflow path
        unsigned int v = ebuf[ebase + i];
        unsigned int pos = atomicAdd(&cur[v >> 17], 1u);
        csr[pos] = (int)(v & 0x1FFFFu);
    }
}

// ---------------- MFMA GEMM: g = bf16(x @ W) * dis  (swapped operands) ----------------
// D = W^T · x^T: D row ↦ wcol (4 consecutive per lane), D col ↦ xrow (lane&15)
// -> epilogue packs 4 consecutive cols per lane into one uint2 store (16 stores/thread).
__global__ __launch_bounds__(256) void k_gemm(const float* __restrict__ x,
                                              const unsigned int* __restrict__ Wt,
                                              const float* __restrict__ dis,
                                              unsigned short* __restrict__ g16) {
    __shared__ unsigned int xl[128 * 64];   // 32 KB bf16-pair tile
    const int tid = threadIdx.x;
    const int lane = tid & 63, wave = tid >> 6;
    const int row0 = blockIdx.x * 128;

#pragma unroll
    for (int i = 0; i < 16; ++i) {
        int fi = i * 256 + tid;            // 0..4095
        int lr = fi >> 5;                  // local row (32 thr/row)
        int cf = (fi & 31) * 4;            // f32 col
        int gr = row0 + lr; if (gr >= NN) gr = NN - 1;
        float4 v = *(const float4*)(x + (size_t)gr * F + cf);
        unsigned int u0 = pack2(v.x, v.y);
        unsigned int u1 = pack2(v.z, v.w);
        int cu = (cf >> 1) ^ ((lr & 7) << 2);
        uint2 w2; w2.x = u0; w2.y = u1;
        *(uint2*)&xl[lr * 64 + cu] = w2;
    }
    __syncthreads();

    const int rbase = row0 + wave * 32;
    short8 afr[2][4];                       // x fragments (B operand now)
#pragma unroll
    for (int m = 0; m < 2; ++m) {
        int lr = wave * 32 + m * 16 + (lane & 15);
#pragma unroll
        for (int kk = 0; kk < 4; ++kk) {
            int cu = (kk * 16 + (lane >> 4) * 4) ^ ((lr & 7) << 2);
            afr[m][kk] = *(const short8*)&xl[lr * 64 + cu];
        }
    }

    f32x4 acc[2][8];
#pragma unroll
    for (int m = 0; m < 2; ++m)
#pragma unroll
        for (int n = 0; n < 8; ++n) { f32x4 z = {0.f, 0.f, 0.f, 0.f}; acc[m][n] = z; }

    const uint4* Wt4 = (const uint4*)Wt;
#pragma unroll
    for (int kk = 0; kk < 4; ++kk) {
        union { uint4 u; short8 s; } bfr[8];   // W^T fragments (A operand now)
#pragma unroll
        for (int n = 0; n < 8; ++n) bfr[n].u = Wt4[(kk * 8 + n) * 64 + lane];
#pragma unroll
        for (int m = 0; m < 2; ++m)
#pragma unroll
            for (int n = 0; n < 8; ++n)
                acc[m][n] = __builtin_amdgcn_mfma_f32_16x16x32_bf16(bfr[n].s, afr[m][kk], acc[m][n], 0, 0, 0);
    }

    // epilogue: lane owns xrow = rbase + m*16 + (lane&15), wcols n*16+(lane>>4)*4 .. +3
#pragma unroll
    for (int m = 0; m < 2; ++m) {
        int xr = rbase + m * 16 + (lane & 15);
        bool ok = xr < NN;
        float d = ok ? dis[xr] : 0.0f;
        unsigned short* gp = g16 + (size_t)(ok ? xr : 0) * F + (lane >> 4) * 4;
#pragma unroll
        for (int n = 0; n < 8; ++n) {
            uint2 w;
            w.x = pack2(acc[m][n][0] * d, acc[m][n][1] * d);
            w.y = pack2(acc[m][n][2] * d, acc[m][n][3] * d);
            if (ok) *(uint2*)(gp + n * 16) = w;
        }
    }
}

// ---------------- gather: agg16 = bf16(b + dis[n]*sum(g[src] over src ∪ {n})) ----------------
__global__ __launch_bounds__(256) void k_gather(const unsigned int* __restrict__ g,
                                                const int* __restrict__ csr,
                                                const int* __restrict__ row_start,
                                                const float* __restrict__ dis,
                                                const float* __restrict__ b,
                                                unsigned int* __restrict__ agg_lo,
                                                unsigned int* __restrict__ agg_hi) {
    const int lane = threadIdx.x & 63;
    const int node = blockIdx.x * 4 + (threadIdx.x >> 6);
    if (node >= NN) return;
    const int q = lane >> 4;           // row slot (0..3)
    const int c = lane & 15;           // uint4 col: features 8c..8c+7
    const int j = row_start[node];
    const int e = row_start[node + 1];
    const int L = e - j + 1;           // + self
    int sv = (j + lane < e) ? csr[j + lane] : node;   // preload ids; self past end
    f32x2 A0 = {0.f, 0.f}, A1 = A0, A2 = A0, A3 = A0;
    int k = 0;
    const int L1 = (L < 64) ? L : 64;
    for (; k < L1; k += 16) {
        int k0 = k + q, k1 = k0 + 4, k2 = k0 + 8, k3 = k0 + 12;
        int r0 = __shfl(sv, k0);
        int r1 = __shfl(sv, k1);
        int r2 = __shfl(sv, k2);
        int r3 = __shfl(sv, k3);
        bool p0 = k0 < L, p1 = k1 < L, p2 = k2 < L, p3 = k3 < L;
        uint4 v0, v1, v2, v3;
        if (p0) v0 = *(const uint4*)&g[(size_t)r0 * 64 + c * 4];
        if (p1) v1 = *(const uint4*)&g[(size_t)r1 * 64 + c * 4];
        if (p2) v2 = *(const uint4*)&g[(size_t)r2 * 64 + c * 4];
        if (p3) v3 = *(const uint4*)&g[(size_t)r3 * 64 + c * 4];
        if (p0) {
            A0 = pkadd(A0, up2n(v0.x)); A1 = pkadd(A1, up2n(v0.y));
            A2 = pkadd(A2, up2n(v0.z)); A3 = pkadd(A3, up2n(v0.w));
        }
        if (p1) {
            A0 = pkadd(A0, up2n(v1.x)); A1 = pkadd(A1, up2n(v1.y));
            A2 = pkadd(A2, up2n(v1.z)); A3 = pkadd(A3, up2n(v1.w));
        }
        if (p2) {
            A0 = pkadd(A0, up2n(v2.x)); A1 = pkadd(A1, up2n(v2.y));
            A2 = pkadd(A2, up2n(v2.z)); A3 = pkadd(A3, up2n(v2.w));
        }
        if (p3) {
            A0 = pkadd(A0, up2n(v3.x)); A1 = pkadd(A1, up2n(v3.y));
            A2 = pkadd(A2, up2n(v3.z)); A3 = pkadd(A3, up2n(v3.w));
        }
    }
    for (; k < L; k += 16) {           // rare: deg+1 > 64
#pragma unroll
        for (int s = 0; s < 4; ++s) {
            int ks = k + q + s * 4;
            if (ks < L) {
                int rs = (j + ks < e) ? csr[j + ks] : node;
                uint4 v = *(const uint4*)&g[(size_t)rs * 64 + c * 4];
                A0 = pkadd(A0, up2n(v.x)); A1 = pkadd(A1, up2n(v.y));
                A2 = pkadd(A2, up2n(v.z)); A3 = pkadd(A3, up2n(v.w));
            }
        }
    }
#define RED2(A) A.x += __shfl_xor(A.x, 16); A.x += __shfl_xor(A.x, 32); \
                A.y += __shfl_xor(A.y, 16); A.y += __shfl_xor(A.y, 32);
    RED2(A0) RED2(A1) RED2(A2) RED2(A3)
#undef RED2
    if (q == 0) {                      // lanes 0..15 write the row (256B contiguous)
        float d = dis[node];
        const float4* bp = (const float4*)&b[c * 8];
        float4 b0 = bp[0], b1 = bp[1];
        uint4 w;
        w.x = pack2(b0.x + d * A0.x, b0.y + d * A0.y);
        w.y = pack2(b0.z + d * A1.x, b0.w + d * A1.y);
        w.z = pack2(b1.x + d * A2.x, b1.y + d * A2.y);
        w.w = pack2(b1.z + d * A3.x, b1.w + d * A3.y);
        unsigned int* base = (node < NSPL) ? (agg_lo + (size_t)node * 64)
                                           : (agg_hi + (size_t)(node - NSPL) * 64);
        *(uint4*)(base + c * 4) = w;
    }
}

// ---------------- stats: uint4 streaming, shfl+LDS reduce, dense partials ----------------
__global__ __launch_bounds__(256) void k_stats(const unsigned int* __restrict__ agg_lo,
                                               const unsigned int* __restrict__ agg_hi,
                                               float* __restrict__ partials) {
    __shared__ float lds[4][16][16];
    const int tid = threadIdx.x;
    const int lane = tid & 63, wave = tid >> 6;
    const uint4* lo4 = (const uint4*)agg_lo;
    const uint4* hi4 = (const uint4*)agg_hi;
    const long totalLo = (long)NSPL * 16;
    const long total   = (long)NN * 16;
    const long stride  = (long)SB * 256;
    float s[8], qq[8];
#pragma unroll
    for (int i = 0; i < 8; ++i) { s[i] = 0.f; qq[i] = 0.f; }
    for (long i = (long)blockIdx.x * 256 + tid; i < total; i += stride) {
        uint4 v = (i < totalLo) ? lo4[i] : hi4[i - totalLo];
        float f0 = blo(v.x), f1 = bhi(v.x), f2 = blo(v.y), f3 = bhi(v.y);
        float f4 = blo(v.z), f5 = bhi(v.z), f6 = blo(v.w), f7 = bhi(v.w);
        s[0] += f0; qq[0] += f0 * f0;  s[1] += f1; qq[1] += f1 * f1;
        s[2] += f2; qq[2] += f2 * f2;  s[3] += f3; qq[3] += f3 * f3;
        s[4] += f4; qq[4] += f4 * f4;  s[5] += f5; qq[5] += f5 * f5;
        s[6] += f6; qq[6] += f6 * f6;  s[7] += f7; qq[7] += f7 * f7;
    }
#pragma unroll
    for (int i = 0; i < 8; ++i) {
        s[i]  += __shfl_xor(s[i], 16);  s[i]  += __shfl_xor(s[i], 32);
        qq[i] += __shfl_xor(qq[i], 16); qq[i] += __shfl_xor(qq[i], 32);
    }
    if (lane < 16) {
#pragma unroll
        for (int i = 0; i < 8; ++i) {
            lds[wave][lane][i]     = s[i];
            lds[wave][lane][i + 8] = qq[i];
        }
    }
    __syncthreads();
    const int c4n = tid >> 4, slot = tid & 15;
    float v = lds[0][c4n][slot] + lds[1][c4n][slot] + lds[2][c4n][slot] + lds[3][c4n][slot];
    int f = c4n * 8 + (slot & 7);
    int idx = (slot < 8) ? f : (F + f);
    partials[(size_t)blockIdx.x * 256 + idx] = v;
}

// ---------------- reduce partials -> stats[256] (sums | sumsq) ----------------
__global__ __launch_bounds__(256) void k_red(const float* __restrict__ partials,
                                             float* __restrict__ stats) {
    float a0 = 0.f, a1 = 0.f, a2 = 0.f, a3 = 0.f;
    for (int bq = 0; bq < SB; bq += 4) {
        a0 += partials[(bq + 0) * 256 + threadIdx.x];
        a1 += partials[(bq + 1) * 256 + threadIdx.x];
        a2 += partials[(bq + 2) * 256 + threadIdx.x];
        a3 += partials[(bq + 3) * 256 + threadIdx.x];
    }
    stats[threadIdx.x] = (a0 + a1) + (a2 + a3);
}

// ---------------- fused norm + eicopy ----------------
__global__ __launch_bounds__(256) void k_normei(const unsigned int* __restrict__ agg_lo,
                                               const unsigned int* __restrict__ agg_hi,
                                               const float* __restrict__ stats,
                                               const float* __restrict__ gw,
                                               const float* __restrict__ gb,
                                               const float* __restrict__ gms,
                                               float* __restrict__ out0,
                                               const int* __restrict__ ei,
                                               float* __restrict__ out1) {
    __shared__ float A[F], Bc[F];
    if (threadIdx.x < F) {
        int f = threadIdx.x;
        const float invn = 1.0f / (float)NN;
        float mean = stats[f] * invn;
        float ms = mean * gms[f];
        float var = stats[F + f] * invn - 2.0f * ms * mean + ms * ms;
        float inv = rsqrtf(var + EPS);
        float a = inv * gw[f];
        A[f] = a;
        Bc[f] = gb[f] - ms * a;
    }
    __syncthreads();
    const int c4 = threadIdx.x & 15;       // fixed uint4-column per thread
    float ra[8], rb[8];
#pragma unroll
    for (int i = 0; i < 8; ++i) { ra[i] = A[c4 * 8 + i]; rb[i] = Bc[c4 * 8 + i]; }
    const uint4* lo4 = (const uint4*)agg_lo;
    const uint4* hi4 = (const uint4*)agg_hi;
    const int4* ei4 = (const int4*)ei;
    float4* o14 = (float4*)out1;
    const long totalLo = (long)NSPL * 16;
    const long total   = (long)NN * 16;
    const long stride  = (long)gridDim.x * 256;
    for (long i = (long)blockIdx.x * 256 + threadIdx.x; i < total; i += stride) {
        bool isLo = i < totalLo;
        uint4 v = isLo ? lo4[i] : hi4[i - totalLo];
        float f0 = blo(v.x) * ra[0] + rb[0], f1 = bhi(v.x) * ra[1] + rb[1];
        float f2 = blo(v.y) * ra[2] + rb[2], f3 = bhi(v.y) * ra[3] + rb[3];
        float f4 = blo(v.z) * ra[4] + rb[4], f5 = bhi(v.z) * ra[5] + rb[5];
        float f6 = blo(v.w) * ra[6] + rb[6], f7 = bhi(v.w) * ra[7] + rb[7];
        f0 = f0 > 0.f ? f0 : SLOPE * f0;  f1 = f1 > 0.f ? f1 : SLOPE * f1;
        f2 = f2 > 0.f ? f2 : SLOPE * f2;  f3 = f3 > 0.f ? f3 : SLOPE * f3;
        f4 = f4 > 0.f ? f4 : SLOPE * f4;  f5 = f5 > 0.f ? f5 : SLOPE * f5;
        f6 = f6 > 0.f ? f6 : SLOPE * f6;  f7 = f7 > 0.f ? f7 : SLOPE * f7;
        float4 r0, r1;
        r0.x = f0; r0.y = f1; r0.z = f2; r0.w = f3;
        r1.x = f4; r1.y = f5; r1.z = f6; r1.w = f7;
        float* op = out0 + i * 8;
        *(float4*)op = r0;
        *(float4*)(op + 4) = r1;
        if (isLo) {
            int4 ev = ei4[i];
            unsigned int z;                       // opaque zero derived from v.x:
            asm("v_and_b32 %0, 0, %1" : "=v"(z) : "v"(v.x));
            float4 r;
            r.x = (float)(ev.x | (int)z);         // store depends on agg load
            r.y = (float)ev.y;
            r.z = (float)ev.z;
            r.w = (float)ev.w;
            o14[i] = r;
        }
    }
}

extern "C" void kernel_launch(void* const* d_in, const int* in_sizes, int n_in,
                              void* d_out, int out_size, void* d_ws, size_t ws_size,
                              hipStream_t stream) {
    const float* x   = (const float*)d_in[0];
    const int*   ei  = (const int*)d_in[1];
    const float* Wm  = (const float*)d_in[2];
    const float* b   = (const float*)d_in[3];
    const float* gw  = (const float*)d_in[4];
    const float* gb  = (const float*)d_in[5];
    const float* gms = (const float*)d_in[6];

    float* out  = (float*)d_out;                 // region0: NN*F, region1: 2*NE
    float* out1 = out + (size_t)NN * F;
    unsigned int* agg_lo = (unsigned int*)out1;  // NSPL*64 u32 = 2*NE u32, exact fit

    // ws layout (u32 units). ebuf aliases g: ebuf consumed by k_fill2 before k_gemm writes g.
    unsigned int* wsu   = (unsigned int*)d_ws;
    unsigned int* g     = wsu;                          // NN*64 u32 (25.6 MB)
    unsigned int* ebuf  = wsu;                          // NE u32 (6.4 MB) — alias of g
    unsigned int* mat   = g + (size_t)NN * 64;          // MATP (padded)
    unsigned int* scn   = mat + MATP;                   // MATP
    unsigned int* bsums = scn + MATP;                   // 128
    int* row_start      = (int*)(bsums + 128);          // NN+1
    int* csr            = row_start + NN + 2;           // NE (+8 pad)
    float* dis          = (float*)(csr + NE + 8);       // NN
    float* stats        = dis + NN;                     // 256
    unsigned int* Wt    = (unsigned int*)(stats + 256); // 8192
    unsigned int* agg_hi = Wt + 8192;                   // (NN-NSPL)*64 u32 (12.8 MB)
    float* partials     = (float*)(agg_hi + (size_t)(NN - NSPL) * 64); // SB*256 (256 KB)

    k_hist1<<<B1, 1024, 0, stream>>>(ei + NE, mat, Wm, Wt);
    k_scanA<<<98, 1024, 0, stream>>>(mat, scn, bsums);
    k_scat1<<<B1, 1024, 0, stream>>>(ei, mat, scn, bsums, ebuf);
    k_fill2<<<NBKT, 256, 0, stream>>>(mat, scn, bsums, ebuf, row_start, dis, csr);
    k_gemm<<<(NN + 127) / 128, 256, 0, stream>>>(x, Wt, dis, (unsigned short*)g);
    k_gather<<<NN / 4, 256, 0, stream>>>(g, csr, row_start, dis, b, agg_lo, agg_hi);
    k_stats<<<SB, 256, 0, stream>>>(agg_lo, agg_hi, partials);
    k_red<<<1, 256, 0, stream>>>(partials, stats);
    k_normei<<<2048, 256, 0, stream>>>(agg_lo, agg_hi, stats, gw, gb, gms, out, ei, out1);
}

// Round 13
// 137.403 us; speedup vs baseline: 1.8033x; 1.1338x over previous
//
#include <hip/hip_runtime.h>

#define NN 100000
#define NE 1600000
#define F  128
#define NSPL 50000              // agg16 split: nodes < NSPL in out1, rest in ws

// radix partition params
#define SH   8                  // bucket = dst >> 8
#define NPB  256                // nodes per bucket
#define NBKT 391                // ceil(NN/256)
#define B1   256                // pass-1 blocks
#define CH1  6250               // NE / B1 exactly
#define MATN (NBKT * B1)        // 100096
#define MATP (98 * 1024)        // padded to scan grid (100352)
#define BCAP2 6144              // fill2 LDS stage cap (mean 4096, +32 sigma)

#define SB   256                // stats blocks (partials, no atomics)

constexpr float EPS   = 1e-5f;
constexpr float SLOPE = 0.01f;

typedef __attribute__((ext_vector_type(8))) short short8;
typedef __attribute__((ext_vector_type(4))) float f32x4;
typedef __attribute__((ext_vector_type(2))) float f32x2;

__device__ inline unsigned int bf16rne(float f) {
    unsigned int u = __float_as_uint(f);
    return (u + 0x7fffu + ((u >> 16) & 1u)) >> 16;
}
__device__ inline float blo(unsigned int u) { return __uint_as_float(u << 16); }
__device__ inline float bhi(unsigned int u) { return __uint_as_float(u & 0xffff0000u); }
__device__ inline unsigned int pack2(float a, float b) {
    return bf16rne(a) | (bf16rne(b) << 16);
}
__device__ inline f32x2 pkadd(f32x2 a, f32x2 b) {
    f32x2 d;
    asm("v_pk_add_f32 %0, %1, %2" : "=v"(d) : "v"(a), "v"(b));
    return d;
}
// fp8 e4m3 HW converters (gfx950 OCP fp8)
__device__ inline f32x2 fp8lo(unsigned int u) {
    return __builtin_amdgcn_cvt_pk_f32_fp8(u, false);   // bytes 0,1 -> 2 floats
}
__device__ inline f32x2 fp8hi(unsigned int u) {
    return __builtin_amdgcn_cvt_pk_f32_fp8(u, true);    // bytes 2,3 -> 2 floats
}
__device__ inline unsigned int fp8pack4(float a, float b, float c, float d) {
    int o = 0;
    o = __builtin_amdgcn_cvt_pk_fp8_f32(a, b, o, false);
    o = __builtin_amdgcn_cvt_pk_fp8_f32(c, d, o, true);
    return (unsigned int)o;
}

// ---------------- pass 1a: per-block bucket histogram + (blocks 0-7) W prep ----------------
__global__ __launch_bounds__(1024) void k_hist1(const int* __restrict__ dst,
                                                unsigned int* __restrict__ mat,
                                                const float* __restrict__ Wm,
                                                unsigned int* __restrict__ Wt) {
    __shared__ unsigned int h[NBKT];
    if (threadIdx.x < NBKT) h[threadIdx.x] = 0u;
    __syncthreads();
    if (blockIdx.x < 8) {                        // fused W prep (8192 entries)
        int idx = blockIdx.x * 1024 + threadIdx.x;
        int p = idx & 3, lane = (idx >> 2) & 63, n = (idx >> 8) & 7, kk = idx >> 11;
        int k0 = kk * 32 + (lane >> 4) * 8 + 2 * p;
        int c  = n * 16 + (lane & 15);
        unsigned int lo = bf16rne(Wm[k0 * F + c]);
        unsigned int hi = bf16rne(Wm[(k0 + 1) * F + c]);
        Wt[idx] = lo | (hi << 16);
    }
    const int e0 = blockIdx.x * CH1;
    for (int i = threadIdx.x; i < CH1; i += 1024)
        atomicAdd(&h[dst[e0 + i] >> SH], 1u);
    __syncthreads();
    if (threadIdx.x < NBKT) mat[threadIdx.x * B1 + blockIdx.x] = h[threadIdx.x];
}

// ---------------- scanA: inclusive per 1024-block + block sums ----------------
__global__ __launch_bounds__(1024) void k_scanA(const unsigned int* __restrict__ mat,
                                                unsigned int* __restrict__ scn,
                                                unsigned int* __restrict__ bsums) {
    __shared__ unsigned int ps[1024];
    const int t = threadIdx.x;
    const int i = blockIdx.x * 1024 + t;        // grid 98*1024 == MATP
    unsigned int v = mat[i];                     // pad region: garbage, harmless
    ps[t] = v;
    __syncthreads();
    for (int off = 1; off < 1024; off <<= 1) {
        unsigned int a = (t >= off) ? ps[t - off] : 0u;
        __syncthreads();
        ps[t] += a;
        __syncthreads();
    }
    scn[i] = ps[t];                              // inclusive within block
    if (t == 1023) bsums[blockIdx.x] = ps[1023];
}

// exclusive(i) = scn[i] + boff[i>>10] - mat[i]; boff computed in-block from bsums

// ---------------- pass 1c: scatter edges into bucket segments ----------------
__global__ __launch_bounds__(1024) void k_scat1(const int* __restrict__ ei,
                                                const unsigned int* __restrict__ mat,
                                                const unsigned int* __restrict__ scn,
                                                const unsigned int* __restrict__ bsums,
                                                unsigned int* __restrict__ ebuf) {
    __shared__ unsigned int cur[NBKT];
    __shared__ unsigned int bo[128];
    const int t = threadIdx.x;
    if (t < 128) {                               // 98-entry exclusive scan of bsums
        unsigned int v = (t < 98) ? bsums[t] : 0u;
        bo[t] = v;
        for (int off = 1; off < 128; off <<= 1) {
            __syncthreads();
            unsigned int a = (t >= off) ? bo[t - off] : 0u;
            __syncthreads();
            bo[t] += a;
        }
        bo[t] -= v;                              // exclusive
    } else {
        for (int off = 1; off < 128; off <<= 1) { __syncthreads(); __syncthreads(); }
    }
    __syncthreads();
    if (t < NBKT) {
        int idx = t * B1 + blockIdx.x;
        cur[t] = scn[idx] + bo[idx >> 10] - mat[idx];
    }
    __syncthreads();
    const int e0 = blockIdx.x * CH1;
    for (int i = t; i < CH1; i += 1024) {
        int s = ei[e0 + i];
        int d = ei[NE + e0 + i];
        unsigned int pos = atomicAdd(&cur[d >> SH], 1u);
        ebuf[pos] = ((unsigned int)(d & (NPB - 1)) << 17) | (unsigned int)s;
    }
}

// ---------------- pass 2: LDS-staged per-bucket degree/scan/row_start/dis + csr ----------------
__global__ __launch_bounds__(256) void k_fill2(const unsigned int* __restrict__ mat,
                                               const unsigned int* __restrict__ scn,
                                               const unsigned int* __restrict__ bsums,
                                               const unsigned int* __restrict__ ebuf,
                                               int* __restrict__ row_start,
                                               float* __restrict__ dis,
                                               int* __restrict__ csr) {
    __shared__ unsigned int stage[BCAP2];
    __shared__ unsigned int hist[NPB];
    __shared__ unsigned int cur[NPB];
    __shared__ unsigned int ps[NPB];
    __shared__ unsigned int bo[128];
    const int t = threadIdx.x;
    const int bkt = blockIdx.x;
    hist[t] = 0u;
    if (t < 128) {                               // 98-entry exclusive scan of bsums
        unsigned int v = (t < 98) ? bsums[t] : 0u;
        bo[t] = v;
        for (int off = 1; off < 128; off <<= 1) {
            __syncthreads();
            unsigned int a = (t >= off) ? bo[t - off] : 0u;
            __syncthreads();
            bo[t] += a;
        }
        bo[t] -= v;
    } else {
        for (int off = 1; off < 128; off <<= 1) { __syncthreads(); __syncthreads(); }
    }
    __syncthreads();
    const int i0 = bkt * B1;
    const unsigned int ebase = scn[i0] + bo[i0 >> 10] - mat[i0];
    unsigned int eend;
    if (bkt == NBKT - 1) eend = (unsigned int)NE;
    else {
        const int i1 = (bkt + 1) * B1;
        eend = scn[i1] + bo[i1 >> 10] - mat[i1];
    }
    const unsigned int n = eend - ebase;
    const unsigned int m = (n < BCAP2) ? n : BCAP2;
    for (unsigned int i = t; i < m; i += 256) {
        unsigned int v = ebuf[ebase + i];
        stage[i] = v;
        atomicAdd(&hist[v >> 17], 1u);
    }
    for (unsigned int i = BCAP2 + t; i < n; i += 256)   // overflow path (≈never)
        atomicAdd(&hist[ebuf[ebase + i] >> 17], 1u);
    __syncthreads();
    const unsigned int deg = hist[t];
    ps[t] = deg;
    __syncthreads();
    for (int off = 1; off < 256; off <<= 1) {
        unsigned int a = (t >= off) ? ps[t - off] : 0u;
        __syncthreads();
        ps[t] += a;
        __syncthreads();
    }
    const unsigned int ex = (t == 0) ? 0u : ps[t - 1];
    cur[t] = ebase + ex;
    const int node = bkt * NPB + t;
    if (node <= NN) row_start[node] = (int)(ebase + ex);   // node==NN lands on NE
    if (node < NN)  dis[node] = rsqrtf((float)(deg + 1u));
    __syncthreads();
    for (unsigned int i = t; i < m; i += 256) {
        unsigned int v = stage[i];
        unsigned int pos = atomicAdd(&cur[v >> 17], 1u);
        csr[pos] = (int)(v & 0x1FFFFu);
    }
    for (unsigned int i = BCAP2 + t; i < n; i += 256) {   // overflow path
        unsigned int v = ebuf[ebase + i];
        unsigned int pos = atomicAdd(&cur[v >> 17], 1u);
        csr[pos] = (int)(v & 0x1FFFFu);
    }
}

// ---------------- MFMA GEMM: g = fp8(x @ W * dis)  (swapped operands) ----------------
// D = W^T · x^T: lane owns xrow (lane&15) and 4 consecutive wcols -> 1 u32 of 4 fp8 per (m,n).
__global__ __launch_bounds__(256) void k_gemm(const float* __restrict__ x,
                                              const unsigned int* __restrict__ Wt,
                                              const float* __restrict__ dis,
                                              unsigned int* __restrict__ g32) {
    __shared__ unsigned int xl[128 * 64];   // 32 KB bf16-pair tile
    const int tid = threadIdx.x;
    const int lane = tid & 63, wave = tid >> 6;
    const int row0 = blockIdx.x * 128;

#pragma unroll
    for (int i = 0; i < 16; ++i) {
        int fi = i * 256 + tid;            // 0..4095
        int lr = fi >> 5;                  // local row (32 thr/row)
        int cf = (fi & 31) * 4;            // f32 col
        int gr = row0 + lr; if (gr >= NN) gr = NN - 1;
        float4 v = *(const float4*)(x + (size_t)gr * F + cf);
        unsigned int u0 = pack2(v.x, v.y);
        unsigned int u1 = pack2(v.z, v.w);
        int cu = (cf >> 1) ^ ((lr & 7) << 2);
        uint2 w2; w2.x = u0; w2.y = u1;
        *(uint2*)&xl[lr * 64 + cu] = w2;
    }
    __syncthreads();

    const int rbase = row0 + wave * 32;
    short8 afr[2][4];                       // x fragments (B operand)
#pragma unroll
    for (int m = 0; m < 2; ++m) {
        int lr = wave * 32 + m * 16 + (lane & 15);
#pragma unroll
        for (int kk = 0; kk < 4; ++kk) {
            int cu = (kk * 16 + (lane >> 4) * 4) ^ ((lr & 7) << 2);
            afr[m][kk] = *(const short8*)&xl[lr * 64 + cu];
        }
    }

    f32x4 acc[2][8];
#pragma unroll
    for (int m = 0; m < 2; ++m)
#pragma unroll
        for (int n = 0; n < 8; ++n) { f32x4 z = {0.f, 0.f, 0.f, 0.f}; acc[m][n] = z; }

    const uint4* Wt4 = (const uint4*)Wt;
#pragma unroll
    for (int kk = 0; kk < 4; ++kk) {
        union { uint4 u; short8 s; } bfr[8];   // W^T fragments (A operand)
#pragma unroll
        for (int n = 0; n < 8; ++n) bfr[n].u = Wt4[(kk * 8 + n) * 64 + lane];
#pragma unroll
        for (int m = 0; m < 2; ++m)
#pragma unroll
            for (int n = 0; n < 8; ++n)
                acc[m][n] = __builtin_amdgcn_mfma_f32_16x16x32_bf16(bfr[n].s, afr[m][kk], acc[m][n], 0, 0, 0);
    }

    // epilogue: lane owns xrow = rbase + m*16 + (lane&15), wcols n*16+(lane>>4)*4 .. +3
#pragma unroll
    for (int m = 0; m < 2; ++m) {
        int xr = rbase + m * 16 + (lane & 15);
        bool ok = xr < NN;
        float d = ok ? dis[xr] : 0.0f;
        unsigned int* gp = g32 + (size_t)(ok ? xr : 0) * 32 + (lane >> 4);
#pragma unroll
        for (int n = 0; n < 8; ++n) {
            unsigned int w = fp8pack4(acc[m][n][0] * d, acc[m][n][1] * d,
                                      acc[m][n][2] * d, acc[m][n][3] * d);
            if (ok) gp[n * 4] = w;
        }
    }
}

// ---------------- gather: agg16 = bf16(b + dis[n]*sum(g[src] over src ∪ {n})) ----------------
// wave per node; fp8 rows (128B = 2 lines); 16 lanes/row (uint2), 4 row-slots,
// 4 rows unrolled per iter; HW fp8->f32 cvt + v_pk_add_f32; 2-stage shfl reduce.
__global__ __launch_bounds__(256) void k_gather(const unsigned int* __restrict__ g32,
                                                const int* __restrict__ csr,
                                                const int* __restrict__ row_start,
                                                const float* __restrict__ dis,
                                                const float* __restrict__ b,
                                                unsigned int* __restrict__ agg_lo,
                                                unsigned int* __restrict__ agg_hi) {
    const int lane = threadIdx.x & 63;
    const int node = blockIdx.x * 4 + (threadIdx.x >> 6);
    if (node >= NN) return;
    const int q = lane >> 4;           // row slot (0..3)
    const int c = lane & 15;           // uint2 col: features 8c..8c+7
    const int j = row_start[node];
    const int e = row_start[node + 1];
    const int L = e - j + 1;           // + self
    int sv = (j + lane < e) ? csr[j + lane] : node;   // preload ids; self past end
    f32x2 A0 = {0.f, 0.f}, A1 = A0, A2 = A0, A3 = A0;
    int k = 0;
    const int L1 = (L < 64) ? L : 64;
    for (; k < L1; k += 16) {
        int k0 = k + q, k1 = k0 + 4, k2 = k0 + 8, k3 = k0 + 12;
        int r0 = __shfl(sv, k0);
        int r1 = __shfl(sv, k1);
        int r2 = __shfl(sv, k2);
        int r3 = __shfl(sv, k3);
        bool p0 = k0 < L, p1 = k1 < L, p2 = k2 < L, p3 = k3 < L;
        uint2 v0, v1, v2, v3;
        if (p0) v0 = *(const uint2*)&g32[(size_t)r0 * 32 + c * 2];
        if (p1) v1 = *(const uint2*)&g32[(size_t)r1 * 32 + c * 2];
        if (p2) v2 = *(const uint2*)&g32[(size_t)r2 * 32 + c * 2];
        if (p3) v3 = *(const uint2*)&g32[(size_t)r3 * 32 + c * 2];
        if (p0) {
            A0 = pkadd(A0, fp8lo(v0.x)); A1 = pkadd(A1, fp8hi(v0.x));
            A2 = pkadd(A2, fp8lo(v0.y)); A3 = pkadd(A3, fp8hi(v0.y));
        }
        if (p1) {
            A0 = pkadd(A0, fp8lo(v1.x)); A1 = pkadd(A1, fp8hi(v1.x));
            A2 = pkadd(A2, fp8lo(v1.y)); A3 = pkadd(A3, fp8hi(v1.y));
        }
        if (p2) {
            A0 = pkadd(A0, fp8lo(v2.x)); A1 = pkadd(A1, fp8hi(v2.x));
            A2 = pkadd(A2, fp8lo(v2.y)); A3 = pkadd(A3, fp8hi(v2.y));
        }
        if (p3) {
            A0 = pkadd(A0, fp8lo(v3.x)); A1 = pkadd(A1, fp8hi(v3.x));
            A2 = pkadd(A2, fp8lo(v3.y)); A3 = pkadd(A3, fp8hi(v3.y));
        }
    }
    for (; k < L; k += 16) {           // rare: deg+1 > 64
#pragma unroll
        for (int s = 0; s < 4; ++s) {
            int ks = k + q + s * 4;
            if (ks < L) {
                int rs = (j + ks < e) ? csr[j + ks] : node;
                uint2 v = *(const uint2*)&g32[(size_t)rs * 32 + c * 2];
                A0 = pkadd(A0, fp8lo(v.x)); A1 = pkadd(A1, fp8hi(v.x));
                A2 = pkadd(A2, fp8lo(v.y)); A3 = pkadd(A3, fp8hi(v.y));
            }
        }
    }
#define RED2(A) A.x += __shfl_xor(A.x, 16); A.x += __shfl_xor(A.x, 32); \
                A.y += __shfl_xor(A.y, 16); A.y += __shfl_xor(A.y, 32);
    RED2(A0) RED2(A1) RED2(A2) RED2(A3)
#undef RED2
    if (q == 0) {                      // lanes 0..15 write the row (256B contiguous)
        float d = dis[node];
        const float4* bp = (const float4*)&b[c * 8];
        float4 b0 = bp[0], b1 = bp[1];
        uint4 w;
        w.x = pack2(b0.x + d * A0.x, b0.y + d * A0.y);
        w.y = pack2(b0.z + d * A1.x, b0.w + d * A1.y);
        w.z = pack2(b1.x + d * A2.x, b1.y + d * A2.y);
        w.w = pack2(b1.z + d * A3.x, b1.w + d * A3.y);
        unsigned int* base = (node < NSPL) ? (agg_lo + (size_t)node * 64)
                                           : (agg_hi + (size_t)(node - NSPL) * 64);
        *(uint4*)(base + c * 4) = w;
    }
}

// ---------------- stats: uint4 streaming, shfl+LDS reduce, dense partials ----------------
__global__ __launch_bounds__(256) void k_stats(const unsigned int* __restrict__ agg_lo,
                                               const unsigned int* __restrict__ agg_hi,
                                               float* __restrict__ partials) {
    __shared__ float lds[4][16][16];
    const int tid = threadIdx.x;
    const int lane = tid & 63, wave = tid >> 6;
    const uint4* lo4 = (const uint4*)agg_lo;
    const uint4* hi4 = (const uint4*)agg_hi;
    const long totalLo = (long)NSPL * 16;
    const long total   = (long)NN * 16;
    const long stride  = (long)SB * 256;
    float s[8], qq[8];
#pragma unroll
    for (int i = 0; i < 8; ++i) { s[i] = 0.f; qq[i] = 0.f; }
    for (long i = (long)blockIdx.x * 256 + tid; i < total; i += stride) {
        uint4 v = (i < totalLo) ? lo4[i] : hi4[i - totalLo];
        float f0 = blo(v.x), f1 = bhi(v.x), f2 = blo(v.y), f3 = bhi(v.y);
        float f4 = blo(v.z), f5 = bhi(v.z), f6 = blo(v.w), f7 = bhi(v.w);
        s[0] += f0; qq[0] += f0 * f0;  s[1] += f1; qq[1] += f1 * f1;
        s[2] += f2; qq[2] += f2 * f2;  s[3] += f3; qq[3] += f3 * f3;
        s[4] += f4; qq[4] += f4 * f4;  s[5] += f5; qq[5] += f5 * f5;
        s[6] += f6; qq[6] += f6 * f6;  s[7] += f7; qq[7] += f7 * f7;
    }
#pragma unroll
    for (int i = 0; i < 8; ++i) {
        s[i]  += __shfl_xor(s[i], 16);  s[i]  += __shfl_xor(s[i], 32);
        qq[i] += __shfl_xor(qq[i], 16); qq[i] += __shfl_xor(qq[i], 32);
    }
    if (lane < 16) {
#pragma unroll
        for (int i = 0; i < 8; ++i) {
            lds[wave][lane][i]     = s[i];
            lds[wave][lane][i + 8] = qq[i];
        }
    }
    __syncthreads();
    const int c4n = tid >> 4, slot = tid & 15;
    float v = lds[0][c4n][slot] + lds[1][c4n][slot] + lds[2][c4n][slot] + lds[3][c4n][slot];
    int f = c4n * 8 + (slot & 7);
    int idx = (slot < 8) ? f : (F + f);
    partials[(size_t)blockIdx.x * 256 + idx] = v;
}

// ---------------- reduce partials -> stats[256] (sums | sumsq) ----------------
__global__ __launch_bounds__(256) void k_red(const float* __restrict__ partials,
                                             float* __restrict__ stats) {
    float a0 = 0.f, a1 = 0.f, a2 = 0.f, a3 = 0.f;
    for (int bq = 0; bq < SB; bq += 4) {
        a0 += partials[(bq + 0) * 256 + threadIdx.x];
        a1 += partials[(bq + 1) * 256 + threadIdx.x];
        a2 += partials[(bq + 2) * 256 + threadIdx.x];
        a3 += partials[(bq + 3) * 256 + threadIdx.x];
    }
    stats[threadIdx.x] = (a0 + a1) + (a2 + a3);
}

// ---------------- fused norm + eicopy ----------------
__global__ __launch_bounds__(256) void k_normei(const unsigned int* __restrict__ agg_lo,
                                               const unsigned int* __restrict__ agg_hi,
                                               const float* __restrict__ stats,
                                               const float* __restrict__ gw,
                                               const float* __restrict__ gb,
                                               const float* __restrict__ gms,
                                               float* __restrict__ out0,
                                               const int* __restrict__ ei,
                                               float* __restrict__ out1) {
    __shared__ float A[F], Bc[F];
    if (threadIdx.x < F) {
        int f = threadIdx.x;
        const float invn = 1.0f / (float)NN;
        float mean = stats[f] * invn;
        float ms = mean * gms[f];
        float var = stats[F + f] * invn - 2.0f * ms * mean + ms * ms;
        float inv = rsqrtf(var + EPS);
        float a = inv * gw[f];
        A[f] = a;
        Bc[f] = gb[f] - ms * a;
    }
    __syncthreads();
    const int c4 = threadIdx.x & 15;       // fixed uint4-column per thread
    float ra[8], rb[8];
#pragma unroll
    for (int i = 0; i < 8; ++i) { ra[i] = A[c4 * 8 + i]; rb[i] = Bc[c4 * 8 + i]; }
    const uint4* lo4 = (const uint4*)agg_lo;
    const uint4* hi4 = (const uint4*)agg_hi;
    const int4* ei4 = (const int4*)ei;
    float4* o14 = (float4*)out1;
    const long totalLo = (long)NSPL * 16;
    const long total   = (long)NN * 16;
    const long stride  = (long)gridDim.x * 256;
    for (long i = (long)blockIdx.x * 256 + threadIdx.x; i < total; i += stride) {
        bool isLo = i < totalLo;
        uint4 v = isLo ? lo4[i] : hi4[i - totalLo];
        float f0 = blo(v.x) * ra[0] + rb[0], f1 = bhi(v.x) * ra[1] + rb[1];
        float f2 = blo(v.y) * ra[2] + rb[2], f3 = bhi(v.y) * ra[3] + rb[3];
        float f4 = blo(v.z) * ra[4] + rb[4], f5 = bhi(v.z) * ra[5] + rb[5];
        float f6 = blo(v.w) * ra[6] + rb[6], f7 = bhi(v.w) * ra[7] + rb[7];
        f0 = f0 > 0.f ? f0 : SLOPE * f0;  f1 = f1 > 0.f ? f1 : SLOPE * f1;
        f2 = f2 > 0.f ? f2 : SLOPE * f2;  f3 = f3 > 0.f ? f3 : SLOPE * f3;
        f4 = f4 > 0.f ? f4 : SLOPE * f4;  f5 = f5 > 0.f ? f5 : SLOPE * f5;
        f6 = f6 > 0.f ? f6 : SLOPE * f6;  f7 = f7 > 0.f ? f7 : SLOPE * f7;
        float4 r0, r1;
        r0.x = f0; r0.y = f1; r0.z = f2; r0.w = f3;
        r1.x = f4; r1.y = f5; r1.z = f6; r1.w = f7;
        float* op = out0 + i * 8;
        *(float4*)op = r0;
        *(float4*)(op + 4) = r1;
        if (isLo) {
            int4 ev = ei4[i];
            unsigned int z;                       // opaque zero derived from v.x:
            asm("v_and_b32 %0, 0, %1" : "=v"(z) : "v"(v.x));
            float4 r;
            r.x = (float)(ev.x | (int)z);         // store depends on agg load
            r.y = (float)ev.y;
            r.z = (float)ev.z;
            r.w = (float)ev.w;
            o14[i] = r;
        }
    }
}

extern "C" void kernel_launch(void* const* d_in, const int* in_sizes, int n_in,
                              void* d_out, int out_size, void* d_ws, size_t ws_size,
                              hipStream_t stream) {
    const float* x   = (const float*)d_in[0];
    const int*   ei  = (const int*)d_in[1];
    const float* Wm  = (const float*)d_in[2];
    const float* b   = (const float*)d_in[3];
    const float* gw  = (const float*)d_in[4];
    const float* gb  = (const float*)d_in[5];
    const float* gms = (const float*)d_in[6];

    float* out  = (float*)d_out;                 // region0: NN*F, region1: 2*NE
    float* out1 = out + (size_t)NN * F;
    unsigned int* agg_lo = (unsigned int*)out1;  // NSPL*64 u32 = 2*NE u32, exact fit

    // ws layout (u32 units). ebuf aliases g32: ebuf consumed by k_fill2 before k_gemm writes g.
    unsigned int* wsu   = (unsigned int*)d_ws;
    unsigned int* g32   = wsu;                          // NN*32 u32 (12.8 MB, fp8 rows)
    unsigned int* ebuf  = wsu;                          // NE u32 (6.4 MB) — alias of g32
    unsigned int* mat   = g32 + (size_t)NN * 32;        // MATP (padded)
    unsigned int* scn   = mat + MATP;                   // MATP
    unsigned int* bsums = scn + MATP;                   // 128
    int* row_start      = (int*)(bsums + 128);          // NN+1
    int* csr            = row_start + NN + 2;           // NE (+8 pad)
    float* dis          = (float*)(csr + NE + 8);       // NN
    float* stats        = dis + NN;                     // 256
    unsigned int* Wt    = (unsigned int*)(stats + 256); // 8192
    unsigned int* agg_hi = Wt + 8192;                   // (NN-NSPL)*64 u32 (12.8 MB)
    float* partials     = (float*)(agg_hi + (size_t)(NN - NSPL) * 64); // SB*256 (256 KB)

    k_hist1<<<B1, 1024, 0, stream>>>(ei + NE, mat, Wm, Wt);
    k_scanA<<<98, 1024, 0, stream>>>(mat, scn, bsums);
    k_scat1<<<B1, 1024, 0, stream>>>(ei, mat, scn, bsums, ebuf);
    k_fill2<<<NBKT, 256, 0, stream>>>(mat, scn, bsums, ebuf, row_start, dis, csr);
    k_gemm<<<(NN + 127) / 128, 256, 0, stream>>>(x, Wt, dis, g32);
    k_gather<<<NN / 4, 256, 0, stream>>>(g32, csr, row_start, dis, b, agg_lo, agg_hi);
    k_stats<<<SB, 256, 0, stream>>>(agg_lo, agg_hi, partials);
    k_red<<<1, 256, 0, stream>>>(partials, stats);
    k_normei<<<2048, 256, 0, stream>>>(agg_lo, agg_hi, stats, gw, gb, gms, out, ei, out1);
}

// Round 14
// 136.108 us; speedup vs baseline: 1.8205x; 1.0095x over previous
//
#include <hip/hip_runtime.h>

#define NN 100000
#define NE 1600000
#define F  128

// radix partition params
#define SH   8                  // bucket = dst >> 8
#define NPB  256                // nodes per bucket
#define NBKT 391                // ceil(NN/256)
#define B1   256                // pass-1 blocks
#define CH1  6250               // NE / B1 exactly
#define MATN (NBKT * B1)        // 100096
#define MATP (98 * 1024)        // padded to scan grid (100352)
#define BCAP2 6144              // fill2 LDS stage cap (mean 4096, +32 sigma)

#define SB   256                // stats blocks (partials, no atomics)

constexpr float EPS   = 1e-5f;
constexpr float SLOPE = 0.01f;

typedef __attribute__((ext_vector_type(8))) short short8;
typedef __attribute__((ext_vector_type(4))) float f32x4;
typedef __attribute__((ext_vector_type(2))) float f32x2;

__device__ inline unsigned int bf16rne(float f) {
    unsigned int u = __float_as_uint(f);
    return (u + 0x7fffu + ((u >> 16) & 1u)) >> 16;
}
__device__ inline unsigned int pack2(float a, float b) {
    return bf16rne(a) | (bf16rne(b) << 16);
}
__device__ inline f32x2 pkadd(f32x2 a, f32x2 b) {
    f32x2 d;
    asm("v_pk_add_f32 %0, %1, %2" : "=v"(d) : "v"(a), "v"(b));
    return d;
}
__device__ inline f32x2 pkfma(f32x2 a, f32x2 b, f32x2 c) {
    f32x2 d;
    asm("v_pk_fma_f32 %0, %1, %2, %3" : "=v"(d) : "v"(a), "v"(b), "v"(c));
    return d;
}
// fp8 e4m3 HW converters (gfx950 OCP fp8)
__device__ inline f32x2 fp8lo(unsigned int u) {
    return __builtin_amdgcn_cvt_pk_f32_fp8(u, false);   // bytes 0,1 -> 2 floats
}
__device__ inline f32x2 fp8hi(unsigned int u) {
    return __builtin_amdgcn_cvt_pk_f32_fp8(u, true);    // bytes 2,3 -> 2 floats
}
__device__ inline unsigned int fp8pack4(float a, float b, float c, float d) {
    int o = 0;
    o = __builtin_amdgcn_cvt_pk_fp8_f32(a, b, o, false);
    o = __builtin_amdgcn_cvt_pk_fp8_f32(c, d, o, true);
    return (unsigned int)o;
}

// ---------------- pass 1a: per-block bucket histogram + (blocks 0-7) W prep ----------------
__global__ __launch_bounds__(1024) void k_hist1(const int* __restrict__ dst,
                                                unsigned int* __restrict__ mat,
                                                const float* __restrict__ Wm,
                                                unsigned int* __restrict__ Wt) {
    __shared__ unsigned int h[NBKT];
    if (threadIdx.x < NBKT) h[threadIdx.x] = 0u;
    __syncthreads();
    if (blockIdx.x < 8) {                        // fused W prep (8192 entries)
        int idx = blockIdx.x * 1024 + threadIdx.x;
        int p = idx & 3, lane = (idx >> 2) & 63, n = (idx >> 8) & 7, kk = idx >> 11;
        int k0 = kk * 32 + (lane >> 4) * 8 + 2 * p;
        int c  = n * 16 + (lane & 15);
        unsigned int lo = bf16rne(Wm[k0 * F + c]);
        unsigned int hi = bf16rne(Wm[(k0 + 1) * F + c]);
        Wt[idx] = lo | (hi << 16);
    }
    const int e0 = blockIdx.x * CH1;
    for (int i = threadIdx.x; i < CH1; i += 1024)
        atomicAdd(&h[dst[e0 + i] >> SH], 1u);
    __syncthreads();
    if (threadIdx.x < NBKT) mat[threadIdx.x * B1 + blockIdx.x] = h[threadIdx.x];
}

// ---------------- scanA: inclusive per 1024-block + block sums ----------------
__global__ __launch_bounds__(1024) void k_scanA(const unsigned int* __restrict__ mat,
                                                unsigned int* __restrict__ scn,
                                                unsigned int* __restrict__ bsums) {
    __shared__ unsigned int ps[1024];
    const int t = threadIdx.x;
    const int i = blockIdx.x * 1024 + t;        // grid 98*1024 == MATP
    unsigned int v = mat[i];                     // pad region: garbage, harmless
    ps[t] = v;
    __syncthreads();
    for (int off = 1; off < 1024; off <<= 1) {
        unsigned int a = (t >= off) ? ps[t - off] : 0u;
        __syncthreads();
        ps[t] += a;
        __syncthreads();
    }
    scn[i] = ps[t];                              // inclusive within block
    if (t == 1023) bsums[blockIdx.x] = ps[1023];
}

// exclusive(i) = scn[i] + boff[i>>10] - mat[i]; boff computed in-block from bsums

// ---------------- pass 1c: scatter edges into bucket segments ----------------
__global__ __launch_bounds__(1024) void k_scat1(const int* __restrict__ ei,
                                                const unsigned int* __restrict__ mat,
                                                const unsigned int* __restrict__ scn,
                                                const unsigned int* __restrict__ bsums,
                                                unsigned int* __restrict__ ebuf) {
    __shared__ unsigned int cur[NBKT];
    __shared__ unsigned int bo[128];
    const int t = threadIdx.x;
    if (t < 128) {                               // 98-entry exclusive scan of bsums
        unsigned int v = (t < 98) ? bsums[t] : 0u;
        bo[t] = v;
        for (int off = 1; off < 128; off <<= 1) {
            __syncthreads();
            unsigned int a = (t >= off) ? bo[t - off] : 0u;
            __syncthreads();
            bo[t] += a;
        }
        bo[t] -= v;                              // exclusive
    } else {
        for (int off = 1; off < 128; off <<= 1) { __syncthreads(); __syncthreads(); }
    }
    __syncthreads();
    if (t < NBKT) {
        int idx = t * B1 + blockIdx.x;
        cur[t] = scn[idx] + bo[idx >> 10] - mat[idx];
    }
    __syncthreads();
    const int e0 = blockIdx.x * CH1;
    for (int i = t; i < CH1; i += 1024) {
        int s = ei[e0 + i];
        int d = ei[NE + e0 + i];
        unsigned int pos = atomicAdd(&cur[d >> SH], 1u);
        ebuf[pos] = ((unsigned int)(d & (NPB - 1)) << 17) | (unsigned int)s;
    }
}

// ---------------- pass 2: LDS-staged per-bucket degree/scan/row_start/dis + csr ----------------
__global__ __launch_bounds__(256) void k_fill2(const unsigned int* __restrict__ mat,
                                               const unsigned int* __restrict__ scn,
                                               const unsigned int* __restrict__ bsums,
                                               const unsigned int* __restrict__ ebuf,
                                               int* __restrict__ row_start,
                                               float* __restrict__ dis,
                                               int* __restrict__ csr) {
    __shared__ unsigned int stage[BCAP2];
    __shared__ unsigned int hist[NPB];
    __shared__ unsigned int cur[NPB];
    __shared__ unsigned int ps[NPB];
    __shared__ unsigned int bo[128];
    const int t = threadIdx.x;
    const int bkt = blockIdx.x;
    hist[t] = 0u;
    if (t < 128) {                               // 98-entry exclusive scan of bsums
        unsigned int v = (t < 98) ? bsums[t] : 0u;
        bo[t] = v;
        for (int off = 1; off < 128; off <<= 1) {
            __syncthreads();
            unsigned int a = (t >= off) ? bo[t - off] : 0u;
            __syncthreads();
            bo[t] += a;
        }
        bo[t] -= v;
    } else {
        for (int off = 1; off < 128; off <<= 1) { __syncthreads(); __syncthreads(); }
    }
    __syncthreads();
    const int i0 = bkt * B1;
    const unsigned int ebase = scn[i0] + bo[i0 >> 10] - mat[i0];
    unsigned int eend;
    if (bkt == NBKT - 1) eend = (unsigned int)NE;
    else {
        const int i1 = (bkt + 1) * B1;
        eend = scn[i1] + bo[i1 >> 10] - mat[i1];
    }
    const unsigned int n = eend - ebase;
    const unsigned int m = (n < BCAP2) ? n : BCAP2;
    for (unsigned int i = t; i < m; i += 256) {
        unsigned int v = ebuf[ebase + i];
        stage[i] = v;
        atomicAdd(&hist[v >> 17], 1u);
    }
    for (unsigned int i = BCAP2 + t; i < n; i += 256)   // overflow path (≈never)
        atomicAdd(&hist[ebuf[ebase + i] >> 17], 1u);
    __syncthreads();
    const unsigned int deg = hist[t];
    ps[t] = deg;
    __syncthreads();
    for (int off = 1; off < 256; off <<= 1) {
        unsigned int a = (t >= off) ? ps[t - off] : 0u;
        __syncthreads();
        ps[t] += a;
        __syncthreads();
    }
    const unsigned int ex = (t == 0) ? 0u : ps[t - 1];
    cur[t] = ebase + ex;
    const int node = bkt * NPB + t;
    if (node <= NN) row_start[node] = (int)(ebase + ex);   // node==NN lands on NE
    if (node < NN)  dis[node] = rsqrtf((float)(deg + 1u));
    __syncthreads();
    for (unsigned int i = t; i < m; i += 256) {
        unsigned int v = stage[i];
        unsigned int pos = atomicAdd(&cur[v >> 17], 1u);
        csr[pos] = (int)(v & 0x1FFFFu);
    }
    for (unsigned int i = BCAP2 + t; i < n; i += 256) {   // overflow path
        unsigned int v = ebuf[ebase + i];
        unsigned int pos = atomicAdd(&cur[v >> 17], 1u);
        csr[pos] = (int)(v & 0x1FFFFu);
    }
}

// ---------------- MFMA GEMM: g = fp8(x @ W * dis)  (swapped operands) ----------------
__global__ __launch_bounds__(256) void k_gemm(const float* __restrict__ x,
                                              const unsigned int* __restrict__ Wt,
                                              const float* __restrict__ dis,
                                              unsigned int* __restrict__ g32) {
    __shared__ unsigned int xl[128 * 64];   // 32 KB bf16-pair tile
    const int tid = threadIdx.x;
    const int lane = tid & 63, wave = tid >> 6;
    const int row0 = blockIdx.x * 128;

#pragma unroll
    for (int i = 0; i < 16; ++i) {
        int fi = i * 256 + tid;            // 0..4095
        int lr = fi >> 5;                  // local row (32 thr/row)
        int cf = (fi & 31) * 4;            // f32 col
        int gr = row0 + lr; if (gr >= NN) gr = NN - 1;
        float4 v = *(const float4*)(x + (size_t)gr * F + cf);
        unsigned int u0 = pack2(v.x, v.y);
        unsigned int u1 = pack2(v.z, v.w);
        int cu = (cf >> 1) ^ ((lr & 7) << 2);
        uint2 w2; w2.x = u0; w2.y = u1;
        *(uint2*)&xl[lr * 64 + cu] = w2;
    }
    __syncthreads();

    const int rbase = row0 + wave * 32;
    short8 afr[2][4];                       // x fragments (B operand)
#pragma unroll
    for (int m = 0; m < 2; ++m) {
        int lr = wave * 32 + m * 16 + (lane & 15);
#pragma unroll
        for (int kk = 0; kk < 4; ++kk) {
            int cu = (kk * 16 + (lane >> 4) * 4) ^ ((lr & 7) << 2);
            afr[m][kk] = *(const short8*)&xl[lr * 64 + cu];
        }
    }

    f32x4 acc[2][8];
#pragma unroll
    for (int m = 0; m < 2; ++m)
#pragma unroll
        for (int n = 0; n < 8; ++n) { f32x4 z = {0.f, 0.f, 0.f, 0.f}; acc[m][n] = z; }

    const uint4* Wt4 = (const uint4*)Wt;
#pragma unroll
    for (int kk = 0; kk < 4; ++kk) {
        union { uint4 u; short8 s; } bfr[8];   // W^T fragments (A operand)
#pragma unroll
        for (int n = 0; n < 8; ++n) bfr[n].u = Wt4[(kk * 8 + n) * 64 + lane];
#pragma unroll
        for (int m = 0; m < 2; ++m)
#pragma unroll
            for (int n = 0; n < 8; ++n)
                acc[m][n] = __builtin_amdgcn_mfma_f32_16x16x32_bf16(bfr[n].s, afr[m][kk], acc[m][n], 0, 0, 0);
    }

    // epilogue: lane owns xrow = rbase + m*16 + (lane&15), wcols n*16+(lane>>4)*4 .. +3
#pragma unroll
    for (int m = 0; m < 2; ++m) {
        int xr = rbase + m * 16 + (lane & 15);
        bool ok = xr < NN;
        float d = ok ? dis[xr] : 0.0f;
        unsigned int* gp = g32 + (size_t)(ok ? xr : 0) * 32 + (lane >> 4);
#pragma unroll
        for (int n = 0; n < 8; ++n) {
            unsigned int w = fp8pack4(acc[m][n][0] * d, acc[m][n][1] * d,
                                      acc[m][n][2] * d, acc[m][n][3] * d);
            if (ok) gp[n * 4] = w;
        }
    }
}

// ---------------- gather: agg8 = fp8(b + dis[n]*sum(g[src] over src ∪ {n})) ----------------
// wave per node; fp8 rows (128B = 2 lines); 16 lanes/row (uint2), 4 row-slots,
// 4 rows unrolled per iter; HW fp8 cvt + v_pk_add_f32; 2-stage shfl reduce; fp8 out.
__global__ __launch_bounds__(256) void k_gather(const unsigned int* __restrict__ g32,
                                                const int* __restrict__ csr,
                                                const int* __restrict__ row_start,
                                                const float* __restrict__ dis,
                                                const float* __restrict__ b,
                                                unsigned int* __restrict__ agg8) {
    const int lane = threadIdx.x & 63;
    const int node = blockIdx.x * 4 + (threadIdx.x >> 6);
    if (node >= NN) return;
    const int q = lane >> 4;           // row slot (0..3)
    const int c = lane & 15;           // uint2 col: features 8c..8c+7
    const int j = row_start[node];
    const int e = row_start[node + 1];
    const int L = e - j + 1;           // + self
    int sv = (j + lane < e) ? csr[j + lane] : node;   // preload ids; self past end
    f32x2 A0 = {0.f, 0.f}, A1 = A0, A2 = A0, A3 = A0;
    int k = 0;
    const int L1 = (L < 64) ? L : 64;
    for (; k < L1; k += 16) {
        int k0 = k + q, k1 = k0 + 4, k2 = k0 + 8, k3 = k0 + 12;
        int r0 = __shfl(sv, k0);
        int r1 = __shfl(sv, k1);
        int r2 = __shfl(sv, k2);
        int r3 = __shfl(sv, k3);
        bool p0 = k0 < L, p1 = k1 < L, p2 = k2 < L, p3 = k3 < L;
        uint2 v0, v1, v2, v3;
        if (p0) v0 = *(const uint2*)&g32[(size_t)r0 * 32 + c * 2];
        if (p1) v1 = *(const uint2*)&g32[(size_t)r1 * 32 + c * 2];
        if (p2) v2 = *(const uint2*)&g32[(size_t)r2 * 32 + c * 2];
        if (p3) v3 = *(const uint2*)&g32[(size_t)r3 * 32 + c * 2];
        if (p0) {
            A0 = pkadd(A0, fp8lo(v0.x)); A1 = pkadd(A1, fp8hi(v0.x));
            A2 = pkadd(A2, fp8lo(v0.y)); A3 = pkadd(A3, fp8hi(v0.y));
        }
        if (p1) {
            A0 = pkadd(A0, fp8lo(v1.x)); A1 = pkadd(A1, fp8hi(v1.x));
            A2 = pkadd(A2, fp8lo(v1.y)); A3 = pkadd(A3, fp8hi(v1.y));
        }
        if (p2) {
            A0 = pkadd(A0, fp8lo(v2.x)); A1 = pkadd(A1, fp8hi(v2.x));
            A2 = pkadd(A2, fp8lo(v2.y)); A3 = pkadd(A3, fp8hi(v2.y));
        }
        if (p3) {
            A0 = pkadd(A0, fp8lo(v3.x)); A1 = pkadd(A1, fp8hi(v3.x));
            A2 = pkadd(A2, fp8lo(v3.y)); A3 = pkadd(A3, fp8hi(v3.y));
        }
    }
    for (; k < L; k += 16) {           // rare: deg+1 > 64
#pragma unroll
        for (int s = 0; s < 4; ++s) {
            int ks = k + q + s * 4;
            if (ks < L) {
                int rs = (j + ks < e) ? csr[j + ks] : node;
                uint2 v = *(const uint2*)&g32[(size_t)rs * 32 + c * 2];
                A0 = pkadd(A0, fp8lo(v.x)); A1 = pkadd(A1, fp8hi(v.x));
                A2 = pkadd(A2, fp8lo(v.y)); A3 = pkadd(A3, fp8hi(v.y));
            }
        }
    }
#define RED2(A) A.x += __shfl_xor(A.x, 16); A.x += __shfl_xor(A.x, 32); \
                A.y += __shfl_xor(A.y, 16); A.y += __shfl_xor(A.y, 32);
    RED2(A0) RED2(A1) RED2(A2) RED2(A3)
#undef RED2
    if (q == 0) {                      // lanes 0..15 write the row (128B contiguous)
        float d = dis[node];
        const float4* bp = (const float4*)&b[c * 8];
        float4 b0 = bp[0], b1 = bp[1];
        uint2 w;
        w.x = fp8pack4(b0.x + d * A0.x, b0.y + d * A0.y,
                       b0.z + d * A1.x, b0.w + d * A1.y);
        w.y = fp8pack4(b1.x + d * A2.x, b1.y + d * A2.y,
                       b1.z + d * A3.x, b1.w + d * A3.y);
        *(uint2*)&agg8[(size_t)node * 32 + c * 2] = w;
    }
}

// ---------------- stats: fp8 agg uint4 streaming, pk_fma, shfl+LDS reduce ----------------
// stride % 8 == 0 -> thread owns fixed uint4-column c8 (features 16c8..16c8+15).
__global__ __launch_bounds__(256) void k_stats(const unsigned int* __restrict__ agg8,
                                               float* __restrict__ partials) {
    __shared__ float lds[4][8][32];
    const int tid = threadIdx.x;
    const int lane = tid & 63, wave = tid >> 6;
    const uint4* a4 = (const uint4*)agg8;
    const long total  = (long)NN * 8;
    const long stride = (long)SB * 256;
    f32x2 S[8], Q[8];
#pragma unroll
    for (int i = 0; i < 8; ++i) { f32x2 z = {0.f, 0.f}; S[i] = z; Q[i] = z; }
    for (long i = (long)blockIdx.x * 256 + tid; i < total; i += stride) {
        uint4 v = a4[i];
        f32x2 p0 = fp8lo(v.x), p1 = fp8hi(v.x), p2 = fp8lo(v.y), p3 = fp8hi(v.y);
        f32x2 p4 = fp8lo(v.z), p5 = fp8hi(v.z), p6 = fp8lo(v.w), p7 = fp8hi(v.w);
        S[0] = pkadd(S[0], p0); Q[0] = pkfma(p0, p0, Q[0]);
        S[1] = pkadd(S[1], p1); Q[1] = pkfma(p1, p1, Q[1]);
        S[2] = pkadd(S[2], p2); Q[2] = pkfma(p2, p2, Q[2]);
        S[3] = pkadd(S[3], p3); Q[3] = pkfma(p3, p3, Q[3]);
        S[4] = pkadd(S[4], p4); Q[4] = pkfma(p4, p4, Q[4]);
        S[5] = pkadd(S[5], p5); Q[5] = pkfma(p5, p5, Q[5]);
        S[6] = pkadd(S[6], p6); Q[6] = pkfma(p6, p6, Q[6]);
        S[7] = pkadd(S[7], p7); Q[7] = pkfma(p7, p7, Q[7]);
    }
#pragma unroll
    for (int i = 0; i < 8; ++i) {
        S[i].x += __shfl_xor(S[i].x, 8); S[i].x += __shfl_xor(S[i].x, 16); S[i].x += __shfl_xor(S[i].x, 32);
        S[i].y += __shfl_xor(S[i].y, 8); S[i].y += __shfl_xor(S[i].y, 16); S[i].y += __shfl_xor(S[i].y, 32);
        Q[i].x += __shfl_xor(Q[i].x, 8); Q[i].x += __shfl_xor(Q[i].x, 16); Q[i].x += __shfl_xor(Q[i].x, 32);
        Q[i].y += __shfl_xor(Q[i].y, 8); Q[i].y += __shfl_xor(Q[i].y, 16); Q[i].y += __shfl_xor(Q[i].y, 32);
    }
    if (lane < 8) {                    // lane == c8; features 16*lane .. +15
#pragma unroll
        for (int i = 0; i < 8; ++i) {
            lds[wave][lane][2 * i]      = S[i].x;
            lds[wave][lane][2 * i + 1]  = S[i].y;
            lds[wave][lane][16 + 2 * i]     = Q[i].x;
            lds[wave][lane][16 + 2 * i + 1] = Q[i].y;
        }
    }
    __syncthreads();
    const int kind = tid >> 7;         // 0 sums, 1 sumsq
    const int f = tid & 127;
    const int l = f >> 4, slot = (f & 15) + 16 * kind;
    float v = lds[0][l][slot] + lds[1][l][slot] + lds[2][l][slot] + lds[3][l][slot];
    partials[(size_t)blockIdx.x * 256 + tid] = v;
}

// ---------------- reduce partials -> stats[256] (sums | sumsq) ----------------
__global__ __launch_bounds__(256) void k_red(const float* __restrict__ partials,
                                             float* __restrict__ stats) {
    float a0 = 0.f, a1 = 0.f, a2 = 0.f, a3 = 0.f;
    for (int bq = 0; bq < SB; bq += 4) {
        a0 += partials[(bq + 0) * 256 + threadIdx.x];
        a1 += partials[(bq + 1) * 256 + threadIdx.x];
        a2 += partials[(bq + 2) * 256 + threadIdx.x];
        a3 += partials[(bq + 3) * 256 + threadIdx.x];
    }
    stats[threadIdx.x] = (a0 + a1) + (a2 + a3);
}

// ---------------- fused norm + eicopy (fp8 agg in out1, 1:1 with ei copy) ----------------
__global__ __launch_bounds__(256) void k_normei(const unsigned int* __restrict__ agg8,
                                               const float* __restrict__ stats,
                                               const float* __restrict__ gw,
                                               const float* __restrict__ gb,
                                               const float* __restrict__ gms,
                                               float* __restrict__ out0,
                                               const int* __restrict__ ei,
                                               float* __restrict__ out1) {
    __shared__ float A[F], Bc[F];
    if (threadIdx.x < F) {
        int f = threadIdx.x;
        const float invn = 1.0f / (float)NN;
        float mean = stats[f] * invn;
        float ms = mean * gms[f];
        float var = stats[F + f] * invn - 2.0f * ms * mean + ms * ms;
        float inv = rsqrtf(var + EPS);
        float a = inv * gw[f];
        A[f] = a;
        Bc[f] = gb[f] - ms * a;
    }
    __syncthreads();
    const int c8 = threadIdx.x & 7;        // fixed uint4-column (features 16c8..16c8+15)
    float ra[16], rb[16];
#pragma unroll
    for (int i = 0; i < 16; ++i) { ra[i] = A[c8 * 16 + i]; rb[i] = Bc[c8 * 16 + i]; }
    const uint4* a4 = (const uint4*)agg8;
    const int4* ei4 = (const int4*)ei;
    float4* o14 = (float4*)out1;
    const long total  = (long)NN * 8;      // uint4 count == int4 count of ei
    const long stride = (long)gridDim.x * 256;
    for (long i = (long)blockIdx.x * 256 + threadIdx.x; i < total; i += stride) {
        uint4 v = a4[i];
        f32x2 p0 = fp8lo(v.x), p1 = fp8hi(v.x), p2 = fp8lo(v.y), p3 = fp8hi(v.y);
        f32x2 p4 = fp8lo(v.z), p5 = fp8hi(v.z), p6 = fp8lo(v.w), p7 = fp8hi(v.w);
        float fv[16];
        fv[0] = p0.x * ra[0] + rb[0];   fv[1] = p0.y * ra[1] + rb[1];
        fv[2] = p1.x * ra[2] + rb[2];   fv[3] = p1.y * ra[3] + rb[3];
        fv[4] = p2.x * ra[4] + rb[4];   fv[5] = p2.y * ra[5] + rb[5];
        fv[6] = p3.x * ra[6] + rb[6];   fv[7] = p3.y * ra[7] + rb[7];
        fv[8] = p4.x * ra[8] + rb[8];   fv[9] = p4.y * ra[9] + rb[9];
        fv[10] = p5.x * ra[10] + rb[10]; fv[11] = p5.y * ra[11] + rb[11];
        fv[12] = p6.x * ra[12] + rb[12]; fv[13] = p6.y * ra[13] + rb[13];
        fv[14] = p7.x * ra[14] + rb[14]; fv[15] = p7.y * ra[15] + rb[15];
#pragma unroll
        for (int t = 0; t < 16; ++t) fv[t] = fv[t] > 0.f ? fv[t] : SLOPE * fv[t];
        float* op = out0 + i * 16;
#pragma unroll
        for (int t = 0; t < 4; ++t) {
            float4 r; r.x = fv[4 * t]; r.y = fv[4 * t + 1]; r.z = fv[4 * t + 2]; r.w = fv[4 * t + 3];
            *(float4*)(op + 4 * t) = r;
        }
        // ei copy overwrites the same 16 bytes this thread just read from agg8
        int4 ev = ei4[i];
        unsigned int z;                       // opaque zero derived from v.x:
        asm("v_and_b32 %0, 0, %1" : "=v"(z) : "v"(v.x));
        float4 r;
        r.x = (float)(ev.x | (int)z);         // store depends on agg load
        r.y = (float)ev.y;
        r.z = (float)ev.z;
        r.w = (float)ev.w;
        o14[i] = r;
    }
}

extern "C" void kernel_launch(void* const* d_in, const int* in_sizes, int n_in,
                              void* d_out, int out_size, void* d_ws, size_t ws_size,
                              hipStream_t stream) {
    const float* x   = (const float*)d_in[0];
    const int*   ei  = (const int*)d_in[1];
    const float* Wm  = (const float*)d_in[2];
    const float* b   = (const float*)d_in[3];
    const float* gw  = (const float*)d_in[4];
    const float* gb  = (const float*)d_in[5];
    const float* gms = (const float*)d_in[6];

    float* out  = (float*)d_out;                 // region0: NN*F, region1: 2*NE
    float* out1 = out + (size_t)NN * F;
    unsigned int* agg8 = (unsigned int*)out1;    // NN*32 u32 = 2*NE u32, exact fit

    // ws layout (u32 units). ebuf aliases g32: ebuf consumed by k_fill2 before k_gemm writes g.
    unsigned int* wsu   = (unsigned int*)d_ws;
    unsigned int* g32   = wsu;                          // NN*32 u32 (12.8 MB, fp8 rows)
    unsigned int* ebuf  = wsu;                          // NE u32 (6.4 MB) — alias of g32
    unsigned int* mat   = g32 + (size_t)NN * 32;        // MATP (padded)
    unsigned int* scn   = mat + MATP;                   // MATP
    unsigned int* bsums = scn + MATP;                   // 128
    int* row_start      = (int*)(bsums + 128);          // NN+1
    int* csr            = row_start + NN + 2;           // NE (+8 pad)
    float* dis          = (float*)(csr + NE + 8);       // NN
    float* stats        = dis + NN;                     // 256
    unsigned int* Wt    = (unsigned int*)(stats + 256); // 8192
    float* partials     = (float*)(Wt + 8192);          // SB*256 (256 KB)

    k_hist1<<<B1, 1024, 0, stream>>>(ei + NE, mat, Wm, Wt);
    k_scanA<<<98, 1024, 0, stream>>>(mat, scn, bsums);
    k_scat1<<<B1, 1024, 0, stream>>>(ei, mat, scn, bsums, ebuf);
    k_fill2<<<NBKT, 256, 0, stream>>>(mat, scn, bsums, ebuf, row_start, dis, csr);
    k_gemm<<<(NN + 127) / 128, 256, 0, stream>>>(x, Wt, dis, g32);
    k_gather<<<NN / 4, 256, 0, stream>>>(g32, csr, row_start, dis, b, agg8);
    k_stats<<<SB, 256, 0, stream>>>(agg8, partials);
    k_red<<<1, 256, 0, stream>>>(partials, stats);
    k_normei<<<2048, 256, 0, stream>>>(agg8, stats, gw, gb, gms, out, ei, out1);
}